// Round 2
// baseline (1075.318 us; speedup 1.0000x reference)
//
#include <hip/hip_runtime.h>
#include <hip/hip_bf16.h>

constexpr int NN  = 32768;      // total nodes
constexpr int FDI = 128;        // input feature dim
constexpr int HD  = 256;        // hidden dim
constexpr int NB  = 256;        // graphs
constexpr int MX  = 128;        // nodes per graph
constexpr int NE  = 524288;     // edges; per graph = 2048 = 1<<11

// ---------------- adjacency build ----------------
__global__ void k_deg(const int* __restrict__ dstL, float* __restrict__ deg) {
    int e = blockIdx.x * 256 + threadIdx.x;
    int g = e >> 11;
    atomicAdd(&deg[(g << 7) + dstL[e]], 1.0f);   // integer counts: order-exact
}

__global__ void k_dinv(float* __restrict__ deg) {
    int i = blockIdx.x * 256 + threadIdx.x;
    deg[i] = rsqrtf(deg[i] + 1.0f);   // +1 self loop; deg>=1 always
}

__global__ void k_adj_edges(const int* __restrict__ srcL, const int* __restrict__ dstL,
                            const float* __restrict__ dinv, float* __restrict__ A) {
    int e = blockIdx.x * 256 + threadIdx.x;
    int g = e >> 11;
    int s = srcL[e], d = dstL[e];
    float nrm = dinv[(g << 7) + s] * dinv[(g << 7) + d];
    // duplicates of (s,d) add identical values -> order-independent rounding
    atomicAdd(&A[((long)g << 14) + (d << 7) + s], nrm);
}

__global__ void k_adj_diag(const float* __restrict__ dinv, float* __restrict__ A) {
    int i = blockIdx.x * 256 + threadIdx.x;  // node
    int g = i >> 7, l = i & 127;
    A[((long)g << 14) + (l << 7) + l] += dinv[i] * dinv[i];
}

// ---------------- generic tiled GEMM (f32) ----------------
// C[M x Nc] = A[M x K] @ B[K x Nc]   (TRANSB: B is [Nc x K], use B^T)
// EPI: 0 none, 1 +bias, 2 +bias+relu.  M,Nc multiples of 64; K multiple of 16.
template <bool TRANSB, int EPI>
__global__ __launch_bounds__(256)
void k_gemm(const float* __restrict__ A, const float* __restrict__ Bm,
            const float* __restrict__ bias, float* __restrict__ C,
            int M, int Nc, int K, long sA_, long sB_, long sC_) {
    int g = blockIdx.z;
    A += (long)g * sA_; Bm += (long)g * sB_; C += (long)g * sC_;
    __shared__ float sA[16][65];
    __shared__ float sB[16][65];
    int m0 = blockIdx.y * 64, n0 = blockIdx.x * 64;
    int t = threadIdx.x;
    int ty = t >> 4, tx = t & 15;
    float acc[4][4] = {};
    for (int k0 = 0; k0 < K; k0 += 16) {
        {   // A tile: 64 rows x 16 k
            int l = t * 4;
            int row = l >> 4, kk = l & 15;
#pragma unroll
            for (int i = 0; i < 4; ++i)
                sA[kk + i][row] = A[(long)(m0 + row) * K + k0 + kk + i];
        }
        if (!TRANSB) {   // B tile: 16 k x 64 cols
            int l = t * 4;
            int kk = l >> 6, col = l & 63;
#pragma unroll
            for (int i = 0; i < 4; ++i)
                sB[kk][col + i] = Bm[(long)(k0 + kk) * Nc + n0 + col + i];
        } else {         // sB[kk][col] = B[n0+col][k0+kk]
            int l = t * 4;
            int col = l >> 4, kk = l & 15;
#pragma unroll
            for (int i = 0; i < 4; ++i)
                sB[kk + i][col] = Bm[(long)(n0 + col) * K + k0 + kk + i];
        }
        __syncthreads();
#pragma unroll
        for (int kk = 0; kk < 16; ++kk) {
            float a[4], b[4];
#pragma unroll
            for (int i = 0; i < 4; ++i) a[i] = sA[kk][ty * 4 + i];
#pragma unroll
            for (int j = 0; j < 4; ++j) b[j] = sB[kk][tx * 4 + j];
#pragma unroll
            for (int i = 0; i < 4; ++i)
#pragma unroll
                for (int j = 0; j < 4; ++j) acc[i][j] += a[i] * b[j];
        }
        __syncthreads();
    }
#pragma unroll
    for (int i = 0; i < 4; ++i) {
        int m = m0 + ty * 4 + i;
#pragma unroll
        for (int j = 0; j < 4; ++j) {
            int n = n0 + tx * 4 + j;
            float v = acc[i][j];
            if (EPI >= 1) v += bias[n];
            if (EPI == 2) v = fmaxf(v, 0.f);
            C[(long)m * Nc + n] = v;
        }
    }
}

// ---------------- batchnorm (deterministic two-phase) ----------------
// part: [256 blocks][512] (sum[256], sumsq[256]);  stats: mean[256], rstd[256]
__global__ void k_bnpart(const float* __restrict__ X, float* __restrict__ part) {
    int t = threadIdx.x;
    long r0 = (long)blockIdx.x * 128;
    float s = 0.f, s2 = 0.f;
    for (int r = 0; r < 128; ++r) {
        float v = X[(r0 + r) * 256 + t];   // coalesced: consecutive t
        s += v; s2 += v * v;
    }
    part[blockIdx.x * 512 + t]       = s;
    part[blockIdx.x * 512 + 256 + t] = s2;
}

__global__ void k_bnfin(const float* __restrict__ part, float* __restrict__ stats) {
    int t = threadIdx.x;
    float s = 0.f, s2 = 0.f;
    for (int b = 0; b < 256; ++b) {        // fixed order -> deterministic
        s  += part[b * 512 + t];
        s2 += part[b * 512 + 256 + t];
    }
    float m = s / (float)NN;
    float var = s2 / (float)NN - m * m;
    stats[t]       = m;
    stats[256 + t] = rsqrtf(var + 1e-5f);
}

// MODE 0: plain BN.  MODE 1: relu(relu(BN(x)) + res)
template <int MODE>
__global__ void k_apply(const float* __restrict__ X, const float* __restrict__ stats,
                        const float* __restrict__ gam, const float* __restrict__ bet,
                        const float* __restrict__ res, float* __restrict__ Zo) {
    long i = (long)blockIdx.x * 256 + threadIdx.x;
    int c = (int)(i & 255);
    float v = (X[i] - stats[c]) * stats[256 + c] * gam[c] + bet[c];
    if (MODE == 1) {
        v = fmaxf(v, 0.f) + res[i];
        v = fmaxf(v, 0.f);
    }
    Zo[i] = v;
}

// ---------------- misc ----------------
__global__ void k_l2norm(const float* __restrict__ Z, float* __restrict__ Zn,
                         float* __restrict__ outz) {
    int r = blockIdx.x, c = threadIdx.x;
    long i = (long)r * 256 + c;
    float v = Z[i];
    float s = v * v;
#pragma unroll
    for (int o = 32; o > 0; o >>= 1) s += __shfl_down(s, o);
    __shared__ float red[4];
    __shared__ float denom;
    int lane = c & 63, wid = c >> 6;
    if (lane == 0) red[wid] = s;
    __syncthreads();
    if (c == 0) denom = fmaxf(sqrtf(red[0] + red[1] + red[2] + red[3]), 1e-12f);
    __syncthreads();
    float o = v / denom;
    Zn[i] = o;
    outz[i] = o;
}

__global__ void k_sigdiag(const float* __restrict__ S, float* __restrict__ O) {
    long i = (long)blockIdx.x * 256 + threadIdx.x;
    int r = (int)((i >> 7) & 127);
    int c = (int)(i & 127);
    float v = 1.f / (1.f + __expf(-S[i]));
    if (r == c) v = 0.f;
    O[i] = v;
}

__global__ void k_pool(const float* __restrict__ Zn, float* __restrict__ outzg) {
    int g = blockIdx.x, c = threadIdx.x;
    const float* p = Zn + (long)g * MX * 256 + c;
    float m = -3.4e38f;
    for (int r = 0; r < MX; ++r) m = fmaxf(m, p[(long)r * 256]);
    outzg[g * 256 + c] = m;
}

// ---------------- host ----------------
template <bool TRANSB, int EPI>
static void gemm(hipStream_t s, const float* A, const float* Bm, const float* bias,
                 float* C, int M, int Nc, int K, int batch, long sA, long sB, long sC) {
    dim3 g(Nc / 64, M / 64, batch), b(256);
    k_gemm<TRANSB, EPI><<<g, b, 0, s>>>(A, Bm, bias, C, M, Nc, K, sA, sB, sC);
}

static void bn(hipStream_t s, const float* X, float* part, float* stats) {
    k_bnpart<<<256, 256, 0, s>>>(X, part);
    k_bnfin<<<1, 256, 0, s>>>(part, stats);
}

extern "C" void kernel_launch(void* const* d_in, const int* in_sizes, int n_in,
                              void* d_out, int out_size, void* d_ws, size_t ws_size,
                              hipStream_t stream) {
    const float* x      = (const float*)d_in[0];
    const int*   srcL   = (const int*)d_in[1];
    const int*   dstL   = (const int*)d_in[2];
    const float* gcn_w0 = (const float*)d_in[3];
    const float* bn_g0  = (const float*)d_in[5];
    const float* bn_b0  = (const float*)d_in[6];
    const float* gcn_w1 = (const float*)d_in[7];
    const float* bn_g1  = (const float*)d_in[9];
    const float* bn_b1  = (const float*)d_in[10];
    const float* gcn_w2 = (const float*)d_in[11];
    const float* bn_g2  = (const float*)d_in[13];
    const float* bn_b2  = (const float*)d_in[14];
    const float* sc_w0  = (const float*)d_in[15];
    const float* sc_b0  = (const float*)d_in[16];
    const float* edge_w = (const float*)d_in[17];
    const float* fd_w0  = (const float*)d_in[18];
    const float* fd_b0  = (const float*)d_in[19];
    const float* fd_g0  = (const float*)d_in[20];
    const float* fd_be0 = (const float*)d_in[21];
    const float* fd_w1  = (const float*)d_in[22];
    const float* fd_b1  = (const float*)d_in[23];
    const float* fd_g1  = (const float*)d_in[24];
    const float* fd_be1 = (const float*)d_in[25];
    const float* fd_w2  = (const float*)d_in[26];
    const float* fd_b2  = (const float*)d_in[27];
    const float* ph_w0  = (const float*)d_in[28];
    const float* ph_b0  = (const float*)d_in[29];
    const float* ph_w1  = (const float*)d_in[30];
    const float* ph_b1  = (const float*)d_in[31];

    float* out     = (float*)d_out;
    float* out_z   = out;                    // 32768*256
    float* out_adj = out + 8388608;          // 256*128*128
    float* out_xr  = out + 12582912;         // 32768*128
    float* out_zg  = out + 16777216;         // 256*256
    float* out_zgm = out + 16842752;         // 256*256

    float* w     = (float*)d_ws;
    float* deg   = w;                        // 32768
    float* part  = deg + 32768;              // 131072
    float* stats = part + 131072;            // 512
    float* P1    = stats + 512;              // 65536
    float* Aadj  = P1 + 65536;               // 4,194,304  (B x 128 x 128)
    float* B1    = Aadj + 4194304;           // 8,388,608  (N x 256)
    float* B2    = B1 + 8388608;             // 8,388,608
    float* B3    = B2 + 8388608;             // 8,388,608
    // total = 29,590,528 floats = 118.4 MB

    // --- adjacency ---
    hipMemsetAsync(deg, 0, 32768 * 4, stream);
    k_deg<<<2048, 256, 0, stream>>>(dstL, deg);
    k_dinv<<<128, 256, 0, stream>>>(deg);
    hipMemsetAsync(Aadj, 0, (size_t)4194304 * 4, stream);
    k_adj_edges<<<2048, 256, 0, stream>>>(srcL, dstL, deg, Aadj);
    k_adj_diag<<<128, 256, 0, stream>>>(deg, Aadj);

    // --- layer 0 ---  (gcn bias is zero in setup; BN cancels it anyway)
    gemm<false, 0>(stream, x, gcn_w0, nullptr, B1, NN, HD, FDI, 1, 0, 0, 0);
    gemm<false, 1>(stream, x, sc_w0, sc_b0, B3, NN, HD, FDI, 1, 0, 0, 0);     // residual
    gemm<false, 0>(stream, Aadj, B1, nullptr, B2, MX, HD, MX, NB, 16384, 32768, 32768);
    bn(stream, B2, part, stats);
    k_apply<1><<<32768, 256, 0, stream>>>(B2, stats, bn_g0, bn_b0, B3, B2);   // Z0 in B2

    // --- layer 1 ---
    gemm<false, 0>(stream, B2, gcn_w1, nullptr, B1, NN, HD, HD, 1, 0, 0, 0);
    gemm<false, 0>(stream, Aadj, B1, nullptr, B3, MX, HD, MX, NB, 16384, 32768, 32768);
    bn(stream, B3, part, stats);
    k_apply<1><<<32768, 256, 0, stream>>>(B3, stats, bn_g1, bn_b1, B2, B3);   // Z1 in B3

    // --- layer 2 ---
    gemm<false, 0>(stream, B3, gcn_w2, nullptr, B1, NN, HD, HD, 1, 0, 0, 0);
    gemm<false, 0>(stream, Aadj, B1, nullptr, B2, MX, HD, MX, NB, 16384, 32768, 32768);
    bn(stream, B2, part, stats);
    k_apply<1><<<32768, 256, 0, stream>>>(B2, stats, bn_g2, bn_b2, B3, B2);   // Z2 in B2

    // --- L2 normalize -> Znorm in B3, also writes z output ---
    k_l2norm<<<32768, 256, 0, stream>>>(B2, B3, out_z);

    // --- edge decoder: adj = sigmoid(Z W Z^T), zero diag ---
    gemm<false, 0>(stream, B3, edge_w, nullptr, B1, NN, HD, HD, 1, 0, 0, 0);
    gemm<true, 0>(stream, B1, B3, nullptr, B2, MX, MX, HD, NB, 32768, 32768, 16384);
    k_sigdiag<<<16384, 256, 0, stream>>>(B2, out_adj);

    // --- feature decoder ---
    gemm<false, 2>(stream, B3, fd_w0, fd_b0, B1, NN, HD, HD, 1, 0, 0, 0);
    bn(stream, B1, part, stats);
    k_apply<0><<<32768, 256, 0, stream>>>(B1, stats, fd_g0, fd_be0, nullptr, B1);

    gemm<false, 2>(stream, B1, fd_w1, fd_b1, B2, NN, HD, HD, 1, 0, 0, 0);
    bn(stream, B2, part, stats);
    k_apply<0><<<32768, 256, 0, stream>>>(B2, stats, fd_g1, fd_be1, nullptr, B2);

    gemm<false, 1>(stream, B2, fd_w2, fd_b2, out_xr, NN, FDI, HD, 1, 0, 0, 0);

    // --- pooling head ---
    k_pool<<<256, 256, 0, stream>>>(B3, out_zg);
    gemm<false, 2>(stream, out_zg, ph_w0, ph_b0, P1, 256, 256, 256, 1, 0, 0, 0);
    gemm<false, 1>(stream, P1, ph_w1, ph_b1, out_zgm, 256, 256, 256, 1, 0, 0, 0);
}

// Round 3
// 444.679 us; speedup vs baseline: 2.4182x; 2.4182x over previous
//
#include <hip/hip_runtime.h>
#include <hip/hip_bf16.h>

using bf = __hip_bfloat16;
typedef __attribute__((ext_vector_type(8))) short s8;
typedef __attribute__((ext_vector_type(4))) float f4;

constexpr int NN  = 32768;
constexpr int HD  = 256;
constexpr int MX  = 128;

__device__ __forceinline__ float bf2f(bf b) {
    unsigned short h = *reinterpret_cast<unsigned short*>(&b);
    union { unsigned u; float f; } x; x.u = ((unsigned)h) << 16;
    return x.f;
}
__device__ __forceinline__ float u2f(unsigned short h) {
    union { unsigned u; float f; } x; x.u = ((unsigned)h) << 16;
    return x.f;
}
__device__ __forceinline__ bf f2bf(float f) {
    union { float f; unsigned u; } x; x.f = f;
    unsigned r = x.u + 0x7FFF + ((x.u >> 16) & 1);
    unsigned short h = (unsigned short)(r >> 16);
    return *reinterpret_cast<bf*>(&h);
}
__device__ __forceinline__ unsigned short f2u(float f) {
    union { float f; unsigned u; } x; x.f = f;
    unsigned r = x.u + 0x7FFF + ((x.u >> 16) & 1);
    return (unsigned short)(r >> 16);
}

// ---------------- adjacency build ----------------
__global__ void k_deg(const int* __restrict__ dstL, float* __restrict__ deg) {
    int e = blockIdx.x * 256 + threadIdx.x;
    int g = e >> 11;
    atomicAdd(&deg[(g << 7) + dstL[e]], 1.0f);
}
__global__ void k_dinv(float* __restrict__ deg) {
    int i = blockIdx.x * 256 + threadIdx.x;
    deg[i] = rsqrtf(deg[i] + 1.0f);
}
__global__ void k_adj_edges(const int* __restrict__ srcL, const int* __restrict__ dstL,
                            const float* __restrict__ dinv, float* __restrict__ A) {
    int e = blockIdx.x * 256 + threadIdx.x;
    int g = e >> 11;
    int s = srcL[e], d = dstL[e];
    float nrm = dinv[(g << 7) + s] * dinv[(g << 7) + d];
    atomicAdd(&A[((long)g << 14) + (d << 7) + s], nrm);
}
__global__ void k_adj_diag(const float* __restrict__ dinv, float* __restrict__ A) {
    int i = blockIdx.x * 256 + threadIdx.x;
    int g = i >> 7, l = i & 127;
    A[((long)g << 14) + (l << 7) + l] += dinv[i] * dinv[i];
}

// ---------------- f32 -> bf16 convert ----------------
__global__ void k_cvt(const float* __restrict__ X, bf* __restrict__ O) {
    long i = (long)blockIdx.x * 256 + threadIdx.x;
    O[i] = f2bf(X[i]);
}

// ---------------- weight transpose f32 [K x N] -> bf16 [N x K] ----------------
struct WTd { const float* src; int K, N, off; };
struct WTpack { WTd w[10]; };
__global__ void k_wt(WTpack p, bf* __restrict__ out) {
    WTd d = p.w[blockIdx.z];
    int n0 = blockIdx.x * 64, k0 = blockIdx.y * 64;
    if (n0 >= d.N || k0 >= d.K) return;
    __shared__ float s[64][65];
    int t = threadIdx.x;
    int cc = t & 63, rq = t >> 6;
#pragma unroll
    for (int i = 0; i < 16; ++i) {
        int r = i * 4 + rq;
        s[r][cc] = d.src[(long)(k0 + r) * d.N + n0 + cc];
    }
    __syncthreads();
#pragma unroll
    for (int i = 0; i < 16; ++i) {
        int r = i * 4 + rq;
        out[d.off + (long)(n0 + r) * d.K + k0 + cc] = f2bf(s[cc][r]);
    }
}

// ---------------- per-graph transpose H[g][128][256] -> HT[g][256][128] ----------------
__global__ void k_tr(const bf* __restrict__ H, bf* __restrict__ HT) {
    __shared__ bf s[64][65];
    int g = blockIdx.z;
    int r0 = blockIdx.y * 64, c0 = blockIdx.x * 64;
    int t = threadIdx.x;
    int cc = t & 63, rq = t >> 6;
    const bf* src = H + (long)g * 32768;
#pragma unroll
    for (int i = 0; i < 16; ++i) {
        int r = i * 4 + rq;
        s[r][cc] = src[(long)(r0 + r) * 256 + c0 + cc];
    }
    __syncthreads();
    bf* dst = HT + (long)g * 32768;
#pragma unroll
    for (int i = 0; i < 16; ++i) {
        int r = i * 4 + rq;
        dst[(long)(c0 + r) * 128 + r0 + cc] = s[cc][r];
    }
}

// ---------------- MFMA GEMM ----------------
// C[M x N] = A[M x K] @ BT[N x K]^T ; A,BT bf16 row-major; tiles 128x128, BK=32.
// EPI: 0 none, 1 +bias, 2 +bias+relu, 3 sigmoid+zero-diag(row==col).
constexpr int LP = 40;  // padded LDS row (bf16): 80 B, 16B-aligned rows
template <int EPI, bool WF, bool WB>
__global__ __launch_bounds__(256) void mg(
    const bf* __restrict__ A, const bf* __restrict__ BT,
    const float* __restrict__ bias, float* __restrict__ Cf, bf* __restrict__ Cb,
    int M, int N, int K, long sA, long sB, long sC, int ldc) {
    __shared__ __align__(16) bf sA_[128 * LP];
    __shared__ __align__(16) bf sB_[128 * LP];
    const int g = blockIdx.z;
    const int m0 = blockIdx.y * 128, n0 = blockIdx.x * 128;
    const bf* Ab = A + (long)g * sA + (long)m0 * K;
    const bf* Bb = BT + (long)g * sB + (long)n0 * K;
    const int t = threadIdx.x;
    const int lane = t & 63;
    const int w = t >> 6;
    const int wm = (w >> 1) * 64, wn = (w & 1) * 64;
    const int fr16 = lane & 15, kq = lane >> 4;
    f4 acc[4][4] = {};
    for (int k0 = 0; k0 < K; k0 += 32) {
#pragma unroll
        for (int i = 0; i < 2; ++i) {
            int e = i * 256 + t;
            int row = e >> 2, sl = e & 3;
            *(s8*)&sA_[row * LP + sl * 8] = *(const s8*)&Ab[(long)row * K + k0 + sl * 8];
            *(s8*)&sB_[row * LP + sl * 8] = *(const s8*)&Bb[(long)row * K + k0 + sl * 8];
        }
        __syncthreads();
        s8 af[4], bg[4];
#pragma unroll
        for (int f = 0; f < 4; ++f) {
            af[f] = *(const s8*)&sA_[(wm + f * 16 + fr16) * LP + kq * 8];
            bg[f] = *(const s8*)&sB_[(wn + f * 16 + fr16) * LP + kq * 8];
        }
#pragma unroll
        for (int fr = 0; fr < 4; ++fr)
#pragma unroll
            for (int fc = 0; fc < 4; ++fc)
                acc[fr][fc] = __builtin_amdgcn_mfma_f32_16x16x32_bf16(
                    af[fr], bg[fc], acc[fr][fc], 0, 0, 0);
        __syncthreads();
    }
#pragma unroll
    for (int fr = 0; fr < 4; ++fr) {
        int rowb = m0 + wm + fr * 16 + (lane >> 4) * 4;
#pragma unroll
        for (int fc = 0; fc < 4; ++fc) {
            int col = n0 + wn + fc * 16 + (lane & 15);
            float bv = (EPI == 1 || EPI == 2) ? bias[col] : 0.f;
#pragma unroll
            for (int i = 0; i < 4; ++i) {
                float v = acc[fr][fc][i];
                int r = rowb + i;
                if (EPI == 1 || EPI == 2) v += bv;
                if (EPI == 2) v = fmaxf(v, 0.f);
                if (EPI == 3) {
                    v = 1.f / (1.f + __expf(-v));
                    if (r == col) v = 0.f;
                }
                long o = (long)g * sC + (long)r * ldc + col;
                if (WF) Cf[o] = v;
                if (WB) Cb[o] = f2bf(v);
            }
        }
    }
}

// ---------------- batchnorm (deterministic two-phase, bf16 input) ----------------
__global__ void k_bnpart(const bf* __restrict__ X, float* __restrict__ part) {
    int t = threadIdx.x;
    long r0 = (long)blockIdx.x * 128;
    float s = 0.f, s2 = 0.f;
    for (int r = 0; r < 128; ++r) {
        float v = bf2f(X[(r0 + r) * 256 + t]);
        s += v; s2 += v * v;
    }
    part[blockIdx.x * 512 + t]       = s;
    part[blockIdx.x * 512 + 256 + t] = s2;
}
__global__ void k_bnfin(const float* __restrict__ part, float* __restrict__ stats) {
    int t = threadIdx.x;
    float s = 0.f, s2 = 0.f;
    for (int b = 0; b < 256; ++b) {
        s  += part[b * 512 + t];
        s2 += part[b * 512 + 256 + t];
    }
    float m = s / (float)NN;
    float var = s2 / (float)NN - m * m;
    stats[t]       = m;
    stats[256 + t] = rsqrtf(var + 1e-5f);
}

// MODE 0: BN only (in-place ok). MODE 1: relu(relu(BN(x)) + res)
template <int MODE>
__global__ void k_apply(const bf* __restrict__ X, const float* __restrict__ stats,
                        const float* __restrict__ gam, const float* __restrict__ bet,
                        const bf* __restrict__ res, bf* __restrict__ Z) {
    long i4 = ((long)blockIdx.x * 256 + threadIdx.x) * 4;
    int c0 = (int)(i4 & 255);
    ushort4 xv = *(const ushort4*)(X + i4);
    ushort4 rv;
    if (MODE == 1) rv = *(const ushort4*)(res + i4);
    unsigned short xs[4] = {xv.x, xv.y, xv.z, xv.w};
    unsigned short rs[4];
    if (MODE == 1) { rs[0] = rv.x; rs[1] = rv.y; rs[2] = rv.z; rs[3] = rv.w; }
    unsigned short o[4];
#pragma unroll
    for (int j = 0; j < 4; ++j) {
        int c = c0 + j;
        float v = (u2f(xs[j]) - stats[c]) * stats[256 + c] * gam[c] + bet[c];
        if (MODE == 1) {
            v = fmaxf(v, 0.f) + u2f(rs[j]);
            v = fmaxf(v, 0.f);
        }
        o[j] = f2u(v);
    }
    *(ushort4*)(Z + i4) = make_ushort4(o[0], o[1], o[2], o[3]);
}

// ---------------- l2 normalize, pool ----------------
__global__ void k_l2norm(const bf* __restrict__ Z, float* __restrict__ outz,
                         bf* __restrict__ Znb) {
    int r = blockIdx.x, c = threadIdx.x;
    long i = (long)r * 256 + c;
    float v = bf2f(Z[i]);
    float s = v * v;
#pragma unroll
    for (int o = 32; o > 0; o >>= 1) s += __shfl_down(s, o);
    __shared__ float red[4];
    __shared__ float denom;
    int lane = c & 63, wid = c >> 6;
    if (lane == 0) red[wid] = s;
    __syncthreads();
    if (c == 0) denom = fmaxf(sqrtf(red[0] + red[1] + red[2] + red[3]), 1e-12f);
    __syncthreads();
    float o = v / denom;
    outz[i] = o;
    Znb[i] = f2bf(o);
}

__global__ void k_pool(const bf* __restrict__ Zn, float* __restrict__ outzg,
                       bf* __restrict__ ZGb) {
    int g = blockIdx.x, c = threadIdx.x;
    const bf* p = Zn + (long)g * 32768 + c;
    float m = -3.4e38f;
    for (int r = 0; r < 128; ++r) m = fmaxf(m, bf2f(p[(long)r * 256]));
    outzg[g * 256 + c] = m;
    ZGb[g * 256 + c] = f2bf(m);
}

// ---------------- host ----------------
template <int EPI, bool WF, bool WB>
static void MG(hipStream_t st, const bf* A, const bf* BT, const float* bias,
               float* Cf, bf* Cb, int M, int N, int K, int batch,
               long sA, long sB, long sC, int ldc) {
    dim3 g(N / 128, M / 128, batch);
    mg<EPI, WF, WB><<<g, 256, 0, st>>>(A, BT, bias, Cf, Cb, M, N, K, sA, sB, sC, ldc);
}

extern "C" void kernel_launch(void* const* d_in, const int* in_sizes, int n_in,
                              void* d_out, int out_size, void* d_ws, size_t ws_size,
                              hipStream_t stream) {
    const float* x      = (const float*)d_in[0];
    const int*   srcL   = (const int*)d_in[1];
    const int*   dstL   = (const int*)d_in[2];
    const float* gcn_w0 = (const float*)d_in[3];
    const float* bn_g0  = (const float*)d_in[5];
    const float* bn_b0  = (const float*)d_in[6];
    const float* gcn_w1 = (const float*)d_in[7];
    const float* bn_g1  = (const float*)d_in[9];
    const float* bn_b1  = (const float*)d_in[10];
    const float* gcn_w2 = (const float*)d_in[11];
    const float* bn_g2  = (const float*)d_in[13];
    const float* bn_b2  = (const float*)d_in[14];
    const float* sc_w0  = (const float*)d_in[15];
    const float* sc_b0  = (const float*)d_in[16];
    const float* edge_w = (const float*)d_in[17];
    const float* fd_w0  = (const float*)d_in[18];
    const float* fd_b0  = (const float*)d_in[19];
    const float* fd_g0  = (const float*)d_in[20];
    const float* fd_be0 = (const float*)d_in[21];
    const float* fd_w1  = (const float*)d_in[22];
    const float* fd_b1  = (const float*)d_in[23];
    const float* fd_g1  = (const float*)d_in[24];
    const float* fd_be1 = (const float*)d_in[25];
    const float* fd_w2  = (const float*)d_in[26];
    const float* fd_b2  = (const float*)d_in[27];
    const float* ph_w0  = (const float*)d_in[28];
    const float* ph_b0  = (const float*)d_in[29];
    const float* ph_w1  = (const float*)d_in[30];
    const float* ph_b1  = (const float*)d_in[31];

    float* out     = (float*)d_out;
    float* out_z   = out;
    float* out_adj = out + 8388608;
    float* out_xr  = out + 12582912;
    float* out_zg  = out + 16777216;
    float* out_zgm = out + 16842752;

    // workspace map (f32 words)
    float* w      = (float*)d_ws;
    float* deg    = w;                       // 32768
    float* part   = deg + 32768;             // 131072
    float* stats  = part + 131072;           // 512
    bf*    wT     = (bf*)(stats + 512);      // 557056 bf16 (278528 w)
    bf*    xb     = (bf*)(w + 442880);       // 4194304 bf16
    bf*    Aadjb  = (bf*)(w + 2540032);      // 4194304 bf16
    float* AadjF  = w + 4637184;             // 4194304 f32 (aliases Hb region)
    bf*    Hb     = (bf*)(w + 4637184);      // 8388608 bf16 (after AadjF dead)
    bf*    HT     = (bf*)(w + 8831488);      // 8388608 bf16
    bf*    Zbb    = (bf*)(w + 13025792);     // 8388608 bf16 (also RESb)
    bf*    AGb    = (bf*)(w + 17220096);     // 8388608 bf16 (also Znb)
    bf*    Zba    = (bf*)(w + 21414400);     // 8388608 bf16
    bf*    ZGb    = (bf*)(w + 25608704);     // 65536 bf16
    bf*    P1b    = (bf*)(w + 25641472);     // 65536 bf16
    bf*    RESb   = Zbb;
    bf*    Znb    = AGb;
    bf*    Eb     = Hb;

    // weight transpose offsets (bf16 elements within wT)
    WTpack pk;
    pk.w[0] = {gcn_w0, 128, 256, 0};
    pk.w[1] = {sc_w0,  128, 256, 32768};
    pk.w[2] = {gcn_w1, 256, 256, 65536};
    pk.w[3] = {gcn_w2, 256, 256, 131072};
    pk.w[4] = {edge_w, 256, 256, 196608};
    pk.w[5] = {fd_w0,  256, 256, 262144};
    pk.w[6] = {fd_w1,  256, 256, 327680};
    pk.w[7] = {fd_w2,  256, 128, 393216};
    pk.w[8] = {ph_w0,  256, 256, 425984};
    pk.w[9] = {ph_w1,  256, 256, 491520};

    // --- adjacency ---
    hipMemsetAsync(deg, 0, 32768 * 4, stream);
    k_deg<<<2048, 256, 0, stream>>>(dstL, deg);
    k_dinv<<<128, 256, 0, stream>>>(deg);
    hipMemsetAsync(AadjF, 0, (size_t)4194304 * 4, stream);
    k_adj_edges<<<2048, 256, 0, stream>>>(srcL, dstL, deg, AadjF);
    k_adj_diag<<<128, 256, 0, stream>>>(deg, AadjF);
    k_cvt<<<16384, 256, 0, stream>>>(AadjF, Aadjb);

    // --- preconvert x, weights ---
    k_cvt<<<16384, 256, 0, stream>>>(x, xb);
    k_wt<<<dim3(4, 4, 10), 256, 0, stream>>>(pk, wT);

    // --- layer 0 ---
    MG<0,false,true>(stream, xb, wT + 0, nullptr, nullptr, Hb, NN, HD, 128, 1, 0,0,0, 256);
    MG<1,false,true>(stream, xb, wT + 32768, sc_b0, nullptr, RESb, NN, HD, 128, 1, 0,0,0, 256);
    k_tr<<<dim3(4, 2, 256), 256, 0, stream>>>(Hb, HT);
    MG<0,false,true>(stream, Aadjb, HT, nullptr, nullptr, AGb, MX, HD, 128, 256,
                     16384, 32768, 32768, 256);
    k_bnpart<<<256, 256, 0, stream>>>(AGb, part);
    k_bnfin<<<1, 256, 0, stream>>>(part, stats);
    k_apply<1><<<8192, 256, 0, stream>>>(AGb, stats, bn_g0, bn_b0, RESb, Zba);

    // --- layer 1 ---
    MG<0,false,true>(stream, Zba, wT + 65536, nullptr, nullptr, Hb, NN, HD, HD, 1, 0,0,0, 256);
    k_tr<<<dim3(4, 2, 256), 256, 0, stream>>>(Hb, HT);
    MG<0,false,true>(stream, Aadjb, HT, nullptr, nullptr, AGb, MX, HD, 128, 256,
                     16384, 32768, 32768, 256);
    k_bnpart<<<256, 256, 0, stream>>>(AGb, part);
    k_bnfin<<<1, 256, 0, stream>>>(part, stats);
    k_apply<1><<<8192, 256, 0, stream>>>(AGb, stats, bn_g1, bn_b1, Zba, Zbb);

    // --- layer 2 ---
    MG<0,false,true>(stream, Zbb, wT + 131072, nullptr, nullptr, Hb, NN, HD, HD, 1, 0,0,0, 256);
    k_tr<<<dim3(4, 2, 256), 256, 0, stream>>>(Hb, HT);
    MG<0,false,true>(stream, Aadjb, HT, nullptr, nullptr, AGb, MX, HD, 128, 256,
                     16384, 32768, 32768, 256);
    k_bnpart<<<256, 256, 0, stream>>>(AGb, part);
    k_bnfin<<<1, 256, 0, stream>>>(part, stats);
    k_apply<1><<<8192, 256, 0, stream>>>(AGb, stats, bn_g2, bn_b2, Zbb, Zba);

    // --- L2 normalize (Zba -> out_z f32, Znb bf16) ---
    k_l2norm<<<32768, 256, 0, stream>>>(Zba, out_z, Znb);

    // --- edge decoder ---
    MG<0,false,true>(stream, Znb, wT + 196608, nullptr, nullptr, Eb, NN, HD, HD, 1, 0,0,0, 256);
    MG<3,true,false>(stream, Eb, Znb, nullptr, out_adj, nullptr, MX, MX, HD, 256,
                     32768, 32768, 16384, 128);

    // --- feature decoder ---
    MG<2,false,true>(stream, Znb, wT + 262144, fd_b0, nullptr, Zbb, NN, HD, HD, 1, 0,0,0, 256);
    k_bnpart<<<256, 256, 0, stream>>>(Zbb, part);
    k_bnfin<<<1, 256, 0, stream>>>(part, stats);
    k_apply<0><<<8192, 256, 0, stream>>>(Zbb, stats, fd_g0, fd_be0, nullptr, Zbb);

    MG<2,false,true>(stream, Zbb, wT + 327680, fd_b1, nullptr, Zba, NN, HD, HD, 1, 0,0,0, 256);
    k_bnpart<<<256, 256, 0, stream>>>(Zba, part);
    k_bnfin<<<1, 256, 0, stream>>>(part, stats);
    k_apply<0><<<8192, 256, 0, stream>>>(Zba, stats, fd_g1, fd_be1, nullptr, Zba);

    MG<1,true,false>(stream, Zba, wT + 393216, fd_b2, out_xr, nullptr, NN, 128, HD, 1,
                     0,0,0, 128);

    // --- pooling head ---
    k_pool<<<256, 256, 0, stream>>>(Znb, out_zg, ZGb);
    MG<2,false,true>(stream, ZGb, wT + 425984, ph_b0, nullptr, P1b, 256, 256, 256, 1,
                     0,0,0, 256);
    MG<1,true,false>(stream, P1b, wT + 491520, ph_b1, out_zgm, nullptr, 256, 256, 256, 1,
                     0,0,0, 256);
}

// Round 5
// 307.451 us; speedup vs baseline: 3.4975x; 1.4463x over previous
//
#include <hip/hip_runtime.h>
#include <hip/hip_bf16.h>

using bf = __hip_bfloat16;
typedef __attribute__((ext_vector_type(8))) short s8;
typedef __attribute__((ext_vector_type(4))) float f4;

constexpr int NN  = 32768;
constexpr int HD  = 256;

__device__ __forceinline__ float u2f(unsigned short h) {
    union { unsigned u; float f; } x; x.u = ((unsigned)h) << 16;
    return x.f;
}
__device__ __forceinline__ unsigned short f2u(float f) {
    union { float f; unsigned u; } x; x.f = f;
    unsigned r = x.u + 0x7FFF + ((x.u >> 16) & 1);
    return (unsigned short)(r >> 16);
}
__device__ __forceinline__ bf f2bf(float f) {
    unsigned short h = f2u(f);
    return *reinterpret_cast<bf*>(&h);
}
__device__ __forceinline__ float bf2f(bf b) {
    return u2f(*reinterpret_cast<unsigned short*>(&b));
}

// ---------------- adjacency build: one kernel, all in LDS ----------------
__global__ __launch_bounds__(256) void k_adj(const int* __restrict__ srcL,
                                             const int* __restrict__ dstL,
                                             float* __restrict__ A) {
    __shared__ float sT[128 * 64];   // 32KB: [dst][src-half]
    __shared__ float sdin[128];
    int g = blockIdx.x, t = threadIdx.x;
    const int* sg = srcL + (g << 11);
    const int* dg = dstL + (g << 11);
    if (t < 128) sdin[t] = 0.f;
    __syncthreads();
    for (int e = t; e < 2048; e += 256) atomicAdd(&sdin[dg[e]], 1.0f);
    __syncthreads();
    if (t < 128) sdin[t] = rsqrtf(sdin[t] + 1.0f);
    __syncthreads();
    float* out = A + ((long)g << 14);
    for (int half = 0; half < 2; ++half) {
        for (int i = t; i < 8192; i += 256) sT[i] = 0.f;
        __syncthreads();
        for (int e = t; e < 2048; e += 256) {
            int s = sg[e], d = dg[e];
            if ((s >> 6) == half)
                atomicAdd(&sT[(d << 6) + (s & 63)], sdin[s] * sdin[d]);
        }
        __syncthreads();
        if (t < 128 && (t >> 6) == half)
            sT[(t << 6) + (t & 63)] += sdin[t] * sdin[t];
        __syncthreads();
        for (int i4 = t; i4 < 2048; i4 += 256) {
            int d = i4 >> 4, c4 = (i4 & 15) * 4;
            *(float4*)&out[(d << 7) + (half << 6) + c4] = *(float4*)&sT[(d << 6) + c4];
        }
        __syncthreads();
    }
}

// ---------------- weight transpose f32 [K x N] -> bf16 [N x K] ----------------
struct WTd { const float* src; int K, N, off; };
struct WTpack { WTd w[10]; };
__global__ void k_wt(WTpack p, bf* __restrict__ out) {
    WTd d = p.w[blockIdx.z];
    int n0 = blockIdx.x * 64, k0 = blockIdx.y * 64;
    if (n0 >= d.N || k0 >= d.K) return;
    __shared__ float s[64][65];
    int t = threadIdx.x;
    int cc = t & 63, rq = t >> 6;
#pragma unroll
    for (int i = 0; i < 16; ++i) {
        int r = i * 4 + rq;
        s[r][cc] = d.src[(long)(k0 + r) * d.N + n0 + cc];
    }
    __syncthreads();
#pragma unroll
    for (int i = 0; i < 16; ++i) {
        int r = i * 4 + rq;
        out[d.off + (long)(n0 + r) * d.K + k0 + cc] = f2bf(s[cc][r]);
    }
}

// ---------------- MFMA GEMM ----------------
// C[M x N] = A[M x K] @ BT[N x K]^T.  Tiles 128x128, BK=64, 4 waves (2x2 of 64x64).
// TA: float (convert on stage) or bf.  EPI: 0 none,1 +bias,2 +bias+relu,3 sigmoid+zerodiag.
// OUT: 0 f32 row-major, 1 bf16 row-major, 2 bf16 per-graph-transposed HT[g][256][128].
// PART: fused per-block column sum/sumsq partials.
// BNA: apply batchnorm (stats+gam+bet) to A during staging.
__device__ __forceinline__ int swz(int row, int slot) {
    return row * 64 + ((slot ^ (row & 7)) << 3);   // element offset, 16B slots
}

template <typename TA, int EPI, int OUT, bool PART, bool BNA>
__global__ __launch_bounds__(256) void mg(
    const void* __restrict__ Av, const bf* __restrict__ BT,
    const float* __restrict__ bias,
    const float* __restrict__ bnstats, const float* __restrict__ bngam,
    const float* __restrict__ bnbet,
    float* __restrict__ Cf, bf* __restrict__ Cb, float* __restrict__ part,
    int M, int N, int K, long sA, long sB, long sC, int ldc) {
    constexpr bool AF32 = (sizeof(TA) == 4);
    __shared__ __align__(16) bf sAl[128 * 64];
    __shared__ __align__(16) bf sBl[128 * 64];
    const int g = blockIdx.z;
    const int m0 = blockIdx.y * 128, n0 = blockIdx.x * 128;
    const TA* Ab = (const TA*)Av + (long)g * sA + (long)m0 * K;
    const bf* Bb = BT + (long)g * sB + (long)n0 * K;
    const int t = threadIdx.x;
    const int lane = t & 63;
    const int w = t >> 6;
    const int wm = (w >> 1) * 64, wn = (w & 1) * 64;
    const int fr16 = lane & 15, kq = lane >> 4;
    f4 acc[4][4] = {};
    for (int k0 = 0; k0 < K; k0 += 64) {
#pragma unroll
        for (int i = 0; i < 4; ++i) {
            int sdx = i * 256 + t;
            int row = sdx >> 3, sl = sdx & 7;
            s8 av;
            if constexpr (AF32) {
                const float* src = (const float*)Ab + (long)row * K + k0 + sl * 8;
                float4 f0 = *(const float4*)src;
                float4 f1 = *(const float4*)(src + 4);
                float ff[8] = {f0.x, f0.y, f0.z, f0.w, f1.x, f1.y, f1.z, f1.w};
                unsigned short u[8];
#pragma unroll
                for (int j = 0; j < 8; ++j) u[j] = f2u(ff[j]);
                av = *(s8*)u;
            } else {
                av = *(const s8*)((const bf*)Ab + (long)row * K + k0 + sl * 8);
                if constexpr (BNA) {
                    unsigned short* u = (unsigned short*)&av;
#pragma unroll
                    for (int j = 0; j < 8; ++j) {
                        int c = k0 + sl * 8 + j;
                        float v = (u2f(u[j]) - bnstats[c]) * bnstats[256 + c] * bngam[c]
                                  + bnbet[c];
                        u[j] = f2u(v);
                    }
                }
            }
            *(s8*)&sAl[swz(row, sl)] = av;
            s8 bv = *(const s8*)&Bb[(long)row * K + k0 + sl * 8];
            *(s8*)&sBl[swz(row, sl)] = bv;
        }
        __syncthreads();
#pragma unroll
        for (int ks = 0; ks < 2; ++ks) {
            s8 af[4], bg[4];
#pragma unroll
            for (int f = 0; f < 4; ++f) {
                af[f] = *(const s8*)&sAl[swz(wm + f * 16 + fr16, kq + 4 * ks)];
                bg[f] = *(const s8*)&sBl[swz(wn + f * 16 + fr16, kq + 4 * ks)];
            }
#pragma unroll
            for (int fr = 0; fr < 4; ++fr)
#pragma unroll
                for (int fc = 0; fc < 4; ++fc)
                    acc[fr][fc] = __builtin_amdgcn_mfma_f32_16x16x32_bf16(
                        af[fr], bg[fc], acc[fr][fc], 0, 0, 0);
        }
        __syncthreads();
    }
    // ---------------- epilogue ----------------
    float ps[4], ps2[4];
    if (PART) {
#pragma unroll
        for (int fc = 0; fc < 4; ++fc) { ps[fc] = 0.f; ps2[fc] = 0.f; }
    }
#pragma unroll
    for (int fr = 0; fr < 4; ++fr) {
        int rl = wm + fr * 16 + (lane >> 4) * 4;       // local row base
#pragma unroll
        for (int fc = 0; fc < 4; ++fc) {
            int cl = wn + fc * 16 + (lane & 15);       // local col
            int col = n0 + cl;
            float bv = (EPI == 1 || EPI == 2) ? bias[col] : 0.f;
            unsigned short pk[4];
#pragma unroll
            for (int i = 0; i < 4; ++i) {
                float v = acc[fr][fc][i];
                if (EPI == 1 || EPI == 2) v += bv;
                if (EPI == 2) v = fmaxf(v, 0.f);
                if (EPI == 3) {
                    v = 1.f / (1.f + __expf(-v));
                    if (rl + i == col) v = 0.f;
                }
                if (PART) { ps[fc] += v; ps2[fc] += v * v; }
                if (OUT == 0) Cf[(long)g * sC + (long)(m0 + rl + i) * ldc + col] = v;
                if (OUT == 1) Cb[(long)g * sC + (long)(m0 + rl + i) * ldc + col] = f2bf(v);
                if (OUT == 2) pk[i] = f2u(v);
            }
            if (OUT == 2) {
                int gg = m0 >> 7;   // M-tile == one graph
                *(ushort4*)&Cb[(long)gg * 32768 + (long)col * 128 + rl] =
                    make_ushort4(pk[0], pk[1], pk[2], pk[3]);
            }
        }
    }
    if (PART) {
        __syncthreads();           // LDS free for scratch
        float* scr = (float*)sAl;  // [4 waves][2 stats][64 cols] = 2KB
#pragma unroll
        for (int fc = 0; fc < 4; ++fc) {
            ps[fc] += __shfl_xor(ps[fc], 16);  ps[fc] += __shfl_xor(ps[fc], 32);
            ps2[fc] += __shfl_xor(ps2[fc], 16); ps2[fc] += __shfl_xor(ps2[fc], 32);
        }
        if (lane < 16) {
#pragma unroll
            for (int fc = 0; fc < 4; ++fc) {
                scr[(w * 2 + 0) * 64 + fc * 16 + lane] = ps[fc];
                scr[(w * 2 + 1) * 64 + fc * 16 + lane] = ps2[fc];
            }
        }
        __syncthreads();
        int id = blockIdx.x * (gridDim.y * gridDim.z) + blockIdx.y * gridDim.z + blockIdx.z;
        int stat = t >> 7, c = t & 127;
        int ci = c & 63, half = c >> 6;
        float v = scr[(half * 2 + stat) * 64 + ci] + scr[((half + 2) * 2 + stat) * 64 + ci];
        part[(long)id * 256 + stat * 128 + c] = v;
    }
}

// ---------------- batchnorm finalize ----------------
// part: [512 ids][sum(128) | sumsq(128)], id = colhalf*256 + blockSeq.
// 256 threads: channel ch; colhalf = ch>>7, cc = ch&127.
__global__ void k_bnfin(const float* __restrict__ part, float* __restrict__ stats) {
    int ch = threadIdx.x;
    int half = ch >> 7, cc = ch & 127;
    float s = 0.f, s2 = 0.f;
    for (int b = 0; b < 256; ++b) {
        const float* p = part + (long)(half * 256 + b) * 256;
        s  += p[cc];
        s2 += p[128 + cc];
    }
    float m = s / (float)NN;
    float var = s2 / (float)NN - m * m;
    stats[ch]       = m;
    stats[256 + ch] = rsqrtf(var + 1e-5f);
}

// relu(relu(BN(x)) + res)
__global__ void k_apply(const bf* __restrict__ X, const float* __restrict__ stats,
                        const float* __restrict__ gam, const float* __restrict__ bet,
                        const bf* __restrict__ res, bf* __restrict__ Z) {
    long i4 = ((long)blockIdx.x * 256 + threadIdx.x) * 4;
    int c0 = (int)(i4 & 255);
    ushort4 xv = *(const ushort4*)(X + i4);
    ushort4 rv = *(const ushort4*)(res + i4);
    unsigned short xs[4] = {xv.x, xv.y, xv.z, xv.w};
    unsigned short rs[4] = {rv.x, rv.y, rv.z, rv.w};
    unsigned short o[4];
#pragma unroll
    for (int j = 0; j < 4; ++j) {
        int c = c0 + j;
        float v = (u2f(xs[j]) - stats[c]) * stats[256 + c] * gam[c] + bet[c];
        v = fmaxf(v, 0.f) + u2f(rs[j]);
        o[j] = f2u(fmaxf(v, 0.f));
    }
    *(ushort4*)(Z + i4) = make_ushort4(o[0], o[1], o[2], o[3]);
}

// ---------------- l2 normalize, pool ----------------
__global__ void k_l2norm(const bf* __restrict__ Z, float* __restrict__ outz,
                         bf* __restrict__ Znb) {
    int r = blockIdx.x, c = threadIdx.x;
    long i = (long)r * 256 + c;
    float v = bf2f(Z[i]);
    float s = v * v;
#pragma unroll
    for (int o = 32; o > 0; o >>= 1) s += __shfl_down(s, o);
    __shared__ float red[4];
    __shared__ float denom;
    int lane = c & 63, wid = c >> 6;
    if (lane == 0) red[wid] = s;
    __syncthreads();
    if (c == 0) denom = fmaxf(sqrtf(red[0] + red[1] + red[2] + red[3]), 1e-12f);
    __syncthreads();
    float o = v / denom;
    outz[i] = o;
    Znb[i] = f2bf(o);
}

__global__ void k_pool(const bf* __restrict__ Zn, float* __restrict__ outzg,
                       bf* __restrict__ ZGb) {
    int g = blockIdx.x, c = threadIdx.x;
    const bf* p = Zn + (long)g * 32768 + c;
    float m = -3.4e38f;
    for (int r = 0; r < 128; ++r) m = fmaxf(m, bf2f(p[(long)r * 256]));
    outzg[g * 256 + c] = m;
    ZGb[g * 256 + c] = f2bf(m);
}

// ---------------- host ----------------
template <typename TA, int EPI, int OUT, bool PART, bool BNA>
static void MG(hipStream_t st, const void* A, const bf* BT, const float* bias,
               const float* bnstats, const float* bngam, const float* bnbet,
               float* Cf, bf* Cb, float* part,
               int M, int N, int K, int batch, long sA, long sB, long sC, int ldc) {
    dim3 g(N / 128, M / 128, batch);
    mg<TA, EPI, OUT, PART, BNA><<<g, 256, 0, st>>>(A, BT, bias, bnstats, bngam, bnbet,
                                                   Cf, Cb, part, M, N, K, sA, sB, sC, ldc);
}

extern "C" void kernel_launch(void* const* d_in, const int* in_sizes, int n_in,
                              void* d_out, int out_size, void* d_ws, size_t ws_size,
                              hipStream_t stream) {
    const float* x      = (const float*)d_in[0];
    const int*   srcL   = (const int*)d_in[1];
    const int*   dstL   = (const int*)d_in[2];
    const float* gcn_w0 = (const float*)d_in[3];
    const float* bn_g0  = (const float*)d_in[5];
    const float* bn_b0  = (const float*)d_in[6];
    const float* gcn_w1 = (const float*)d_in[7];
    const float* bn_g1  = (const float*)d_in[9];
    const float* bn_b1  = (const float*)d_in[10];
    const float* gcn_w2 = (const float*)d_in[11];
    const float* bn_g2  = (const float*)d_in[13];
    const float* bn_b2  = (const float*)d_in[14];
    const float* sc_w0  = (const float*)d_in[15];
    const float* sc_b0  = (const float*)d_in[16];
    const float* edge_w = (const float*)d_in[17];
    const float* fd_w0  = (const float*)d_in[18];
    const float* fd_b0  = (const float*)d_in[19];
    const float* fd_g0  = (const float*)d_in[20];
    const float* fd_be0 = (const float*)d_in[21];
    const float* fd_w1  = (const float*)d_in[22];
    const float* fd_b1  = (const float*)d_in[23];
    const float* fd_g1  = (const float*)d_in[24];
    const float* fd_be1 = (const float*)d_in[25];
    const float* fd_w2  = (const float*)d_in[26];
    const float* fd_b2  = (const float*)d_in[27];
    const float* ph_w0  = (const float*)d_in[28];
    const float* ph_b0  = (const float*)d_in[29];
    const float* ph_w1  = (const float*)d_in[30];
    const float* ph_b1  = (const float*)d_in[31];

    float* out     = (float*)d_out;
    float* out_z   = out;
    float* out_adj = out + 8388608;
    float* out_xr  = out + 12582912;
    float* out_zg  = out + 16777216;
    float* out_zgm = out + 16842752;

    // workspace map (f32 word offsets)
    float* w     = (float*)d_ws;
    float* part  = w;                        // 131072
    float* stats = w + 131072;               // 512
    bf*    wT    = (bf*)(w + 131584);        // 557056 bf16 = 278528 f
    float* Aadj  = w + 410112;               // 4194304 f32
    bf*    HT    = (bf*)(w + 4604416);       // 8388608 bf16
    bf*    U1    = (bf*)(w + 8798720);       // 8388608 bf16
    bf*    U2    = (bf*)(w + 12993024);      // 8388608 bf16
    bf*    U3    = (bf*)(w + 17187328);      // 8388608 bf16
    bf*    ZGb   = (bf*)(w + 21381632);      // 65536 bf16
    bf*    P1b   = (bf*)(w + 21414400);      // 65536 bf16
    // total ~85.8 MB

    WTpack pk;
    pk.w[0] = {gcn_w0, 128, 256, 0};
    pk.w[1] = {sc_w0,  128, 256, 32768};
    pk.w[2] = {gcn_w1, 256, 256, 65536};
    pk.w[3] = {gcn_w2, 256, 256, 131072};
    pk.w[4] = {edge_w, 256, 256, 196608};
    pk.w[5] = {fd_w0,  256, 256, 262144};
    pk.w[6] = {fd_w1,  256, 256, 327680};
    pk.w[7] = {fd_w2,  256, 128, 393216};
    pk.w[8] = {ph_w0,  256, 256, 425984};
    pk.w[9] = {ph_w1,  256, 256, 491520};

    k_adj<<<256, 256, 0, stream>>>(srcL, dstL, Aadj);
    k_wt<<<dim3(4, 4, 10), 256, 0, stream>>>(pk, wT);

    // --- layer 0 ---
    MG<float,0,2,false,false>(stream, x, wT + 0, nullptr, nullptr,nullptr,nullptr,
                              nullptr, HT, nullptr, NN, HD, 128, 1, 0,0,0, 0);
    MG<float,1,1,false,false>(stream, x, wT + 32768, sc_b0, nullptr,nullptr,nullptr,
                              nullptr, U1, nullptr, NN, HD, 128, 1, 0,0,0, 256);
    MG<float,0,1,true,false>(stream, Aadj, HT, nullptr, nullptr,nullptr,nullptr,
                             nullptr, U2, part, 128, HD, 128, 256, 16384, 32768, 32768, 256);
    k_bnfin<<<1, 256, 0, stream>>>(part, stats);
    k_apply<<<8192, 256, 0, stream>>>(U2, stats, bn_g0, bn_b0, U1, U3);   // Z0 in U3

    // --- layer 1 ---
    MG<bf,0,2,false,false>(stream, U3, wT + 65536, nullptr, nullptr,nullptr,nullptr,
                           nullptr, HT, nullptr, NN, HD, HD, 1, 0,0,0, 0);
    MG<float,0,1,true,false>(stream, Aadj, HT, nullptr, nullptr,nullptr,nullptr,
                             nullptr, U1, part, 128, HD, 128, 256, 16384, 32768, 32768, 256);
    k_bnfin<<<1, 256, 0, stream>>>(part, stats);
    k_apply<<<8192, 256, 0, stream>>>(U1, stats, bn_g1, bn_b1, U3, U2);   // Z1 in U2

    // --- layer 2 ---
    MG<bf,0,2,false,false>(stream, U2, wT + 131072, nullptr, nullptr,nullptr,nullptr,
                           nullptr, HT, nullptr, NN, HD, HD, 1, 0,0,0, 0);
    MG<float,0,1,true,false>(stream, Aadj, HT, nullptr, nullptr,nullptr,nullptr,
                             nullptr, U1, part, 128, HD, 128, 256, 16384, 32768, 32768, 256);
    k_bnfin<<<1, 256, 0, stream>>>(part, stats);
    k_apply<<<8192, 256, 0, stream>>>(U1, stats, bn_g2, bn_b2, U2, U3);   // Z2 in U3

    // --- L2 normalize: U3 -> out_z (f32) + U1 (Znorm bf16) ---
    k_l2norm<<<32768, 256, 0, stream>>>(U3, out_z, U1);

    // --- edge decoder ---
    MG<bf,0,1,false,false>(stream, U1, wT + 196608, nullptr, nullptr,nullptr,nullptr,
                           nullptr, U2, nullptr, NN, HD, HD, 1, 0,0,0, 256);
    MG<bf,3,0,false,false>(stream, U2, U1, nullptr, nullptr,nullptr,nullptr,
                           out_adj, nullptr, nullptr, 128, 128, HD, 256,
                           32768, 32768, 16384, 128);

    // --- feature decoder (BN applied on-the-fly in next GEMM's A-staging) ---
    MG<bf,2,1,true,false>(stream, U1, wT + 262144, fd_b0, nullptr,nullptr,nullptr,
                          nullptr, U3, part, NN, HD, HD, 1, 0,0,0, 256);
    k_bnfin<<<1, 256, 0, stream>>>(part, stats);
    MG<bf,2,1,true,true>(stream, U3, wT + 327680, fd_b1, stats, fd_g0, fd_be0,
                         nullptr, U2, part, NN, HD, HD, 1, 0,0,0, 256);
    k_bnfin<<<1, 256, 0, stream>>>(part, stats);
    MG<bf,1,0,false,true>(stream, U2, wT + 393216, fd_b2, stats, fd_g1, fd_be1,
                          out_xr, nullptr, nullptr, NN, 128, HD, 1, 0,0,0, 128);

    // --- pooling head ---
    k_pool<<<256, 256, 0, stream>>>(U1, out_zg, ZGb);
    MG<bf,2,1,false,false>(stream, ZGb, wT + 425984, ph_b0, nullptr,nullptr,nullptr,
                           nullptr, P1b, nullptr, 256, 256, 256, 1, 0,0,0, 256);
    MG<bf,1,0,false,false>(stream, P1b, wT + 491520, ph_b1, nullptr,nullptr,nullptr,
                           out_zgm, nullptr, nullptr, 256, 256, 256, 1, 0,0,0, 256);
}

// Round 6
// 265.278 us; speedup vs baseline: 4.0536x; 1.1590x over previous
//
#include <hip/hip_runtime.h>
#include <hip/hip_bf16.h>

using bf = __hip_bfloat16;
typedef __attribute__((ext_vector_type(8))) short s8;
typedef __attribute__((ext_vector_type(4))) float f4;

constexpr int NN  = 32768;
constexpr int HD  = 256;

__device__ __forceinline__ float u2f(unsigned short h) {
    union { unsigned u; float f; } x; x.u = ((unsigned)h) << 16;
    return x.f;
}
__device__ __forceinline__ unsigned short f2u(float f) {
    union { float f; unsigned u; } x; x.f = f;
    unsigned r = x.u + 0x7FFF + ((x.u >> 16) & 1);
    return (unsigned short)(r >> 16);
}
__device__ __forceinline__ bf f2bf(float f) {
    unsigned short h = f2u(f);
    return *reinterpret_cast<bf*>(&h);
}
__device__ __forceinline__ float bf2f(bf b) {
    return u2f(*reinterpret_cast<unsigned short*>(&b));
}

// ---------------- adjacency build: one kernel, all in LDS, bf16 out ----------------
__global__ __launch_bounds__(256) void k_adj(const int* __restrict__ srcL,
                                             const int* __restrict__ dstL,
                                             bf* __restrict__ A) {
    __shared__ float sT[128 * 64];   // 32KB: [dst][src-half]
    __shared__ float sdin[128];
    int g = blockIdx.x, t = threadIdx.x;
    const int* sg = srcL + (g << 11);
    const int* dg = dstL + (g << 11);
    if (t < 128) sdin[t] = 0.f;
    __syncthreads();
    for (int e = t; e < 2048; e += 256) atomicAdd(&sdin[dg[e]], 1.0f);
    __syncthreads();
    if (t < 128) sdin[t] = rsqrtf(sdin[t] + 1.0f);
    __syncthreads();
    bf* out = A + ((long)g << 14);
    for (int half = 0; half < 2; ++half) {
        for (int i = t; i < 8192; i += 256) sT[i] = 0.f;
        __syncthreads();
        for (int e = t; e < 2048; e += 256) {
            int s = sg[e], d = dg[e];
            if ((s >> 6) == half)
                atomicAdd(&sT[(d << 6) + (s & 63)], sdin[s] * sdin[d]);
        }
        __syncthreads();
        if (t < 128 && (t >> 6) == half)
            sT[(t << 6) + (t & 63)] += sdin[t] * sdin[t];
        __syncthreads();
        for (int i4 = t; i4 < 2048; i4 += 256) {
            int d = i4 >> 4, c4 = (i4 & 15) * 4;
            float4 v = *(float4*)&sT[(d << 6) + c4];
            ushort4 u = make_ushort4(f2u(v.x), f2u(v.y), f2u(v.z), f2u(v.w));
            *(ushort4*)&out[(d << 7) + (half << 6) + c4] = u;
        }
        __syncthreads();
    }
}

// ---------------- weight transpose f32 [K x N] -> bf16 [N x K] ----------------
struct WTd { const float* src; int K, N, off; };
struct WTpack { WTd w[10]; };
__global__ void k_wt(WTpack p, bf* __restrict__ out) {
    WTd d = p.w[blockIdx.z];
    int n0 = blockIdx.x * 64, k0 = blockIdx.y * 64;
    if (n0 >= d.N || k0 >= d.K) return;
    __shared__ float s[64][65];
    int t = threadIdx.x;
    int cc = t & 63, rq = t >> 6;
#pragma unroll
    for (int i = 0; i < 16; ++i) {
        int r = i * 4 + rq;
        s[r][cc] = d.src[(long)(k0 + r) * d.N + n0 + cc];
    }
    __syncthreads();
#pragma unroll
    for (int i = 0; i < 16; ++i) {
        int r = i * 4 + rq;
        out[d.off + (long)(n0 + r) * d.K + k0 + cc] = f2bf(s[cc][r]);
    }
}

// ---------------- MFMA GEMM ----------------
// C[M x N] = A[M x K] @ BT[N x K]^T.  Tiles 128x128, BK=64, 4 waves (2x2 of 64x64).
// TA: float (convert on stage) or bf.  EPI: 0 none,1 +bias,2 +bias+relu,3 sigmoid+zerodiag.
// OUT: 0 f32 row-major, 1 bf16 row-major, 2 bf16 per-graph-transposed HT[g][256][128],
//      4 dual: cols<256 -> HT transposed (Cb), cols>=256 -> bf16 row-major (bf*)Cf + bias.
// PART: fused per-block column sum/sumsq partials.
// BNA: apply batchnorm (stats+gam+bet) to A during staging.
__device__ __forceinline__ int swz(int row, int slot) {
    return row * 64 + ((slot ^ (row & 7)) << 3);   // element offset, 16B slots
}

template <typename TA, int EPI, int OUT, bool PART, bool BNA>
__global__ __launch_bounds__(256) void mg(
    const void* __restrict__ Av, const bf* __restrict__ BT,
    const float* __restrict__ bias,
    const float* __restrict__ bnstats, const float* __restrict__ bngam,
    const float* __restrict__ bnbet,
    float* __restrict__ Cf, bf* __restrict__ Cb, float* __restrict__ part,
    int M, int N, int K, long sA, long sB, long sC, int ldc) {
    constexpr bool AF32 = (sizeof(TA) == 4);
    __shared__ __align__(16) bf sAl[128 * 64];
    __shared__ __align__(16) bf sBl[128 * 64];
    const int g = blockIdx.z;
    const int m0 = blockIdx.y * 128, n0 = blockIdx.x * 128;
    const TA* Ab = (const TA*)Av + (long)g * sA + (long)m0 * K;
    const bf* Bb = BT + (long)g * sB + (long)n0 * K;
    const int t = threadIdx.x;
    const int lane = t & 63;
    const int w = t >> 6;
    const int wm = (w >> 1) * 64, wn = (w & 1) * 64;
    const int fr16 = lane & 15, kq = lane >> 4;
    f4 acc[4][4] = {};
    for (int k0 = 0; k0 < K; k0 += 64) {
#pragma unroll
        for (int i = 0; i < 4; ++i) {
            int sdx = i * 256 + t;
            int row = sdx >> 3, sl = sdx & 7;
            s8 av;
            if constexpr (AF32) {
                const float* src = (const float*)Ab + (long)row * K + k0 + sl * 8;
                float4 f0 = *(const float4*)src;
                float4 f1 = *(const float4*)(src + 4);
                float ff[8] = {f0.x, f0.y, f0.z, f0.w, f1.x, f1.y, f1.z, f1.w};
                unsigned short u[8];
#pragma unroll
                for (int j = 0; j < 8; ++j) u[j] = f2u(ff[j]);
                av = *(s8*)u;
            } else {
                av = *(const s8*)((const bf*)Ab + (long)row * K + k0 + sl * 8);
                if constexpr (BNA) {
                    unsigned short* u = (unsigned short*)&av;
#pragma unroll
                    for (int j = 0; j < 8; ++j) {
                        int c = k0 + sl * 8 + j;
                        float v = (u2f(u[j]) - bnstats[c]) * bnstats[256 + c] * bngam[c]
                                  + bnbet[c];
                        u[j] = f2u(v);
                    }
                }
            }
            *(s8*)&sAl[swz(row, sl)] = av;
            s8 bv = *(const s8*)&Bb[(long)row * K + k0 + sl * 8];
            *(s8*)&sBl[swz(row, sl)] = bv;
        }
        __syncthreads();
#pragma unroll
        for (int ks = 0; ks < 2; ++ks) {
            s8 af[4], bg[4];
#pragma unroll
            for (int f = 0; f < 4; ++f) {
                af[f] = *(const s8*)&sAl[swz(wm + f * 16 + fr16, kq + 4 * ks)];
                bg[f] = *(const s8*)&sBl[swz(wn + f * 16 + fr16, kq + 4 * ks)];
            }
#pragma unroll
            for (int fr = 0; fr < 4; ++fr)
#pragma unroll
                for (int fc = 0; fc < 4; ++fc)
                    acc[fr][fc] = __builtin_amdgcn_mfma_f32_16x16x32_bf16(
                        af[fr], bg[fc], acc[fr][fc], 0, 0, 0);
        }
        __syncthreads();
    }
    // ---------------- epilogue ----------------
    float ps[4], ps2[4];
    if (PART) {
#pragma unroll
        for (int fc = 0; fc < 4; ++fc) { ps[fc] = 0.f; ps2[fc] = 0.f; }
    }
#pragma unroll
    for (int fr = 0; fr < 4; ++fr) {
        int rl = wm + fr * 16 + (lane >> 4) * 4;       // local row base
#pragma unroll
        for (int fc = 0; fc < 4; ++fc) {
            int cl = wn + fc * 16 + (lane & 15);       // local col
            int col = n0 + cl;
            if (OUT == 4) {
                if (col < 256) {                        // H -> transposed HT
                    unsigned short pk[4];
#pragma unroll
                    for (int i = 0; i < 4; ++i) pk[i] = f2u(acc[fr][fc][i]);
                    int gg = m0 >> 7;
                    *(ushort4*)&Cb[(long)gg * 32768 + (long)col * 128 + rl] =
                        make_ushort4(pk[0], pk[1], pk[2], pk[3]);
                } else {                                // shortcut -> row-major + bias
                    float bv = bias[col - 256];
                    bf* C2 = (bf*)Cf;
#pragma unroll
                    for (int i = 0; i < 4; ++i)
                        C2[(long)(m0 + rl + i) * 256 + (col - 256)] =
                            f2bf(acc[fr][fc][i] + bv);
                }
                continue;
            }
            float bv = (EPI == 1 || EPI == 2) ? bias[col] : 0.f;
            unsigned short pk[4];
#pragma unroll
            for (int i = 0; i < 4; ++i) {
                float v = acc[fr][fc][i];
                if (EPI == 1 || EPI == 2) v += bv;
                if (EPI == 2) v = fmaxf(v, 0.f);
                if (EPI == 3) {
                    v = 1.f / (1.f + __expf(-v));
                    if (rl + i == col) v = 0.f;
                }
                if (PART) { ps[fc] += v; ps2[fc] += v * v; }
                if (OUT == 0) Cf[(long)g * sC + (long)(m0 + rl + i) * ldc + col] = v;
                if (OUT == 1) Cb[(long)g * sC + (long)(m0 + rl + i) * ldc + col] = f2bf(v);
                if (OUT == 2) pk[i] = f2u(v);
            }
            if (OUT == 2) {
                int gg = m0 >> 7;   // M-tile == one graph
                *(ushort4*)&Cb[(long)gg * 32768 + (long)col * 128 + rl] =
                    make_ushort4(pk[0], pk[1], pk[2], pk[3]);
            }
        }
    }
    if (PART) {
        __syncthreads();           // LDS free for scratch
        float* scr = (float*)sAl;  // [4 waves][2 stats][64 cols] = 2KB
#pragma unroll
        for (int fc = 0; fc < 4; ++fc) {
            ps[fc] += __shfl_xor(ps[fc], 16);  ps[fc] += __shfl_xor(ps[fc], 32);
            ps2[fc] += __shfl_xor(ps2[fc], 16); ps2[fc] += __shfl_xor(ps2[fc], 32);
        }
        if (lane < 16) {
#pragma unroll
            for (int fc = 0; fc < 4; ++fc) {
                scr[(w * 2 + 0) * 64 + fc * 16 + lane] = ps[fc];
                scr[(w * 2 + 1) * 64 + fc * 16 + lane] = ps2[fc];
            }
        }
        __syncthreads();
        int id = blockIdx.x * (gridDim.y * gridDim.z) + blockIdx.y * gridDim.z + blockIdx.z;
        int stat = t >> 7, c = t & 127;
        int ci = c & 63, half = c >> 6;
        float v = scr[(half * 2 + stat) * 64 + ci] + scr[((half + 2) * 2 + stat) * 64 + ci];
        part[(long)id * 256 + stat * 128 + c] = v;
    }
}

// ---------------- batchnorm finalize (parallel, deterministic tree) ----------------
// part: [512 ids][sum(128) | sumsq(128)], id = colhalf*256 + blockSeq.
// grid 256 (one block per channel), 256 threads.
__global__ void k_bnfin(const float* __restrict__ part, float* __restrict__ stats) {
    int ch = blockIdx.x;
    int half = ch >> 7, cc = ch & 127;
    int t = threadIdx.x;
    __shared__ float2 sm[256];
    const float* p = part + (long)(half * 256 + t) * 256;
    sm[t] = make_float2(p[cc], p[128 + cc]);
    __syncthreads();
    for (int s = 128; s > 0; s >>= 1) {
        if (t < s) { sm[t].x += sm[t + s].x; sm[t].y += sm[t + s].y; }
        __syncthreads();
    }
    if (t == 0) {
        float m = sm[0].x / (float)NN;
        float var = sm[0].y / (float)NN - m * m;
        stats[ch]       = m;
        stats[256 + ch] = rsqrtf(var + 1e-5f);
    }
}

// relu(relu(BN(x)) + res)
__global__ void k_apply(const bf* __restrict__ X, const float* __restrict__ stats,
                        const float* __restrict__ gam, const float* __restrict__ bet,
                        const bf* __restrict__ res, bf* __restrict__ Z) {
    long i4 = ((long)blockIdx.x * 256 + threadIdx.x) * 4;
    int c0 = (int)(i4 & 255);
    ushort4 xv = *(const ushort4*)(X + i4);
    ushort4 rv = *(const ushort4*)(res + i4);
    unsigned short xs[4] = {xv.x, xv.y, xv.z, xv.w};
    unsigned short rs[4] = {rv.x, rv.y, rv.z, rv.w};
    unsigned short o[4];
#pragma unroll
    for (int j = 0; j < 4; ++j) {
        int c = c0 + j;
        float v = (u2f(xs[j]) - stats[c]) * stats[256 + c] * gam[c] + bet[c];
        v = fmaxf(v, 0.f) + u2f(rs[j]);
        o[j] = f2u(fmaxf(v, 0.f));
    }
    *(ushort4*)(Z + i4) = make_ushort4(o[0], o[1], o[2], o[3]);
}

// layer-2 apply fused with L2-normalize: z=relu(relu(BN(X))+res); z/=||row||
__global__ void k_apply_l2(const bf* __restrict__ X, const float* __restrict__ stats,
                           const float* __restrict__ gam, const float* __restrict__ bet,
                           const bf* __restrict__ res, float* __restrict__ outz,
                           bf* __restrict__ Znb) {
    int r = blockIdx.x, c = threadIdx.x;
    long i = (long)r * 256 + c;
    float v = (bf2f(X[i]) - stats[c]) * stats[256 + c] * gam[c] + bet[c];
    v = fmaxf(v, 0.f) + bf2f(res[i]);
    v = fmaxf(v, 0.f);
    float s = v * v;
#pragma unroll
    for (int o = 32; o > 0; o >>= 1) s += __shfl_down(s, o);
    __shared__ float red[4];
    __shared__ float denom;
    int lane = c & 63, wid = c >> 6;
    if (lane == 0) red[wid] = s;
    __syncthreads();
    if (c == 0) denom = fmaxf(sqrtf(red[0] + red[1] + red[2] + red[3]), 1e-12f);
    __syncthreads();
    float o = v / denom;
    outz[i] = o;
    Znb[i] = f2bf(o);
}

__global__ void k_pool(const bf* __restrict__ Zn, float* __restrict__ outzg,
                       bf* __restrict__ ZGb) {
    int g = blockIdx.x, c = threadIdx.x;
    const bf* p = Zn + (long)g * 32768 + c;
    float m = -3.4e38f;
    for (int r = 0; r < 128; ++r) m = fmaxf(m, bf2f(p[(long)r * 256]));
    outzg[g * 256 + c] = m;
    ZGb[g * 256 + c] = f2bf(m);
}

// ---------------- host ----------------
template <typename TA, int EPI, int OUT, bool PART, bool BNA>
static void MG(hipStream_t st, const void* A, const bf* BT, const float* bias,
               const float* bnstats, const float* bngam, const float* bnbet,
               float* Cf, bf* Cb, float* part,
               int M, int N, int K, int batch, long sA, long sB, long sC, int ldc) {
    dim3 g(N / 128, M / 128, batch);
    mg<TA, EPI, OUT, PART, BNA><<<g, 256, 0, st>>>(A, BT, bias, bnstats, bngam, bnbet,
                                                   Cf, Cb, part, M, N, K, sA, sB, sC, ldc);
}

extern "C" void kernel_launch(void* const* d_in, const int* in_sizes, int n_in,
                              void* d_out, int out_size, void* d_ws, size_t ws_size,
                              hipStream_t stream) {
    const float* x      = (const float*)d_in[0];
    const int*   srcL   = (const int*)d_in[1];
    const int*   dstL   = (const int*)d_in[2];
    const float* gcn_w0 = (const float*)d_in[3];
    const float* bn_g0  = (const float*)d_in[5];
    const float* bn_b0  = (const float*)d_in[6];
    const float* gcn_w1 = (const float*)d_in[7];
    const float* bn_g1  = (const float*)d_in[9];
    const float* bn_b1  = (const float*)d_in[10];
    const float* gcn_w2 = (const float*)d_in[11];
    const float* bn_g2  = (const float*)d_in[13];
    const float* bn_b2  = (const float*)d_in[14];
    const float* sc_w0  = (const float*)d_in[15];
    const float* sc_b0  = (const float*)d_in[16];
    const float* edge_w = (const float*)d_in[17];
    const float* fd_w0  = (const float*)d_in[18];
    const float* fd_b0  = (const float*)d_in[19];
    const float* fd_g0  = (const float*)d_in[20];
    const float* fd_be0 = (const float*)d_in[21];
    const float* fd_w1  = (const float*)d_in[22];
    const float* fd_b1  = (const float*)d_in[23];
    const float* fd_g1  = (const float*)d_in[24];
    const float* fd_be1 = (const float*)d_in[25];
    const float* fd_w2  = (const float*)d_in[26];
    const float* fd_b2  = (const float*)d_in[27];
    const float* ph_w0  = (const float*)d_in[28];
    const float* ph_b0  = (const float*)d_in[29];
    const float* ph_w1  = (const float*)d_in[30];
    const float* ph_b1  = (const float*)d_in[31];

    float* out     = (float*)d_out;
    float* out_z   = out;
    float* out_adj = out + 8388608;
    float* out_xr  = out + 12582912;
    float* out_zg  = out + 16777216;
    float* out_zgm = out + 16842752;

    // workspace map (f32 word offsets)
    float* w     = (float*)d_ws;
    float* part  = w;                        // 131072
    float* stats = w + 131072;               // 512
    bf*    wT    = (bf*)(w + 131584);        // 557056 bf16
    bf*    Aadjb = (bf*)(w + 410112);        // 4194304 bf16
    bf*    HT    = (bf*)(w + 2507264);       // 8388608 bf16
    bf*    U1    = (bf*)(w + 6701568);       // 8388608 bf16
    bf*    U2    = (bf*)(w + 10895872);      // 8388608 bf16
    bf*    U3    = (bf*)(w + 15090176);      // 8388608 bf16
    bf*    ZGb   = (bf*)(w + 19284480);      // 65536 bf16
    bf*    P1b   = (bf*)(w + 19317248);      // 65536 bf16
    // total ~77.4 MB

    WTpack pk;
    pk.w[0] = {gcn_w0, 128, 256, 0};
    pk.w[1] = {sc_w0,  128, 256, 32768};
    pk.w[2] = {gcn_w1, 256, 256, 65536};
    pk.w[3] = {gcn_w2, 256, 256, 131072};
    pk.w[4] = {edge_w, 256, 256, 196608};
    pk.w[5] = {fd_w0,  256, 256, 262144};
    pk.w[6] = {fd_w1,  256, 256, 327680};
    pk.w[7] = {fd_w2,  256, 128, 393216};
    pk.w[8] = {ph_w0,  256, 256, 425984};
    pk.w[9] = {ph_w1,  256, 256, 491520};

    k_adj<<<256, 256, 0, stream>>>(srcL, dstL, Aadjb);
    k_wt<<<dim3(4, 4, 10), 256, 0, stream>>>(pk, wT);

    // --- layer 0: combined [H | shortcut] GEMM over x (N=512) ---
    MG<float,0,4,false,false>(stream, x, wT + 0, sc_b0, nullptr,nullptr,nullptr,
                              (float*)U1, HT, nullptr, NN, 512, 128, 1, 0,0,0, 0);
    MG<bf,0,1,true,false>(stream, Aadjb, HT, nullptr, nullptr,nullptr,nullptr,
                          nullptr, U2, part, 128, HD, 128, 256, 16384, 32768, 32768, 256);
    k_bnfin<<<256, 256, 0, stream>>>(part, stats);
    k_apply<<<8192, 256, 0, stream>>>(U2, stats, bn_g0, bn_b0, U1, U3);   // Z0 in U3

    // --- layer 1 ---
    MG<bf,0,2,false,false>(stream, U3, wT + 65536, nullptr, nullptr,nullptr,nullptr,
                           nullptr, HT, nullptr, NN, HD, HD, 1, 0,0,0, 0);
    MG<bf,0,1,true,false>(stream, Aadjb, HT, nullptr, nullptr,nullptr,nullptr,
                          nullptr, U1, part, 128, HD, 128, 256, 16384, 32768, 32768, 256);
    k_bnfin<<<256, 256, 0, stream>>>(part, stats);
    k_apply<<<8192, 256, 0, stream>>>(U1, stats, bn_g1, bn_b1, U3, U2);   // Z1 in U2

    // --- layer 2 ---
    MG<bf,0,2,false,false>(stream, U2, wT + 131072, nullptr, nullptr,nullptr,nullptr,
                           nullptr, HT, nullptr, NN, HD, HD, 1, 0,0,0, 0);
    MG<bf,0,1,true,false>(stream, Aadjb, HT, nullptr, nullptr,nullptr,nullptr,
                          nullptr, U1, part, 128, HD, 128, 256, 16384, 32768, 32768, 256);
    k_bnfin<<<256, 256, 0, stream>>>(part, stats);
    // fused apply + L2 normalize: agg2 in U1, res Z1 in U2 -> out_z + Znorm in U3
    k_apply_l2<<<32768, 256, 0, stream>>>(U1, stats, bn_g2, bn_b2, U2, out_z, U3);

    // --- edge decoder ---
    MG<bf,0,1,false,false>(stream, U3, wT + 196608, nullptr, nullptr,nullptr,nullptr,
                           nullptr, U1, nullptr, NN, HD, HD, 1, 0,0,0, 256);
    MG<bf,3,0,false,false>(stream, U1, U3, nullptr, nullptr,nullptr,nullptr,
                           out_adj, nullptr, nullptr, 128, 128, HD, 256,
                           32768, 32768, 16384, 128);

    // --- feature decoder (BN applied on-the-fly in next GEMM's A-staging) ---
    MG<bf,2,1,true,false>(stream, U3, wT + 262144, fd_b0, nullptr,nullptr,nullptr,
                          nullptr, U2, part, NN, HD, HD, 1, 0,0,0, 256);
    k_bnfin<<<256, 256, 0, stream>>>(part, stats);
    MG<bf,2,1,true,true>(stream, U2, wT + 327680, fd_b1, stats, fd_g0, fd_be0,
                         nullptr, U1, part, NN, HD, HD, 1, 0,0,0, 256);
    k_bnfin<<<256, 256, 0, stream>>>(part, stats);
    MG<bf,1,0,false,true>(stream, U1, wT + 393216, fd_b2, stats, fd_g1, fd_be1,
                          out_xr, nullptr, nullptr, NN, 128, HD, 1, 0,0,0, 128);

    // --- pooling head ---
    k_pool<<<256, 256, 0, stream>>>(U3, out_zg, ZGb);
    MG<bf,2,1,false,false>(stream, ZGb, wT + 425984, ph_b0, nullptr,nullptr,nullptr,
                           nullptr, P1b, nullptr, 256, 256, 256, 1, 0,0,0, 256);
    MG<bf,1,0,false,false>(stream, P1b, wT + 491520, ph_b1, nullptr,nullptr,nullptr,
                           out_zgm, nullptr, nullptr, 256, 256, 256, 1, 0,0,0, 256);
}

// Round 7
// 245.210 us; speedup vs baseline: 4.3853x; 1.0818x over previous
//
#include <hip/hip_runtime.h>
#include <hip/hip_bf16.h>

using bf = __hip_bfloat16;
typedef __attribute__((ext_vector_type(8))) short s8;
typedef __attribute__((ext_vector_type(4))) float f4;

constexpr int NN  = 32768;
constexpr int HD  = 256;

__device__ __forceinline__ float u2f(unsigned short h) {
    union { unsigned u; float f; } x; x.u = ((unsigned)h) << 16;
    return x.f;
}
__device__ __forceinline__ unsigned short f2u(float f) {
    union { float f; unsigned u; } x; x.f = f;
    unsigned r = x.u + 0x7FFF + ((x.u >> 16) & 1);
    return (unsigned short)(r >> 16);
}
__device__ __forceinline__ bf f2bf(float f) {
    unsigned short h = f2u(f);
    return *reinterpret_cast<bf*>(&h);
}
__device__ __forceinline__ float bf2f(bf b) {
    return u2f(*reinterpret_cast<unsigned short*>(&b));
}

// swizzles: 8-element (16B) slots XOR'd by low row bits
__device__ __forceinline__ int swz(int row, int slot) {      // 64-col rows
    return row * 64 + ((slot ^ (row & 7)) << 3);
}
__device__ __forceinline__ int swz128(int row, int slot) {   // 128-col rows
    return row * 128 + ((slot ^ (row & 7)) << 3);
}

// ---------------- adjacency build: one kernel, all in LDS, bf16 out ----------------
__global__ __launch_bounds__(256) void k_adj(const int* __restrict__ srcL,
                                             const int* __restrict__ dstL,
                                             bf* __restrict__ A) {
    __shared__ float sT[128 * 64];
    __shared__ float sdin[128];
    int g = blockIdx.x, t = threadIdx.x;
    const int* sg = srcL + (g << 11);
    const int* dg = dstL + (g << 11);
    if (t < 128) sdin[t] = 0.f;
    __syncthreads();
    for (int e = t; e < 2048; e += 256) atomicAdd(&sdin[dg[e]], 1.0f);
    __syncthreads();
    if (t < 128) sdin[t] = rsqrtf(sdin[t] + 1.0f);
    __syncthreads();
    bf* out = A + ((long)g << 14);
    for (int half = 0; half < 2; ++half) {
        for (int i = t; i < 8192; i += 256) sT[i] = 0.f;
        __syncthreads();
        for (int e = t; e < 2048; e += 256) {
            int s = sg[e], d = dg[e];
            if ((s >> 6) == half)
                atomicAdd(&sT[(d << 6) + (s & 63)], sdin[s] * sdin[d]);
        }
        __syncthreads();
        if (t < 128 && (t >> 6) == half)
            sT[(t << 6) + (t & 63)] += sdin[t] * sdin[t];
        __syncthreads();
        for (int i4 = t; i4 < 2048; i4 += 256) {
            int d = i4 >> 4, c4 = (i4 & 15) * 4;
            float4 v = *(float4*)&sT[(d << 6) + c4];
            ushort4 u = make_ushort4(f2u(v.x), f2u(v.y), f2u(v.z), f2u(v.w));
            *(ushort4*)&out[(d << 7) + (half << 6) + c4] = u;
        }
        __syncthreads();
    }
}

// ---------------- weight transpose f32 [K x N] -> bf16 [N x K] ----------------
struct WTd { const float* src; int K, N, off; };
struct WTpack { WTd w[10]; };
__global__ void k_wt(WTpack p, bf* __restrict__ out) {
    WTd d = p.w[blockIdx.z];
    int n0 = blockIdx.x * 64, k0 = blockIdx.y * 64;
    if (n0 >= d.N || k0 >= d.K) return;
    __shared__ float s[64][65];
    int t = threadIdx.x;
    int cc = t & 63, rq = t >> 6;
#pragma unroll
    for (int i = 0; i < 16; ++i) {
        int r = i * 4 + rq;
        s[r][cc] = d.src[(long)(k0 + r) * d.N + n0 + cc];
    }
    __syncthreads();
#pragma unroll
    for (int i = 0; i < 16; ++i) {
        int r = i * 4 + rq;
        out[d.off + (long)(n0 + r) * d.K + k0 + cc] = f2bf(s[cc][r]);
    }
}

// ---------------- MFMA GEMM (generic; unchanged structure) ----------------
template <typename TA, int EPI, int OUT, bool PART, bool BNA>
__global__ __launch_bounds__(256) void mg(
    const void* __restrict__ Av, const bf* __restrict__ BT,
    const float* __restrict__ bias,
    const float* __restrict__ bnstats, const float* __restrict__ bngam,
    const float* __restrict__ bnbet,
    float* __restrict__ Cf, bf* __restrict__ Cb, float* __restrict__ part,
    int M, int N, int K, long sA, long sB, long sC, int ldc) {
    constexpr bool AF32 = (sizeof(TA) == 4);
    __shared__ __align__(16) bf sAl[128 * 64];
    __shared__ __align__(16) bf sBl[128 * 64];
    const int g = blockIdx.z;
    const int m0 = blockIdx.y * 128, n0 = blockIdx.x * 128;
    const TA* Ab = (const TA*)Av + (long)g * sA + (long)m0 * K;
    const bf* Bb = BT + (long)g * sB + (long)n0 * K;
    const int t = threadIdx.x;
    const int lane = t & 63;
    const int w = t >> 6;
    const int wm = (w >> 1) * 64, wn = (w & 1) * 64;
    const int fr16 = lane & 15, kq = lane >> 4;
    f4 acc[4][4] = {};
    for (int k0 = 0; k0 < K; k0 += 64) {
#pragma unroll
        for (int i = 0; i < 4; ++i) {
            int sdx = i * 256 + t;
            int row = sdx >> 3, sl = sdx & 7;
            s8 av;
            if constexpr (AF32) {
                const float* src = (const float*)Ab + (long)row * K + k0 + sl * 8;
                float4 f0 = *(const float4*)src;
                float4 f1 = *(const float4*)(src + 4);
                float ff[8] = {f0.x, f0.y, f0.z, f0.w, f1.x, f1.y, f1.z, f1.w};
                unsigned short u[8];
#pragma unroll
                for (int j = 0; j < 8; ++j) u[j] = f2u(ff[j]);
                av = *(s8*)u;
            } else {
                av = *(const s8*)((const bf*)Ab + (long)row * K + k0 + sl * 8);
                if constexpr (BNA) {
                    unsigned short* u = (unsigned short*)&av;
#pragma unroll
                    for (int j = 0; j < 8; ++j) {
                        int c = k0 + sl * 8 + j;
                        float v = (u2f(u[j]) - bnstats[c]) * bnstats[256 + c] * bngam[c]
                                  + bnbet[c];
                        u[j] = f2u(v);
                    }
                }
            }
            *(s8*)&sAl[swz(row, sl)] = av;
            s8 bv = *(const s8*)&Bb[(long)row * K + k0 + sl * 8];
            *(s8*)&sBl[swz(row, sl)] = bv;
        }
        __syncthreads();
#pragma unroll
        for (int ks = 0; ks < 2; ++ks) {
            s8 af[4], bg[4];
#pragma unroll
            for (int f = 0; f < 4; ++f) {
                af[f] = *(const s8*)&sAl[swz(wm + f * 16 + fr16, kq + 4 * ks)];
                bg[f] = *(const s8*)&sBl[swz(wn + f * 16 + fr16, kq + 4 * ks)];
            }
#pragma unroll
            for (int fr = 0; fr < 4; ++fr)
#pragma unroll
                for (int fc = 0; fc < 4; ++fc)
                    acc[fr][fc] = __builtin_amdgcn_mfma_f32_16x16x32_bf16(
                        af[fr], bg[fc], acc[fr][fc], 0, 0, 0);
        }
        __syncthreads();
    }
    float ps[4], ps2[4];
    if (PART) {
#pragma unroll
        for (int fc = 0; fc < 4; ++fc) { ps[fc] = 0.f; ps2[fc] = 0.f; }
    }
#pragma unroll
    for (int fr = 0; fr < 4; ++fr) {
        int rl = wm + fr * 16 + (lane >> 4) * 4;
#pragma unroll
        for (int fc = 0; fc < 4; ++fc) {
            int cl = wn + fc * 16 + (lane & 15);
            int col = n0 + cl;
            if (OUT == 4) {
                if (col < 256) {
                    unsigned short pk[4];
#pragma unroll
                    for (int i = 0; i < 4; ++i) pk[i] = f2u(acc[fr][fc][i]);
                    int gg = m0 >> 7;
                    *(ushort4*)&Cb[(long)gg * 32768 + (long)col * 128 + rl] =
                        make_ushort4(pk[0], pk[1], pk[2], pk[3]);
                } else {
                    float bv = bias[col - 256];
                    bf* C2 = (bf*)Cf;
#pragma unroll
                    for (int i = 0; i < 4; ++i)
                        C2[(long)(m0 + rl + i) * 256 + (col - 256)] =
                            f2bf(acc[fr][fc][i] + bv);
                }
                continue;
            }
            float bv = (EPI == 1 || EPI == 2) ? bias[col] : 0.f;
            unsigned short pk[4];
#pragma unroll
            for (int i = 0; i < 4; ++i) {
                float v = acc[fr][fc][i];
                if (EPI == 1 || EPI == 2) v += bv;
                if (EPI == 2) v = fmaxf(v, 0.f);
                if (EPI == 3) {
                    v = 1.f / (1.f + __expf(-v));
                    if (rl + i == col) v = 0.f;
                }
                if (PART) { ps[fc] += v; ps2[fc] += v * v; }
                if (OUT == 0) Cf[(long)g * sC + (long)(m0 + rl + i) * ldc + col] = v;
                if (OUT == 1) Cb[(long)g * sC + (long)(m0 + rl + i) * ldc + col] = f2bf(v);
                if (OUT == 2) pk[i] = f2u(v);
            }
            if (OUT == 2) {
                int gg = m0 >> 7;
                *(ushort4*)&Cb[(long)gg * 32768 + (long)col * 128 + rl] =
                    make_ushort4(pk[0], pk[1], pk[2], pk[3]);
            }
        }
    }
    if (PART) {
        __syncthreads();
        float* scr = (float*)sAl;
#pragma unroll
        for (int fc = 0; fc < 4; ++fc) {
            ps[fc] += __shfl_xor(ps[fc], 16);  ps[fc] += __shfl_xor(ps[fc], 32);
            ps2[fc] += __shfl_xor(ps2[fc], 16); ps2[fc] += __shfl_xor(ps2[fc], 32);
        }
        if (lane < 16) {
#pragma unroll
            for (int fc = 0; fc < 4; ++fc) {
                scr[(w * 2 + 0) * 64 + fc * 16 + lane] = ps[fc];
                scr[(w * 2 + 1) * 64 + fc * 16 + lane] = ps2[fc];
            }
        }
        __syncthreads();
        int id = blockIdx.x * (gridDim.y * gridDim.z) + blockIdx.y * gridDim.z + blockIdx.z;
        int stat = t >> 7, c = t & 127;
        int ci = c & 63, half = c >> 6;
        float v = scr[(half * 2 + stat) * 64 + ci] + scr[((half + 2) * 2 + stat) * 64 + ci];
        part[(long)id * 256 + stat * 128 + c] = v;
    }
}

// ---------------- fused per-graph two-stage kernel ----------------
// MODE 0 (GCN layer):  AG_g = Aadj_g @ (Z_g @ W)   + BN partials
// MODE 1 (edge dec.):  out_adj_g = sigmoid(Zn_g @ ewT^T @ Zn_g^T), zero diag
// 512 threads = 8 waves (2 M x 4 N), per-wave tile 64x32. LDS 64KB.
template <int MODE>
__global__ __launch_bounds__(512) void k_fused2(
    const bf* __restrict__ Zin, const bf* __restrict__ Wt,
    const bf* __restrict__ Adj, bf* __restrict__ AG,
    float* __restrict__ part, float* __restrict__ adjout) {
    __shared__ __align__(16) bf sOut[128 * 128];   // stage1 result (HT or E), 32KB
    __shared__ __align__(16) bf sStg[128 * 128];   // staging, 32KB
    const int g = blockIdx.x;
    const int t = threadIdx.x;
    const int lane = t & 63, w = t >> 6;
    const int wm = w >> 2, wn = w & 3;
    const int l15 = lane & 15, kq = lane >> 4;
    const bf* Zg = Zin + (long)g * 32768;
    f4 acc2[4][2] = {};
    for (int h = 0; h < 2; ++h) {
        // ---- stage 1: 128x128(half) = A(128xK) @ BT(128xK), K=256 ----
        f4 acc1[4][2] = {};
        for (int k0 = 0; k0 < 256; k0 += 64) {
            __syncthreads();
#pragma unroll
            for (int i = 0; i < 2; ++i) {
                int sdx = i * 512 + t;
                int row = sdx >> 3, sl = sdx & 7;
                const bf* Asrc = (MODE == 0)
                    ? Zg + row * 256 + k0 + sl * 8
                    : Wt + (h * 128 + row) * 256 + k0 + sl * 8;
                *(s8*)&sStg[swz(row, sl)] = *(const s8*)Asrc;
                const bf* Bsrc = (MODE == 0)
                    ? Wt + (h * 128 + row) * 256 + k0 + sl * 8
                    : Zg + row * 256 + k0 + sl * 8;
                *(s8*)&sStg[8192 + swz(row, sl)] = *(const s8*)Bsrc;
            }
            __syncthreads();
#pragma unroll
            for (int ks = 0; ks < 2; ++ks) {
                s8 af[4], bg[2];
#pragma unroll
                for (int f = 0; f < 4; ++f)
                    af[f] = *(const s8*)&sStg[swz(wm * 64 + f * 16 + l15, kq + 4 * ks)];
#pragma unroll
                for (int f = 0; f < 2; ++f)
                    bg[f] = *(const s8*)&sStg[8192 + swz(wn * 32 + f * 16 + l15, kq + 4 * ks)];
#pragma unroll
                for (int fr = 0; fr < 4; ++fr)
#pragma unroll
                    for (int fc = 0; fc < 2; ++fc)
                        acc1[fr][fc] = __builtin_amdgcn_mfma_f32_16x16x32_bf16(
                            af[fr], bg[fc], acc1[fr][fc], 0, 0, 0);
            }
        }
        // transposed store: value (m=rl+i, n=cl) -> sOut[cl][rl..rl+3]
#pragma unroll
        for (int fr = 0; fr < 4; ++fr) {
            int rl = wm * 64 + fr * 16 + kq * 4;
#pragma unroll
            for (int fc = 0; fc < 2; ++fc) {
                int cl = wn * 32 + fc * 16 + l15;
                ushort4 q = make_ushort4(f2u(acc1[fr][fc][0]), f2u(acc1[fr][fc][1]),
                                         f2u(acc1[fr][fc][2]), f2u(acc1[fr][fc][3]));
                int off = cl * 128 + (((rl >> 3) ^ (cl & 7)) << 3) + (rl & 7);
                *(ushort4*)&sOut[off] = q;
            }
        }
        __syncthreads();   // sOut complete; stage1 LDS reads complete
        // ---- stage 2 staging: A operand (128x128) into sStg ----
#pragma unroll
        for (int i = 0; i < 4; ++i) {
            int sdx = i * 512 + t;
            int row = sdx >> 4, sl = sdx & 15;
            const bf* src = (MODE == 0)
                ? Adj + ((long)g << 14) + row * 128 + sl * 8
                : Zg + row * 256 + h * 128 + sl * 8;
            *(s8*)&sStg[swz128(row, sl)] = *(const s8*)src;
        }
        __syncthreads();
        if (MODE == 0) {
#pragma unroll
            for (int fr = 0; fr < 4; ++fr)
#pragma unroll
                for (int fc = 0; fc < 2; ++fc) acc2[fr][fc] = f4{0.f, 0.f, 0.f, 0.f};
        }
#pragma unroll
        for (int ks = 0; ks < 4; ++ks) {
            s8 af[4], bg[2];
#pragma unroll
            for (int f = 0; f < 4; ++f)
                af[f] = *(const s8*)&sStg[swz128(wm * 64 + f * 16 + l15, ks * 4 + kq)];
#pragma unroll
            for (int f = 0; f < 2; ++f)
                bg[f] = *(const s8*)&sOut[swz128(wn * 32 + f * 16 + l15, ks * 4 + kq)];
#pragma unroll
            for (int fr = 0; fr < 4; ++fr)
#pragma unroll
                for (int fc = 0; fc < 2; ++fc)
                    acc2[fr][fc] = __builtin_amdgcn_mfma_f32_16x16x32_bf16(
                        af[fr], bg[fc], acc2[fr][fc], 0, 0, 0);
        }
        if (MODE == 0) {
            // write AG (bf16 row-major, cols h*128..) + BN partials for this half
            float ps[2] = {0.f, 0.f}, ps2[2] = {0.f, 0.f};
#pragma unroll
            for (int fr = 0; fr < 4; ++fr) {
                int rl = wm * 64 + fr * 16 + kq * 4;
#pragma unroll
                for (int fc = 0; fc < 2; ++fc) {
                    int cl = wn * 32 + fc * 16 + l15;
#pragma unroll
                    for (int i = 0; i < 4; ++i) {
                        float v = acc2[fr][fc][i];
                        ps[fc] += v; ps2[fc] += v * v;
                        AG[(long)(g * 128 + rl + i) * 256 + h * 128 + cl] = f2bf(v);
                    }
                }
            }
            __syncthreads();           // sStg free -> scr
            float* scr = (float*)sStg; // [col 128][wm 2][stat 2]
#pragma unroll
            for (int fc = 0; fc < 2; ++fc) {
                ps[fc] += __shfl_xor(ps[fc], 16);  ps[fc] += __shfl_xor(ps[fc], 32);
                ps2[fc] += __shfl_xor(ps2[fc], 16); ps2[fc] += __shfl_xor(ps2[fc], 32);
            }
            if (lane < 16) {
#pragma unroll
                for (int fc = 0; fc < 2; ++fc) {
                    int c = wn * 32 + fc * 16 + lane;
                    scr[(c * 2 + wm) * 2 + 0] = ps[fc];
                    scr[(c * 2 + wm) * 2 + 1] = ps2[fc];
                }
            }
            __syncthreads();
            if (t < 256) {
                int col = t & 127, s = t >> 7;
                part[(long)(h * 256 + g) * 256 + s * 128 + col] =
                    scr[(col * 2 + 0) * 2 + s] + scr[(col * 2 + 1) * 2 + s];
            }
        }
        if (MODE == 1 && h == 1) {
            // acc2[.][.] holds S^T[j=rl+i][i=cl]; write out_adj[g][cl][rl..rl+3]
#pragma unroll
            for (int fr = 0; fr < 4; ++fr) {
                int rl = wm * 64 + fr * 16 + kq * 4;
#pragma unroll
                for (int fc = 0; fc < 2; ++fc) {
                    int cl = wn * 32 + fc * 16 + l15;
                    float4 o;
                    float vv[4];
#pragma unroll
                    for (int i = 0; i < 4; ++i) {
                        float v = 1.f / (1.f + __expf(-acc2[fr][fc][i]));
                        if (cl == rl + i) v = 0.f;
                        vv[i] = v;
                    }
                    o.x = vv[0]; o.y = vv[1]; o.z = vv[2]; o.w = vv[3];
                    *(float4*)&adjout[((long)g << 14) + cl * 128 + rl] = o;
                }
            }
        }
    }
}

// ---------------- batchnorm finalize (parallel, deterministic tree) ----------------
__global__ void k_bnfin(const float* __restrict__ part, float* __restrict__ stats) {
    int ch = blockIdx.x;
    int half = ch >> 7, cc = ch & 127;
    int t = threadIdx.x;
    __shared__ float2 sm[256];
    const float* p = part + (long)(half * 256 + t) * 256;
    sm[t] = make_float2(p[cc], p[128 + cc]);
    __syncthreads();
    for (int s = 128; s > 0; s >>= 1) {
        if (t < s) { sm[t].x += sm[t + s].x; sm[t].y += sm[t + s].y; }
        __syncthreads();
    }
    if (t == 0) {
        float m = sm[0].x / (float)NN;
        float var = sm[0].y / (float)NN - m * m;
        stats[ch]       = m;
        stats[256 + ch] = rsqrtf(var + 1e-5f);
    }
}

// relu(relu(BN(x)) + res)
__global__ void k_apply(const bf* __restrict__ X, const float* __restrict__ stats,
                        const float* __restrict__ gam, const float* __restrict__ bet,
                        const bf* __restrict__ res, bf* __restrict__ Z) {
    long i4 = ((long)blockIdx.x * 256 + threadIdx.x) * 4;
    int c0 = (int)(i4 & 255);
    ushort4 xv = *(const ushort4*)(X + i4);
    ushort4 rv = *(const ushort4*)(res + i4);
    unsigned short xs[4] = {xv.x, xv.y, xv.z, xv.w};
    unsigned short rs[4] = {rv.x, rv.y, rv.z, rv.w};
    unsigned short o[4];
#pragma unroll
    for (int j = 0; j < 4; ++j) {
        int c = c0 + j;
        float v = (u2f(xs[j]) - stats[c]) * stats[256 + c] * gam[c] + bet[c];
        v = fmaxf(v, 0.f) + u2f(rs[j]);
        o[j] = f2u(fmaxf(v, 0.f));
    }
    *(ushort4*)(Z + i4) = make_ushort4(o[0], o[1], o[2], o[3]);
}

// layer-2 apply fused with L2-normalize
__global__ void k_apply_l2(const bf* __restrict__ X, const float* __restrict__ stats,
                           const float* __restrict__ gam, const float* __restrict__ bet,
                           const bf* __restrict__ res, float* __restrict__ outz,
                           bf* __restrict__ Znb) {
    int r = blockIdx.x, c = threadIdx.x;
    long i = (long)r * 256 + c;
    float v = (bf2f(X[i]) - stats[c]) * stats[256 + c] * gam[c] + bet[c];
    v = fmaxf(v, 0.f) + bf2f(res[i]);
    v = fmaxf(v, 0.f);
    float s = v * v;
#pragma unroll
    for (int o = 32; o > 0; o >>= 1) s += __shfl_down(s, o);
    __shared__ float red[4];
    __shared__ float denom;
    int lane = c & 63, wid = c >> 6;
    if (lane == 0) red[wid] = s;
    __syncthreads();
    if (c == 0) denom = fmaxf(sqrtf(red[0] + red[1] + red[2] + red[3]), 1e-12f);
    __syncthreads();
    float o = v / denom;
    outz[i] = o;
    Znb[i] = f2bf(o);
}

__global__ void k_pool(const bf* __restrict__ Zn, float* __restrict__ outzg,
                       bf* __restrict__ ZGb) {
    int g = blockIdx.x, c = threadIdx.x;
    const bf* p = Zn + (long)g * 32768 + c;
    float m = -3.4e38f;
    for (int r = 0; r < 128; ++r) m = fmaxf(m, bf2f(p[(long)r * 256]));
    outzg[g * 256 + c] = m;
    ZGb[g * 256 + c] = f2bf(m);
}

// ---------------- host ----------------
template <typename TA, int EPI, int OUT, bool PART, bool BNA>
static void MG(hipStream_t st, const void* A, const bf* BT, const float* bias,
               const float* bnstats, const float* bngam, const float* bnbet,
               float* Cf, bf* Cb, float* part,
               int M, int N, int K, int batch, long sA, long sB, long sC, int ldc) {
    dim3 g(N / 128, M / 128, batch);
    mg<TA, EPI, OUT, PART, BNA><<<g, 256, 0, st>>>(A, BT, bias, bnstats, bngam, bnbet,
                                                   Cf, Cb, part, M, N, K, sA, sB, sC, ldc);
}

extern "C" void kernel_launch(void* const* d_in, const int* in_sizes, int n_in,
                              void* d_out, int out_size, void* d_ws, size_t ws_size,
                              hipStream_t stream) {
    const float* x      = (const float*)d_in[0];
    const int*   srcL   = (const int*)d_in[1];
    const int*   dstL   = (const int*)d_in[2];
    const float* gcn_w0 = (const float*)d_in[3];
    const float* bn_g0  = (const float*)d_in[5];
    const float* bn_b0  = (const float*)d_in[6];
    const float* gcn_w1 = (const float*)d_in[7];
    const float* bn_g1  = (const float*)d_in[9];
    const float* bn_b1  = (const float*)d_in[10];
    const float* gcn_w2 = (const float*)d_in[11];
    const float* bn_g2  = (const float*)d_in[13];
    const float* bn_b2  = (const float*)d_in[14];
    const float* sc_w0  = (const float*)d_in[15];
    const float* sc_b0  = (const float*)d_in[16];
    const float* edge_w = (const float*)d_in[17];
    const float* fd_w0  = (const float*)d_in[18];
    const float* fd_b0  = (const float*)d_in[19];
    const float* fd_g0  = (const float*)d_in[20];
    const float* fd_be0 = (const float*)d_in[21];
    const float* fd_w1  = (const float*)d_in[22];
    const float* fd_b1  = (const float*)d_in[23];
    const float* fd_g1  = (const float*)d_in[24];
    const float* fd_be1 = (const float*)d_in[25];
    const float* fd_w2  = (const float*)d_in[26];
    const float* fd_b2  = (const float*)d_in[27];
    const float* ph_w0  = (const float*)d_in[28];
    const float* ph_b0  = (const float*)d_in[29];
    const float* ph_w1  = (const float*)d_in[30];
    const float* ph_b1  = (const float*)d_in[31];

    float* out     = (float*)d_out;
    float* out_z   = out;
    float* out_adj = out + 8388608;
    float* out_xr  = out + 12582912;
    float* out_zg  = out + 16777216;
    float* out_zgm = out + 16842752;

    float* w     = (float*)d_ws;
    float* part  = w;                        // 131072
    float* stats = w + 131072;               // 512
    bf*    wT    = (bf*)(w + 131584);        // 557056 bf16
    bf*    Aadjb = (bf*)(w + 410112);        // 4194304 bf16
    bf*    HT    = (bf*)(w + 2507264);       // 8388608 bf16
    bf*    U1    = (bf*)(w + 6701568);       // 8388608 bf16
    bf*    U2    = (bf*)(w + 10895872);      // 8388608 bf16
    bf*    U3    = (bf*)(w + 15090176);      // 8388608 bf16
    bf*    ZGb   = (bf*)(w + 19284480);      // 65536 bf16
    bf*    P1b   = (bf*)(w + 19317248);      // 65536 bf16

    WTpack pk;
    pk.w[0] = {gcn_w0, 128, 256, 0};
    pk.w[1] = {sc_w0,  128, 256, 32768};
    pk.w[2] = {gcn_w1, 256, 256, 65536};
    pk.w[3] = {gcn_w2, 256, 256, 131072};
    pk.w[4] = {edge_w, 256, 256, 196608};
    pk.w[5] = {fd_w0,  256, 256, 262144};
    pk.w[6] = {fd_w1,  256, 256, 327680};
    pk.w[7] = {fd_w2,  256, 128, 393216};
    pk.w[8] = {ph_w0,  256, 256, 425984};
    pk.w[9] = {ph_w1,  256, 256, 491520};

    k_adj<<<256, 256, 0, stream>>>(srcL, dstL, Aadjb);
    k_wt<<<dim3(4, 4, 10), 256, 0, stream>>>(pk, wT);

    // --- layer 0: combined [H | shortcut] GEMM over x (N=512), then agg ---
    MG<float,0,4,false,false>(stream, x, wT + 0, sc_b0, nullptr,nullptr,nullptr,
                              (float*)U1, HT, nullptr, NN, 512, 128, 1, 0,0,0, 0);
    MG<bf,0,1,true,false>(stream, Aadjb, HT, nullptr, nullptr,nullptr,nullptr,
                          nullptr, U2, part, 128, HD, 128, 256, 16384, 32768, 32768, 256);
    k_bnfin<<<256, 256, 0, stream>>>(part, stats);
    k_apply<<<8192, 256, 0, stream>>>(U2, stats, bn_g0, bn_b0, U1, U3);   // Z0 in U3

    // --- layer 1 (fused) ---
    k_fused2<0><<<256, 512, 0, stream>>>(U3, wT + 65536, Aadjb, U1, part, nullptr);
    k_bnfin<<<256, 256, 0, stream>>>(part, stats);
    k_apply<<<8192, 256, 0, stream>>>(U1, stats, bn_g1, bn_b1, U3, U2);   // Z1 in U2

    // --- layer 2 (fused) ---
    k_fused2<0><<<256, 512, 0, stream>>>(U2, wT + 131072, Aadjb, U1, part, nullptr);
    k_bnfin<<<256, 256, 0, stream>>>(part, stats);
    k_apply_l2<<<32768, 256, 0, stream>>>(U1, stats, bn_g2, bn_b2, U2, out_z, U3);

    // --- edge decoder (fused) ---
    k_fused2<1><<<256, 512, 0, stream>>>(U3, wT + 196608, nullptr, nullptr, nullptr,
                                         out_adj);

    // --- feature decoder ---
    MG<bf,2,1,true,false>(stream, U3, wT + 262144, fd_b0, nullptr,nullptr,nullptr,
                          nullptr, U2, part, NN, HD, HD, 1, 0,0,0, 256);
    k_bnfin<<<256, 256, 0, stream>>>(part, stats);
    MG<bf,2,1,true,true>(stream, U2, wT + 327680, fd_b1, stats, fd_g0, fd_be0,
                         nullptr, U1, part, NN, HD, HD, 1, 0,0,0, 256);
    k_bnfin<<<256, 256, 0, stream>>>(part, stats);
    MG<bf,1,0,false,true>(stream, U1, wT + 393216, fd_b2, stats, fd_g1, fd_be1,
                          out_xr, nullptr, nullptr, NN, 128, HD, 1, 0,0,0, 128);

    // --- pooling head ---
    k_pool<<<256, 256, 0, stream>>>(U3, out_zg, ZGb);
    MG<bf,2,1,false,false>(stream, ZGb, wT + 425984, ph_b0, nullptr,nullptr,nullptr,
                           nullptr, P1b, nullptr, 256, 256, 256, 1, 0,0,0, 256);
    MG<bf,1,0,false,false>(stream, P1b, wT + 491520, ph_b1, nullptr,nullptr,nullptr,
                           out_zgm, nullptr, nullptr, 256, 256, 256, 1, 0,0,0, 256);
}

// Round 8
// 222.753 us; speedup vs baseline: 4.8274x; 1.1008x over previous
//
#include <hip/hip_runtime.h>
#include <hip/hip_bf16.h>

using bf = __hip_bfloat16;
typedef __attribute__((ext_vector_type(8))) short s8;
typedef __attribute__((ext_vector_type(4))) float f4;

constexpr int NN  = 32768;
constexpr int HD  = 256;

__device__ __forceinline__ float u2f(unsigned short h) {
    union { unsigned u; float f; } x; x.u = ((unsigned)h) << 16;
    return x.f;
}
__device__ __forceinline__ unsigned short f2u(float f) {
    union { float f; unsigned u; } x; x.f = f;
    unsigned r = x.u + 0x7FFF + ((x.u >> 16) & 1);
    return (unsigned short)(r >> 16);
}
__device__ __forceinline__ bf f2bf(float f) {
    unsigned short h = f2u(f);
    return *reinterpret_cast<bf*>(&h);
}
__device__ __forceinline__ float bf2f(bf b) {
    return u2f(*reinterpret_cast<unsigned short*>(&b));
}

__device__ __forceinline__ int swz(int row, int slot) {      // 64-col rows
    return row * 64 + ((slot ^ (row & 7)) << 3);
}
__device__ __forceinline__ int swz128(int row, int slot) {   // 128-col rows
    return row * 128 + ((slot ^ (row & 7)) << 3);
}

// ---------------- adjacency build ----------------
__global__ __launch_bounds__(256) void k_adj(const int* __restrict__ srcL,
                                             const int* __restrict__ dstL,
                                             bf* __restrict__ A) {
    __shared__ float sT[128 * 64];
    __shared__ float sdin[128];
    int g = blockIdx.x, t = threadIdx.x;
    const int* sg = srcL + (g << 11);
    const int* dg = dstL + (g << 11);
    if (t < 128) sdin[t] = 0.f;
    __syncthreads();
    for (int e = t; e < 2048; e += 256) atomicAdd(&sdin[dg[e]], 1.0f);
    __syncthreads();
    if (t < 128) sdin[t] = rsqrtf(sdin[t] + 1.0f);
    __syncthreads();
    bf* out = A + ((long)g << 14);
    for (int half = 0; half < 2; ++half) {
        for (int i = t; i < 8192; i += 256) sT[i] = 0.f;
        __syncthreads();
        for (int e = t; e < 2048; e += 256) {
            int s = sg[e], d = dg[e];
            if ((s >> 6) == half)
                atomicAdd(&sT[(d << 6) + (s & 63)], sdin[s] * sdin[d]);
        }
        __syncthreads();
        if (t < 128 && (t >> 6) == half)
            sT[(t << 6) + (t & 63)] += sdin[t] * sdin[t];
        __syncthreads();
        for (int i4 = t; i4 < 2048; i4 += 256) {
            int d = i4 >> 4, c4 = (i4 & 15) * 4;
            float4 v = *(float4*)&sT[(d << 6) + c4];
            ushort4 u = make_ushort4(f2u(v.x), f2u(v.y), f2u(v.z), f2u(v.w));
            *(ushort4*)&out[(d << 7) + (half << 6) + c4] = u;
        }
        __syncthreads();
    }
}

// ---------------- weight transpose f32 [K x N] -> bf16 [N x K] ----------------
struct WTd { const float* src; int K, N, off; };
struct WTpack { WTd w[10]; };
__global__ void k_wt(WTpack p, bf* __restrict__ out) {
    WTd d = p.w[blockIdx.z];
    int n0 = blockIdx.x * 64, k0 = blockIdx.y * 64;
    if (n0 >= d.N || k0 >= d.K) return;
    __shared__ float s[64][65];
    int t = threadIdx.x;
    int cc = t & 63, rq = t >> 6;
#pragma unroll
    for (int i = 0; i < 16; ++i) {
        int r = i * 4 + rq;
        s[r][cc] = d.src[(long)(k0 + r) * d.N + n0 + cc];
    }
    __syncthreads();
#pragma unroll
    for (int i = 0; i < 16; ++i) {
        int r = i * 4 + rq;
        out[d.off + (long)(n0 + r) * d.K + k0 + cc] = f2bf(s[cc][r]);
    }
}

// ---------------- MFMA GEMM (fd / ph chains) ----------------
// C = A[M x K] @ BT[N x K]^T. EPI: 1 +bias, 2 +bias+relu. OUT: 0 f32, 1 bf16.
// PART: fused BN partials.  BNA: z = x*sc + sh applied to A during staging.
template <int EPI, int OUT, bool PART, bool BNA>
__global__ __launch_bounds__(256) void mg(
    const bf* __restrict__ A, const bf* __restrict__ BT,
    const float* __restrict__ bias, const float* __restrict__ bnstats,
    float* __restrict__ Cf, bf* __restrict__ Cb, float* __restrict__ part,
    int M, int N, int K, int ldc) {
    __shared__ __align__(16) bf sAl[128 * 64];
    __shared__ __align__(16) bf sBl[128 * 64];
    const int m0 = blockIdx.y * 128, n0 = blockIdx.x * 128;
    const bf* Ab = A + (long)m0 * K;
    const bf* Bb = BT + (long)n0 * K;
    const int t = threadIdx.x;
    const int lane = t & 63;
    const int w = t >> 6;
    const int wm = (w >> 1) * 64, wn = (w & 1) * 64;
    const int fr16 = lane & 15, kq = lane >> 4;
    f4 acc[4][4] = {};
    for (int k0 = 0; k0 < K; k0 += 64) {
#pragma unroll
        for (int i = 0; i < 4; ++i) {
            int sdx = i * 256 + t;
            int row = sdx >> 3, sl = sdx & 7;
            s8 av = *(const s8*)&Ab[(long)row * K + k0 + sl * 8];
            if constexpr (BNA) {
                int c = k0 + sl * 8;
                float4 sc0 = *(const float4*)&bnstats[c];
                float4 sc1 = *(const float4*)&bnstats[c + 4];
                float4 sh0 = *(const float4*)&bnstats[256 + c];
                float4 sh1 = *(const float4*)&bnstats[256 + c + 4];
                float scv[8] = {sc0.x, sc0.y, sc0.z, sc0.w, sc1.x, sc1.y, sc1.z, sc1.w};
                float shv[8] = {sh0.x, sh0.y, sh0.z, sh0.w, sh1.x, sh1.y, sh1.z, sh1.w};
                unsigned short* u = (unsigned short*)&av;
#pragma unroll
                for (int j = 0; j < 8; ++j)
                    u[j] = f2u(fmaf(u2f(u[j]), scv[j], shv[j]));
            }
            *(s8*)&sAl[swz(row, sl)] = av;
            *(s8*)&sBl[swz(row, sl)] = *(const s8*)&Bb[(long)row * K + k0 + sl * 8];
        }
        __syncthreads();
#pragma unroll
        for (int ks = 0; ks < 2; ++ks) {
            s8 af[4], bg[4];
#pragma unroll
            for (int f = 0; f < 4; ++f) {
                af[f] = *(const s8*)&sAl[swz(wm + f * 16 + fr16, kq + 4 * ks)];
                bg[f] = *(const s8*)&sBl[swz(wn + f * 16 + fr16, kq + 4 * ks)];
            }
#pragma unroll
            for (int fr = 0; fr < 4; ++fr)
#pragma unroll
                for (int fc = 0; fc < 4; ++fc)
                    acc[fr][fc] = __builtin_amdgcn_mfma_f32_16x16x32_bf16(
                        af[fr], bg[fc], acc[fr][fc], 0, 0, 0);
        }
        __syncthreads();
    }
    float ps[4], ps2[4];
    if (PART) {
#pragma unroll
        for (int fc = 0; fc < 4; ++fc) { ps[fc] = 0.f; ps2[fc] = 0.f; }
    }
#pragma unroll
    for (int fr = 0; fr < 4; ++fr) {
        int rl = wm + fr * 16 + (lane >> 4) * 4;
#pragma unroll
        for (int fc = 0; fc < 4; ++fc) {
            int cl = wn + fc * 16 + (lane & 15);
            int col = n0 + cl;
            float bv = bias[col];
#pragma unroll
            for (int i = 0; i < 4; ++i) {
                float v = acc[fr][fc][i] + bv;
                if (EPI == 2) v = fmaxf(v, 0.f);
                if (PART) { ps[fc] += v; ps2[fc] += v * v; }
                if (OUT == 0) Cf[(long)(m0 + rl + i) * ldc + col] = v;
                if (OUT == 1) Cb[(long)(m0 + rl + i) * ldc + col] = f2bf(v);
            }
        }
    }
    if (PART) {
        __syncthreads();
        float* scr = (float*)sAl;
#pragma unroll
        for (int fc = 0; fc < 4; ++fc) {
            ps[fc] += __shfl_xor(ps[fc], 16);  ps[fc] += __shfl_xor(ps[fc], 32);
            ps2[fc] += __shfl_xor(ps2[fc], 16); ps2[fc] += __shfl_xor(ps2[fc], 32);
        }
        if (lane < 16) {
#pragma unroll
            for (int fc = 0; fc < 4; ++fc) {
                scr[(w * 2 + 0) * 64 + fc * 16 + lane] = ps[fc];
                scr[(w * 2 + 1) * 64 + fc * 16 + lane] = ps2[fc];
            }
        }
        __syncthreads();
        int id = blockIdx.x * gridDim.y + blockIdx.y;   // gridDim = (2, 256)
        int stat = t >> 7, c = t & 127;
        int ci = c & 63, half = c >> 6;
        float v = scr[(half * 2 + stat) * 64 + ci] + scr[((half + 2) * 2 + stat) * 64 + ci];
        part[(long)id * 256 + stat * 128 + c] = v;
    }
}

// ---------------- fused per-graph kernels ----------------
// MODE 0: GCN layer w/ BN-fused staging:
//   Z = relu(relu(Xag*sc+sh) + Res)  (computed during stage-1 staging, written h==0)
//   AG = Aadj @ (Z @ W) + BN partials
// MODE 1: edge decoder: adjout = sigmoid(Zn @ ew @ Zn^T), zero diag
// MODE 2: layer 0: H = x@w0 -> AG = Aadj@H (+partials); ResOut = x@sc_w + b
// 512 threads = 8 waves (2 M x 4 N). LDS 64KB.
template <int MODE>
__global__ __launch_bounds__(512) void k_fused(
    const bf* __restrict__ Xin, const float* __restrict__ xf,
    const bf* __restrict__ Res, const float* __restrict__ stats,
    const bf* __restrict__ Wt, const bf* __restrict__ Wt2,
    const float* __restrict__ scb, const bf* __restrict__ Adj,
    bf* __restrict__ Zout, bf* __restrict__ AG, bf* __restrict__ ResOut,
    float* __restrict__ part, float* __restrict__ adjout) {
    __shared__ __align__(16) bf sOut[128 * 128];
    __shared__ __align__(16) bf sStg[128 * 128];
    const int g = blockIdx.x;
    const int t = threadIdx.x;
    const int lane = t & 63, w = t >> 6;
    const int wm = w >> 2, wn = w & 3;
    const int l15 = lane & 15, kq = lane >> 4;
    constexpr int NPH = (MODE == 2) ? 4 : 2;
    constexpr int KS1 = (MODE == 2) ? 128 : 256;
    const bf* Xg = (MODE == 1) ? Xin + (long)g * 32768
                               : (MODE == 0 ? Xin + (long)g * 32768 : nullptr);
    const bf* Rg = (MODE == 0) ? Res + (long)g * 32768 : nullptr;
    f4 acc2[4][2] = {};
    for (int h = 0; h < NPH; ++h) {
        // ---- stage 1 ----
        f4 acc1[4][2] = {};
        for (int k0 = 0; k0 < KS1; k0 += 64) {
            __syncthreads();
#pragma unroll
            for (int i = 0; i < 2; ++i) {
                int sdx = i * 512 + t;
                int row = sdx >> 3, sl = sdx & 7;
                int c = k0 + sl * 8;
                s8 av;
                if constexpr (MODE == 0) {
                    av = *(const s8*)&Xg[row * 256 + c];
                    s8 rv = *(const s8*)&Rg[row * 256 + c];
                    float4 sc0 = *(const float4*)&stats[c];
                    float4 sc1 = *(const float4*)&stats[c + 4];
                    float4 sh0 = *(const float4*)&stats[256 + c];
                    float4 sh1 = *(const float4*)&stats[256 + c + 4];
                    float scv[8] = {sc0.x, sc0.y, sc0.z, sc0.w, sc1.x, sc1.y, sc1.z, sc1.w};
                    float shv[8] = {sh0.x, sh0.y, sh0.z, sh0.w, sh1.x, sh1.y, sh1.z, sh1.w};
                    unsigned short* u = (unsigned short*)&av;
                    const unsigned short* ru = (const unsigned short*)&rv;
#pragma unroll
                    for (int j = 0; j < 8; ++j) {
                        float v = fmaf(u2f(u[j]), scv[j], shv[j]);
                        v = fmaxf(v, 0.f) + u2f(ru[j]);
                        u[j] = f2u(fmaxf(v, 0.f));
                    }
                    if (h == 0)
                        *(s8*)&Zout[(long)g * 32768 + row * 256 + c] = av;
                } else if constexpr (MODE == 2) {
                    const float* src = xf + ((long)(g * 128 + row)) * 128 + c;
                    float4 f0 = *(const float4*)src;
                    float4 f1 = *(const float4*)(src + 4);
                    unsigned short u[8] = {f2u(f0.x), f2u(f0.y), f2u(f0.z), f2u(f0.w),
                                           f2u(f1.x), f2u(f1.y), f2u(f1.z), f2u(f1.w)};
                    av = *(s8*)u;
                } else {  // MODE 1: A = edge weight rows
                    av = *(const s8*)&Wt[(h * 128 + row) * 256 + c];
                }
                *(s8*)&sStg[swz(row, sl)] = av;
                s8 bv;
                if constexpr (MODE == 0)
                    bv = *(const s8*)&Wt[(h * 128 + row) * 256 + c];
                else if constexpr (MODE == 2) {
                    const bf* Wsrc = (h < 2) ? Wt : Wt2;
                    bv = *(const s8*)&Wsrc[((h & 1) * 128 + row) * 128 + c];
                } else  // MODE 1: B = Zn rows
                    bv = *(const s8*)&Xg[row * 256 + c];
                *(s8*)&sStg[8192 + swz(row, sl)] = bv;
            }
            __syncthreads();
#pragma unroll
            for (int ks = 0; ks < 2; ++ks) {
                s8 af[4], bg[2];
#pragma unroll
                for (int f = 0; f < 4; ++f)
                    af[f] = *(const s8*)&sStg[swz(wm * 64 + f * 16 + l15, kq + 4 * ks)];
#pragma unroll
                for (int f = 0; f < 2; ++f)
                    bg[f] = *(const s8*)&sStg[8192 + swz(wn * 32 + f * 16 + l15, kq + 4 * ks)];
#pragma unroll
                for (int fr = 0; fr < 4; ++fr)
#pragma unroll
                    for (int fc = 0; fc < 2; ++fc)
                        acc1[fr][fc] = __builtin_amdgcn_mfma_f32_16x16x32_bf16(
                            af[fr], bg[fc], acc1[fr][fc], 0, 0, 0);
            }
        }
        if (MODE == 2 && h >= 2) {
            // shortcut: direct row-major write + bias
#pragma unroll
            for (int fr = 0; fr < 4; ++fr) {
                int rl = wm * 64 + fr * 16 + kq * 4;
#pragma unroll
                for (int fc = 0; fc < 2; ++fc) {
                    int cl = wn * 32 + fc * 16 + l15;
                    float bv = scb[(h - 2) * 128 + cl];
#pragma unroll
                    for (int i = 0; i < 4; ++i)
                        ResOut[(long)(g * 128 + rl + i) * 256 + (h - 2) * 128 + cl] =
                            f2bf(acc1[fr][fc][i] + bv);
                }
            }
            continue;
        }
        // transposed store of stage-1 result
#pragma unroll
        for (int fr = 0; fr < 4; ++fr) {
            int rl = wm * 64 + fr * 16 + kq * 4;
#pragma unroll
            for (int fc = 0; fc < 2; ++fc) {
                int cl = wn * 32 + fc * 16 + l15;
                ushort4 q = make_ushort4(f2u(acc1[fr][fc][0]), f2u(acc1[fr][fc][1]),
                                         f2u(acc1[fr][fc][2]), f2u(acc1[fr][fc][3]));
                int off = cl * 128 + (((rl >> 3) ^ (cl & 7)) << 3) + (rl & 7);
                *(ushort4*)&sOut[off] = q;
            }
        }
        __syncthreads();
        // ---- stage 2 staging ----
#pragma unroll
        for (int i = 0; i < 4; ++i) {
            int sdx = i * 512 + t;
            int row = sdx >> 4, sl = sdx & 15;
            const bf* src = (MODE == 1)
                ? Xg + row * 256 + h * 128 + sl * 8
                : Adj + ((long)g << 14) + row * 128 + sl * 8;
            *(s8*)&sStg[swz128(row, sl)] = *(const s8*)src;
        }
        __syncthreads();
        if (MODE != 1) {
#pragma unroll
            for (int fr = 0; fr < 4; ++fr)
#pragma unroll
                for (int fc = 0; fc < 2; ++fc) acc2[fr][fc] = f4{0.f, 0.f, 0.f, 0.f};
        }
#pragma unroll
        for (int ks = 0; ks < 4; ++ks) {
            s8 af[4], bg[2];
#pragma unroll
            for (int f = 0; f < 4; ++f)
                af[f] = *(const s8*)&sStg[swz128(wm * 64 + f * 16 + l15, ks * 4 + kq)];
#pragma unroll
            for (int f = 0; f < 2; ++f)
                bg[f] = *(const s8*)&sOut[swz128(wn * 32 + f * 16 + l15, ks * 4 + kq)];
#pragma unroll
            for (int fr = 0; fr < 4; ++fr)
#pragma unroll
                for (int fc = 0; fc < 2; ++fc)
                    acc2[fr][fc] = __builtin_amdgcn_mfma_f32_16x16x32_bf16(
                        af[fr], bg[fc], acc2[fr][fc], 0, 0, 0);
        }
        if (MODE != 1) {
            float ps[2] = {0.f, 0.f}, ps2[2] = {0.f, 0.f};
#pragma unroll
            for (int fr = 0; fr < 4; ++fr) {
                int rl = wm * 64 + fr * 16 + kq * 4;
#pragma unroll
                for (int fc = 0; fc < 2; ++fc) {
                    int cl = wn * 32 + fc * 16 + l15;
#pragma unroll
                    for (int i = 0; i < 4; ++i) {
                        float v = acc2[fr][fc][i];
                        ps[fc] += v; ps2[fc] += v * v;
                        AG[(long)(g * 128 + rl + i) * 256 + h * 128 + cl] = f2bf(v);
                    }
                }
            }
            __syncthreads();
            float* scr = (float*)sStg;
#pragma unroll
            for (int fc = 0; fc < 2; ++fc) {
                ps[fc] += __shfl_xor(ps[fc], 16);  ps[fc] += __shfl_xor(ps[fc], 32);
                ps2[fc] += __shfl_xor(ps2[fc], 16); ps2[fc] += __shfl_xor(ps2[fc], 32);
            }
            if (lane < 16) {
#pragma unroll
                for (int fc = 0; fc < 2; ++fc) {
                    int c = wn * 32 + fc * 16 + lane;
                    scr[(c * 2 + wm) * 2 + 0] = ps[fc];
                    scr[(c * 2 + wm) * 2 + 1] = ps2[fc];
                }
            }
            __syncthreads();
            if (t < 256) {
                int col = t & 127, s = t >> 7;
                part[(long)(h * 256 + g) * 256 + s * 128 + col] =
                    scr[(col * 2 + 0) * 2 + s] + scr[(col * 2 + 1) * 2 + s];
            }
        }
        if (MODE == 1 && h == 1) {
#pragma unroll
            for (int fr = 0; fr < 4; ++fr) {
                int rl = wm * 64 + fr * 16 + kq * 4;
#pragma unroll
                for (int fc = 0; fc < 2; ++fc) {
                    int cl = wn * 32 + fc * 16 + l15;
                    float vv[4];
#pragma unroll
                    for (int i = 0; i < 4; ++i) {
                        float v = 1.f / (1.f + __expf(-acc2[fr][fc][i]));
                        if (cl == rl + i) v = 0.f;
                        vv[i] = v;
                    }
                    float4 o; o.x = vv[0]; o.y = vv[1]; o.z = vv[2]; o.w = vv[3];
                    *(float4*)&adjout[((long)g << 14) + cl * 128 + rl] = o;
                }
            }
        }
    }
}

// ---------------- batchnorm finalize -> (scale, shift) ----------------
__global__ void k_bnfin(const float* __restrict__ part, const float* __restrict__ gam,
                        const float* __restrict__ bet, float* __restrict__ stats) {
    int ch = blockIdx.x;
    int half = ch >> 7, cc = ch & 127;
    int t = threadIdx.x;
    __shared__ float2 sm[256];
    const float* p = part + (long)(half * 256 + t) * 256;
    sm[t] = make_float2(p[cc], p[128 + cc]);
    __syncthreads();
    for (int s = 128; s > 0; s >>= 1) {
        if (t < s) { sm[t].x += sm[t + s].x; sm[t].y += sm[t + s].y; }
        __syncthreads();
    }
    if (t == 0) {
        float m = sm[0].x / (float)NN;
        float var = sm[0].y / (float)NN - m * m;
        float sc = rsqrtf(var + 1e-5f) * gam[ch];
        stats[ch]       = sc;
        stats[256 + ch] = bet[ch] - m * sc;
    }
}

// layer-2 apply fused with L2-normalize (scale/shift form)
__global__ void k_apply_l2(const bf* __restrict__ X, const float* __restrict__ stats,
                           const bf* __restrict__ res, float* __restrict__ outz,
                           bf* __restrict__ Znb) {
    int r = blockIdx.x, c = threadIdx.x;
    long i = (long)r * 256 + c;
    float v = fmaf(bf2f(X[i]), stats[c], stats[256 + c]);
    v = fmaxf(v, 0.f) + bf2f(res[i]);
    v = fmaxf(v, 0.f);
    float s = v * v;
#pragma unroll
    for (int o = 32; o > 0; o >>= 1) s += __shfl_down(s, o);
    __shared__ float red[4];
    __shared__ float denom;
    int lane = c & 63, wid = c >> 6;
    if (lane == 0) red[wid] = s;
    __syncthreads();
    if (c == 0) denom = fmaxf(sqrtf(red[0] + red[1] + red[2] + red[3]), 1e-12f);
    __syncthreads();
    float o = v / denom;
    outz[i] = o;
    Znb[i] = f2bf(o);
}

__global__ void k_pool(const bf* __restrict__ Zn, float* __restrict__ outzg,
                       bf* __restrict__ ZGb) {
    int g = blockIdx.x, c = threadIdx.x;
    const bf* p = Zn + (long)g * 32768 + c;
    float m = -3.4e38f;
    for (int r = 0; r < 128; ++r) m = fmaxf(m, bf2f(p[(long)r * 256]));
    outzg[g * 256 + c] = m;
    ZGb[g * 256 + c] = f2bf(m);
}

// ---------------- host ----------------
template <int EPI, int OUT, bool PART, bool BNA>
static void MG(hipStream_t st, const bf* A, const bf* BT, const float* bias,
               const float* bnstats, float* Cf, bf* Cb, float* part,
               int M, int N, int K, int ldc) {
    dim3 g(N / 128, M / 128, 1);
    mg<EPI, OUT, PART, BNA><<<g, 256, 0, st>>>(A, BT, bias, bnstats, Cf, Cb, part,
                                               M, N, K, ldc);
}

extern "C" void kernel_launch(void* const* d_in, const int* in_sizes, int n_in,
                              void* d_out, int out_size, void* d_ws, size_t ws_size,
                              hipStream_t stream) {
    const float* x      = (const float*)d_in[0];
    const int*   srcL   = (const int*)d_in[1];
    const int*   dstL   = (const int*)d_in[2];
    const float* gcn_w0 = (const float*)d_in[3];
    const float* bn_g0  = (const float*)d_in[5];
    const float* bn_b0  = (const float*)d_in[6];
    const float* gcn_w1 = (const float*)d_in[7];
    const float* bn_g1  = (const float*)d_in[9];
    const float* bn_b1  = (const float*)d_in[10];
    const float* gcn_w2 = (const float*)d_in[11];
    const float* bn_g2  = (const float*)d_in[13];
    const float* bn_b2  = (const float*)d_in[14];
    const float* sc_w0  = (const float*)d_in[15];
    const float* sc_b0  = (const float*)d_in[16];
    const float* edge_w = (const float*)d_in[17];
    const float* fd_w0  = (const float*)d_in[18];
    const float* fd_b0  = (const float*)d_in[19];
    const float* fd_g0  = (const float*)d_in[20];
    const float* fd_be0 = (const float*)d_in[21];
    const float* fd_w1  = (const float*)d_in[22];
    const float* fd_b1  = (const float*)d_in[23];
    const float* fd_g1  = (const float*)d_in[24];
    const float* fd_be1 = (const float*)d_in[25];
    const float* fd_w2  = (const float*)d_in[26];
    const float* fd_b2  = (const float*)d_in[27];
    const float* ph_w0  = (const float*)d_in[28];
    const float* ph_b0  = (const float*)d_in[29];
    const float* ph_w1  = (const float*)d_in[30];
    const float* ph_b1  = (const float*)d_in[31];

    float* out     = (float*)d_out;
    float* out_z   = out;
    float* out_adj = out + 8388608;
    float* out_xr  = out + 12582912;
    float* out_zg  = out + 16777216;
    float* out_zgm = out + 16842752;

    float* w     = (float*)d_ws;
    float* part  = w;                        // 131072
    float* stats = w + 131072;               // 512
    bf*    wT    = (bf*)(w + 131584);        // 557056 bf16
    bf*    Aadjb = (bf*)(w + 410112);        // 4194304 bf16
    bf*    U4    = (bf*)(w + 2507264);       // 8388608 bf16
    bf*    U1    = (bf*)(w + 6701568);       // 8388608 bf16
    bf*    U2    = (bf*)(w + 10895872);      // 8388608 bf16
    bf*    U3    = (bf*)(w + 15090176);      // 8388608 bf16
    bf*    ZGb   = (bf*)(w + 19284480);      // 65536 bf16
    bf*    P1b   = (bf*)(w + 19317248);      // 65536 bf16

    WTpack pk;
    pk.w[0] = {gcn_w0, 128, 256, 0};
    pk.w[1] = {sc_w0,  128, 256, 32768};
    pk.w[2] = {gcn_w1, 256, 256, 65536};
    pk.w[3] = {gcn_w2, 256, 256, 131072};
    pk.w[4] = {edge_w, 256, 256, 196608};
    pk.w[5] = {fd_w0,  256, 256, 262144};
    pk.w[6] = {fd_w1,  256, 256, 327680};
    pk.w[7] = {fd_w2,  256, 128, 393216};
    pk.w[8] = {ph_w0,  256, 256, 425984};
    pk.w[9] = {ph_w1,  256, 256, 491520};

    k_adj<<<256, 256, 0, stream>>>(srcL, dstL, Aadjb);
    k_wt<<<dim3(4, 4, 10), 256, 0, stream>>>(pk, wT);

    // --- layer 0 (fully fused): AG0 -> U2, res0 -> U1 ---
    k_fused<2><<<256, 512, 0, stream>>>(nullptr, x, nullptr, nullptr,
                                        wT + 0, wT + 32768, sc_b0, Aadjb,
                                        nullptr, U2, U1, part, nullptr);
    k_bnfin<<<256, 256, 0, stream>>>(part, bn_g0, bn_b0, stats);

    // --- layer 1: Z0 -> U3 (byproduct), AG1 -> U4 ---
    k_fused<0><<<256, 512, 0, stream>>>(U2, nullptr, U1, stats,
                                        wT + 65536, nullptr, nullptr, Aadjb,
                                        U3, U4, nullptr, part, nullptr);
    k_bnfin<<<256, 256, 0, stream>>>(part, bn_g1, bn_b1, stats);

    // --- layer 2: Z1 -> U1, AG2 -> U2 ---
    k_fused<0><<<256, 512, 0, stream>>>(U4, nullptr, U3, stats,
                                        wT + 131072, nullptr, nullptr, Aadjb,
                                        U1, U2, nullptr, part, nullptr);
    k_bnfin<<<256, 256, 0, stream>>>(part, bn_g2, bn_b2, stats);

    // --- BN-apply + L2 normalize: AG2 (U2), res Z1 (U1) -> out_z + Zn (U3) ---
    k_apply_l2<<<32768, 256, 0, stream>>>(U2, stats, U1, out_z, U3);

    // --- edge decoder ---
    k_fused<1><<<256, 512, 0, stream>>>(U3, nullptr, nullptr, nullptr,
                                        wT + 196608, nullptr, nullptr, nullptr,
                                        nullptr, nullptr, nullptr, nullptr, out_adj);

    // --- feature decoder ---
    MG<2, 1, true, false>(stream, U3, wT + 262144, fd_b0, nullptr,
                          nullptr, U4, part, NN, HD, HD, 256);
    k_bnfin<<<256, 256, 0, stream>>>(part, fd_g0, fd_be0, stats);
    MG<2, 1, true, true>(stream, U4, wT + 327680, fd_b1, stats,
                         nullptr, U2, part, NN, HD, HD, 256);
    k_bnfin<<<256, 256, 0, stream>>>(part, fd_g1, fd_be1, stats);
    MG<1, 0, false, true>(stream, U2, wT + 393216, fd_b2, stats,
                          out_xr, nullptr, nullptr, NN, 128, HD, 128);

    // --- pooling head ---
    k_pool<<<256, 256, 0, stream>>>(U3, out_zg, ZGb);
    MG<2, 1, false, false>(stream, ZGb, wT + 425984, ph_b0, nullptr,
                           nullptr, P1b, nullptr, 256, 256, 256, 256);
    MG<1, 0, false, false>(stream, P1b, wT + 491520, ph_b1, nullptr,
                           out_zgm, nullptr, nullptr, 256, 256, 256, 256);
}

// Round 9
// 214.345 us; speedup vs baseline: 5.0168x; 1.0392x over previous
//
#include <hip/hip_runtime.h>
#include <hip/hip_bf16.h>

using bf = __hip_bfloat16;
typedef __attribute__((ext_vector_type(8))) short s8;
typedef __attribute__((ext_vector_type(4))) float f4;

constexpr int NN  = 32768;
constexpr int HD  = 256;

__device__ __forceinline__ float u2f(unsigned short h) {
    union { unsigned u; float f; } x; x.u = ((unsigned)h) << 16;
    return x.f;
}
__device__ __forceinline__ unsigned short f2u(float f) {
    union { float f; unsigned u; } x; x.f = f;
    unsigned r = x.u + 0x7FFF + ((x.u >> 16) & 1);
    return (unsigned short)(r >> 16);
}
__device__ __forceinline__ bf f2bf(float f) {
    unsigned short h = f2u(f);
    return *reinterpret_cast<bf*>(&h);
}
__device__ __forceinline__ float bf2f(bf b) {
    return u2f(*reinterpret_cast<unsigned short*>(&b));
}

__device__ __forceinline__ int swz(int row, int slot) {      // 64-col rows
    return row * 64 + ((slot ^ (row & 7)) << 3);
}
__device__ __forceinline__ int swz128(int row, int slot) {   // 128-col rows
    return row * 128 + ((slot ^ (row & 7)) << 3);
}

// ---------------- adjacency build ----------------
__global__ __launch_bounds__(256) void k_adj(const int* __restrict__ srcL,
                                             const int* __restrict__ dstL,
                                             bf* __restrict__ A) {
    __shared__ float sT[128 * 64];
    __shared__ float sdin[128];
    int g = blockIdx.x, t = threadIdx.x;
    const int* sg = srcL + (g << 11);
    const int* dg = dstL + (g << 11);
    if (t < 128) sdin[t] = 0.f;
    __syncthreads();
    for (int e = t; e < 2048; e += 256) atomicAdd(&sdin[dg[e]], 1.0f);
    __syncthreads();
    if (t < 128) sdin[t] = rsqrtf(sdin[t] + 1.0f);
    __syncthreads();
    bf* out = A + ((long)g << 14);
    for (int half = 0; half < 2; ++half) {
        for (int i = t; i < 8192; i += 256) sT[i] = 0.f;
        __syncthreads();
        for (int e = t; e < 2048; e += 256) {
            int s = sg[e], d = dg[e];
            if ((s >> 6) == half)
                atomicAdd(&sT[(d << 6) + (s & 63)], sdin[s] * sdin[d]);
        }
        __syncthreads();
        if (t < 128 && (t >> 6) == half)
            sT[(t << 6) + (t & 63)] += sdin[t] * sdin[t];
        __syncthreads();
        for (int i4 = t; i4 < 2048; i4 += 256) {
            int d = i4 >> 4, c4 = (i4 & 15) * 4;
            float4 v = *(float4*)&sT[(d << 6) + c4];
            ushort4 u = make_ushort4(f2u(v.x), f2u(v.y), f2u(v.z), f2u(v.w));
            *(ushort4*)&out[(d << 7) + (half << 6) + c4] = u;
        }
        __syncthreads();
    }
}

// ---------------- weight transpose f32 [K x N] -> bf16 [N x K] ----------------
struct WTd { const float* src; int K, N, off; };
struct WTpack { WTd w[10]; };
__global__ void k_wt(WTpack p, bf* __restrict__ out) {
    WTd d = p.w[blockIdx.z];
    int n0 = blockIdx.x * 64, k0 = blockIdx.y * 64;
    if (n0 >= d.N || k0 >= d.K) return;
    __shared__ float s[64][65];
    int t = threadIdx.x;
    int cc = t & 63, rq = t >> 6;
#pragma unroll
    for (int i = 0; i < 16; ++i) {
        int r = i * 4 + rq;
        s[r][cc] = d.src[(long)(k0 + r) * d.N + n0 + cc];
    }
    __syncthreads();
#pragma unroll
    for (int i = 0; i < 16; ++i) {
        int r = i * 4 + rq;
        out[d.off + (long)(n0 + r) * d.K + k0 + cc] = f2bf(s[cc][r]);
    }
}

// ---------------- MFMA GEMM (fd / ph chains) ----------------
template <int EPI, int OUT, bool PART, bool BNA>
__global__ __launch_bounds__(256) void mg(
    const bf* __restrict__ A, const bf* __restrict__ BT,
    const float* __restrict__ bias, const float* __restrict__ bnstats,
    float* __restrict__ Cf, bf* __restrict__ Cb, float* __restrict__ part,
    int M, int N, int K, int ldc) {
    __shared__ __align__(16) bf sAl[128 * 64];
    __shared__ __align__(16) bf sBl[128 * 64];
    const int m0 = blockIdx.y * 128, n0 = blockIdx.x * 128;
    const bf* Ab = A + (long)m0 * K;
    const bf* Bb = BT + (long)n0 * K;
    const int t = threadIdx.x;
    const int lane = t & 63;
    const int w = t >> 6;
    const int wm = (w >> 1) * 64, wn = (w & 1) * 64;
    const int fr16 = lane & 15, kq = lane >> 4;
    f4 acc[4][4] = {};
    for (int k0 = 0; k0 < K; k0 += 64) {
#pragma unroll
        for (int i = 0; i < 4; ++i) {
            int sdx = i * 256 + t;
            int row = sdx >> 3, sl = sdx & 7;
            s8 av = *(const s8*)&Ab[(long)row * K + k0 + sl * 8];
            if constexpr (BNA) {
                int c = k0 + sl * 8;
                float4 sc0 = *(const float4*)&bnstats[c];
                float4 sc1 = *(const float4*)&bnstats[c + 4];
                float4 sh0 = *(const float4*)&bnstats[256 + c];
                float4 sh1 = *(const float4*)&bnstats[256 + c + 4];
                float scv[8] = {sc0.x, sc0.y, sc0.z, sc0.w, sc1.x, sc1.y, sc1.z, sc1.w};
                float shv[8] = {sh0.x, sh0.y, sh0.z, sh0.w, sh1.x, sh1.y, sh1.z, sh1.w};
                unsigned short* u = (unsigned short*)&av;
#pragma unroll
                for (int j = 0; j < 8; ++j)
                    u[j] = f2u(fmaf(u2f(u[j]), scv[j], shv[j]));
            }
            *(s8*)&sAl[swz(row, sl)] = av;
            *(s8*)&sBl[swz(row, sl)] = *(const s8*)&Bb[(long)row * K + k0 + sl * 8];
        }
        __syncthreads();
#pragma unroll
        for (int ks = 0; ks < 2; ++ks) {
            s8 af[4], bg[4];
#pragma unroll
            for (int f = 0; f < 4; ++f) {
                af[f] = *(const s8*)&sAl[swz(wm + f * 16 + fr16, kq + 4 * ks)];
                bg[f] = *(const s8*)&sBl[swz(wn + f * 16 + fr16, kq + 4 * ks)];
            }
#pragma unroll
            for (int fr = 0; fr < 4; ++fr)
#pragma unroll
                for (int fc = 0; fc < 4; ++fc)
                    acc[fr][fc] = __builtin_amdgcn_mfma_f32_16x16x32_bf16(
                        af[fr], bg[fc], acc[fr][fc], 0, 0, 0);
        }
        __syncthreads();
    }
    float ps[4], ps2[4];
    if (PART) {
#pragma unroll
        for (int fc = 0; fc < 4; ++fc) { ps[fc] = 0.f; ps2[fc] = 0.f; }
    }
#pragma unroll
    for (int fr = 0; fr < 4; ++fr) {
        int rl = wm + fr * 16 + (lane >> 4) * 4;
#pragma unroll
        for (int fc = 0; fc < 4; ++fc) {
            int cl = wn + fc * 16 + (lane & 15);
            int col = n0 + cl;
            float bv = bias[col];
#pragma unroll
            for (int i = 0; i < 4; ++i) {
                float v = acc[fr][fc][i] + bv;
                if (EPI == 2) v = fmaxf(v, 0.f);
                if (PART) { ps[fc] += v; ps2[fc] += v * v; }
                if (OUT == 0) Cf[(long)(m0 + rl + i) * ldc + col] = v;
                if (OUT == 1) Cb[(long)(m0 + rl + i) * ldc + col] = f2bf(v);
            }
        }
    }
    if (PART) {
        __syncthreads();
        float* scr = (float*)sAl;
#pragma unroll
        for (int fc = 0; fc < 4; ++fc) {
            ps[fc] += __shfl_xor(ps[fc], 16);  ps[fc] += __shfl_xor(ps[fc], 32);
            ps2[fc] += __shfl_xor(ps2[fc], 16); ps2[fc] += __shfl_xor(ps2[fc], 32);
        }
        if (lane < 16) {
#pragma unroll
            for (int fc = 0; fc < 4; ++fc) {
                scr[(w * 2 + 0) * 64 + fc * 16 + lane] = ps[fc];
                scr[(w * 2 + 1) * 64 + fc * 16 + lane] = ps2[fc];
            }
        }
        __syncthreads();
        int id = blockIdx.x * gridDim.y + blockIdx.y;   // gridDim = (2, 256)
        int stat = t >> 7, c = t & 127;
        int ci = c & 63, half = c >> 6;
        float v = scr[(half * 2 + stat) * 64 + ci] + scr[((half + 2) * 2 + stat) * 64 + ci];
        part[(long)id * 256 + stat * 128 + c] = v;
    }
}

// ---------------- fused per-graph kernels ----------------
// MODE 0 (grid 256x2): phase hb = blockIdx.y (independent col-halves)
// MODE 2 (grid 256x4): phases 0,1 = GCN halves; 2,3 = shortcut halves
// MODE 1 (grid 256x1): edge decoder, internal h loop (acc2 accumulates)
template <int MODE>
__global__ __launch_bounds__(512) void k_fused(
    const bf* __restrict__ Xin, const float* __restrict__ xf,
    const bf* __restrict__ Res, const float* __restrict__ stats,
    const bf* __restrict__ Wt, const bf* __restrict__ Wt2,
    const float* __restrict__ scb, const bf* __restrict__ Adj,
    bf* __restrict__ Zout, bf* __restrict__ AG, bf* __restrict__ ResOut,
    float* __restrict__ part, float* __restrict__ adjout) {
    __shared__ __align__(16) bf sOut[128 * 128];
    __shared__ __align__(16) bf sStg[128 * 128];
    const int g = blockIdx.x;
    const int hb = blockIdx.y;
    const int t = threadIdx.x;
    const int lane = t & 63, w = t >> 6;
    const int wm = w >> 2, wn = w & 3;
    const int l15 = lane & 15, kq = lane >> 4;
    constexpr int KS1 = (MODE == 2) ? 128 : 256;
    const int h0 = (MODE == 1) ? 0 : hb;
    const int h1 = (MODE == 1) ? 2 : hb + 1;
    const bf* Xg = (MODE != 2) ? Xin + (long)g * 32768 : nullptr;
    const bf* Rg = (MODE == 0) ? Res + (long)g * 32768 : nullptr;
    f4 acc2[4][2] = {};
    for (int h = h0; h < h1; ++h) {
        // ---- stage 1 ----
        f4 acc1[4][2] = {};
        for (int k0 = 0; k0 < KS1; k0 += 64) {
            __syncthreads();
#pragma unroll
            for (int i = 0; i < 2; ++i) {
                int sdx = i * 512 + t;
                int row = sdx >> 3, sl = sdx & 7;
                int c = k0 + sl * 8;
                s8 av;
                if constexpr (MODE == 0) {
                    av = *(const s8*)&Xg[row * 256 + c];
                    s8 rv = *(const s8*)&Rg[row * 256 + c];
                    float4 sc0 = *(const float4*)&stats[c];
                    float4 sc1 = *(const float4*)&stats[c + 4];
                    float4 sh0 = *(const float4*)&stats[256 + c];
                    float4 sh1 = *(const float4*)&stats[256 + c + 4];
                    float scv[8] = {sc0.x, sc0.y, sc0.z, sc0.w, sc1.x, sc1.y, sc1.z, sc1.w};
                    float shv[8] = {sh0.x, sh0.y, sh0.z, sh0.w, sh1.x, sh1.y, sh1.z, sh1.w};
                    unsigned short* u = (unsigned short*)&av;
                    const unsigned short* ru = (const unsigned short*)&rv;
#pragma unroll
                    for (int j = 0; j < 8; ++j) {
                        float v = fmaf(u2f(u[j]), scv[j], shv[j]);
                        v = fmaxf(v, 0.f) + u2f(ru[j]);
                        u[j] = f2u(fmaxf(v, 0.f));
                    }
                    if (h == 0)
                        *(s8*)&Zout[(long)g * 32768 + row * 256 + c] = av;
                } else if constexpr (MODE == 2) {
                    const float* src = xf + ((long)(g * 128 + row)) * 128 + c;
                    float4 f0 = *(const float4*)src;
                    float4 f1 = *(const float4*)(src + 4);
                    unsigned short u[8] = {f2u(f0.x), f2u(f0.y), f2u(f0.z), f2u(f0.w),
                                           f2u(f1.x), f2u(f1.y), f2u(f1.z), f2u(f1.w)};
                    av = *(s8*)u;
                } else {  // MODE 1
                    av = *(const s8*)&Wt[(h * 128 + row) * 256 + c];
                }
                *(s8*)&sStg[swz(row, sl)] = av;
                s8 bv;
                if constexpr (MODE == 0)
                    bv = *(const s8*)&Wt[(h * 128 + row) * 256 + c];
                else if constexpr (MODE == 2) {
                    const bf* Wsrc = (h < 2) ? Wt : Wt2;
                    bv = *(const s8*)&Wsrc[((h & 1) * 128 + row) * 128 + c];
                } else  // MODE 1
                    bv = *(const s8*)&Xg[row * 256 + c];
                *(s8*)&sStg[8192 + swz(row, sl)] = bv;
            }
            __syncthreads();
#pragma unroll
            for (int ks = 0; ks < 2; ++ks) {
                s8 af[4], bg[2];
#pragma unroll
                for (int f = 0; f < 4; ++f)
                    af[f] = *(const s8*)&sStg[swz(wm * 64 + f * 16 + l15, kq + 4 * ks)];
#pragma unroll
                for (int f = 0; f < 2; ++f)
                    bg[f] = *(const s8*)&sStg[8192 + swz(wn * 32 + f * 16 + l15, kq + 4 * ks)];
#pragma unroll
                for (int fr = 0; fr < 4; ++fr)
#pragma unroll
                    for (int fc = 0; fc < 2; ++fc)
                        acc1[fr][fc] = __builtin_amdgcn_mfma_f32_16x16x32_bf16(
                            af[fr], bg[fc], acc1[fr][fc], 0, 0, 0);
            }
        }
        if (MODE == 2 && h >= 2) {
#pragma unroll
            for (int fr = 0; fr < 4; ++fr) {
                int rl = wm * 64 + fr * 16 + kq * 4;
#pragma unroll
                for (int fc = 0; fc < 2; ++fc) {
                    int cl = wn * 32 + fc * 16 + l15;
                    float bv = scb[(h - 2) * 128 + cl];
#pragma unroll
                    for (int i = 0; i < 4; ++i)
                        ResOut[(long)(g * 128 + rl + i) * 256 + (h - 2) * 128 + cl] =
                            f2bf(acc1[fr][fc][i] + bv);
                }
            }
            continue;
        }
        // transposed store of stage-1 result
#pragma unroll
        for (int fr = 0; fr < 4; ++fr) {
            int rl = wm * 64 + fr * 16 + kq * 4;
#pragma unroll
            for (int fc = 0; fc < 2; ++fc) {
                int cl = wn * 32 + fc * 16 + l15;
                ushort4 q = make_ushort4(f2u(acc1[fr][fc][0]), f2u(acc1[fr][fc][1]),
                                         f2u(acc1[fr][fc][2]), f2u(acc1[fr][fc][3]));
                int off = cl * 128 + (((rl >> 3) ^ (cl & 7)) << 3) + (rl & 7);
                *(ushort4*)&sOut[off] = q;
            }
        }
        __syncthreads();
        // ---- stage 2 staging ----
#pragma unroll
        for (int i = 0; i < 4; ++i) {
            int sdx = i * 512 + t;
            int row = sdx >> 4, sl = sdx & 15;
            const bf* src = (MODE == 1)
                ? Xg + row * 256 + h * 128 + sl * 8
                : Adj + ((long)g << 14) + row * 128 + sl * 8;
            *(s8*)&sStg[swz128(row, sl)] = *(const s8*)src;
        }
        __syncthreads();
        if (MODE != 1) {
#pragma unroll
            for (int fr = 0; fr < 4; ++fr)
#pragma unroll
                for (int fc = 0; fc < 2; ++fc) acc2[fr][fc] = f4{0.f, 0.f, 0.f, 0.f};
        }
#pragma unroll
        for (int ks = 0; ks < 4; ++ks) {
            s8 af[4], bg[2];
#pragma unroll
            for (int f = 0; f < 4; ++f)
                af[f] = *(const s8*)&sStg[swz128(wm * 64 + f * 16 + l15, ks * 4 + kq)];
#pragma unroll
            for (int f = 0; f < 2; ++f)
                bg[f] = *(const s8*)&sOut[swz128(wn * 32 + f * 16 + l15, ks * 4 + kq)];
#pragma unroll
            for (int fr = 0; fr < 4; ++fr)
#pragma unroll
                for (int fc = 0; fc < 2; ++fc)
                    acc2[fr][fc] = __builtin_amdgcn_mfma_f32_16x16x32_bf16(
                        af[fr], bg[fc], acc2[fr][fc], 0, 0, 0);
        }
        if (MODE != 1) {
            float ps[2] = {0.f, 0.f}, ps2[2] = {0.f, 0.f};
#pragma unroll
            for (int fr = 0; fr < 4; ++fr) {
                int rl = wm * 64 + fr * 16 + kq * 4;
#pragma unroll
                for (int fc = 0; fc < 2; ++fc) {
                    int cl = wn * 32 + fc * 16 + l15;
#pragma unroll
                    for (int i = 0; i < 4; ++i) {
                        float v = acc2[fr][fc][i];
                        ps[fc] += v; ps2[fc] += v * v;
                        AG[(long)(g * 128 + rl + i) * 256 + h * 128 + cl] = f2bf(v);
                    }
                }
            }
            __syncthreads();
            float* scr = (float*)sStg;
#pragma unroll
            for (int fc = 0; fc < 2; ++fc) {
                ps[fc] += __shfl_xor(ps[fc], 16);  ps[fc] += __shfl_xor(ps[fc], 32);
                ps2[fc] += __shfl_xor(ps2[fc], 16); ps2[fc] += __shfl_xor(ps2[fc], 32);
            }
            if (lane < 16) {
#pragma unroll
                for (int fc = 0; fc < 2; ++fc) {
                    int c = wn * 32 + fc * 16 + lane;
                    scr[(c * 2 + wm) * 2 + 0] = ps[fc];
                    scr[(c * 2 + wm) * 2 + 1] = ps2[fc];
                }
            }
            __syncthreads();
            if (t < 256) {
                int col = t & 127, s = t >> 7;
                part[(long)(h * 256 + g) * 256 + s * 128 + col] =
                    scr[(col * 2 + 0) * 2 + s] + scr[(col * 2 + 1) * 2 + s];
            }
        }
        if (MODE == 1 && h == 1) {
#pragma unroll
            for (int fr = 0; fr < 4; ++fr) {
                int rl = wm * 64 + fr * 16 + kq * 4;
#pragma unroll
                for (int fc = 0; fc < 2; ++fc) {
                    int cl = wn * 32 + fc * 16 + l15;
                    float vv[4];
#pragma unroll
                    for (int i = 0; i < 4; ++i) {
                        float v = 1.f / (1.f + __expf(-acc2[fr][fc][i]));
                        if (cl == rl + i) v = 0.f;
                        vv[i] = v;
                    }
                    float4 o; o.x = vv[0]; o.y = vv[1]; o.z = vv[2]; o.w = vv[3];
                    *(float4*)&adjout[((long)g << 14) + cl * 128 + rl] = o;
                }
            }
        }
    }
}

// ---------------- batchnorm finalize -> (scale, shift) ----------------
__global__ void k_bnfin(const float* __restrict__ part, const float* __restrict__ gam,
                        const float* __restrict__ bet, float* __restrict__ stats) {
    int ch = blockIdx.x;
    int half = ch >> 7, cc = ch & 127;
    int t = threadIdx.x;
    __shared__ float2 sm[256];
    const float* p = part + (long)(half * 256 + t) * 256;
    sm[t] = make_float2(p[cc], p[128 + cc]);
    __syncthreads();
    for (int s = 128; s > 0; s >>= 1) {
        if (t < s) { sm[t].x += sm[t + s].x; sm[t].y += sm[t + s].y; }
        __syncthreads();
    }
    if (t == 0) {
        float m = sm[0].x / (float)NN;
        float var = sm[0].y / (float)NN - m * m;
        float sc = rsqrtf(var + 1e-5f) * gam[ch];
        stats[ch]       = sc;
        stats[256 + ch] = bet[ch] - m * sc;
    }
}

// ---------------- final: BN-apply + residual + relu + L2-norm + pool ----------------
// grid 256 (graph), 512 threads: 2 rows per iteration, 64 iterations.
__global__ __launch_bounds__(512) void k_finz(
    const bf* __restrict__ X, const float* __restrict__ stats,
    const bf* __restrict__ res, float* __restrict__ outz, bf* __restrict__ Znb,
    float* __restrict__ outzg, bf* __restrict__ ZGb) {
    int g = blockIdx.x, t = threadIdx.x;
    int rr = t >> 8;           // 0/1: which row of the pair
    int c = t & 255;
    int lane = t & 63, wid = (t >> 6) & 3;
    float cmax = 0.f;          // values are >= 0
    __shared__ float red[2][4];
    __shared__ float den[2];
    __shared__ float pm[512];
    for (int it = 0; it < 64; ++it) {
        int r = it * 2 + rr;
        long i = (long)(g * 128 + r) * 256 + c;
        float v = fmaf(bf2f(X[i]), stats[c], stats[256 + c]);
        v = fmaxf(v, 0.f) + bf2f(res[i]);
        v = fmaxf(v, 0.f);
        float s = v * v;
#pragma unroll
        for (int o = 32; o > 0; o >>= 1) s += __shfl_down(s, o);
        if (lane == 0) red[rr][wid] = s;
        __syncthreads();
        if (c == 0) den[rr] = fmaxf(sqrtf(red[rr][0] + red[rr][1] + red[rr][2] + red[rr][3]),
                                    1e-12f);
        __syncthreads();
        float o = v / den[rr];
        outz[i] = o;
        Znb[i] = f2bf(o);
        cmax = fmaxf(cmax, o);
    }
    pm[t] = cmax;
    __syncthreads();
    if (t < 256) {
        float m = fmaxf(pm[t], pm[t + 256]);
        outzg[g * 256 + t] = m;
        ZGb[g * 256 + t] = f2bf(m);
    }
}

// ---------------- host ----------------
template <int EPI, int OUT, bool PART, bool BNA>
static void MG(hipStream_t st, const bf* A, const bf* BT, const float* bias,
               const float* bnstats, float* Cf, bf* Cb, float* part,
               int M, int N, int K, int ldc) {
    dim3 g(N / 128, M / 128, 1);
    mg<EPI, OUT, PART, BNA><<<g, 256, 0, st>>>(A, BT, bias, bnstats, Cf, Cb, part,
                                               M, N, K, ldc);
}

extern "C" void kernel_launch(void* const* d_in, const int* in_sizes, int n_in,
                              void* d_out, int out_size, void* d_ws, size_t ws_size,
                              hipStream_t stream) {
    const float* x      = (const float*)d_in[0];
    const int*   srcL   = (const int*)d_in[1];
    const int*   dstL   = (const int*)d_in[2];
    const float* gcn_w0 = (const float*)d_in[3];
    const float* bn_g0  = (const float*)d_in[5];
    const float* bn_b0  = (const float*)d_in[6];
    const float* gcn_w1 = (const float*)d_in[7];
    const float* bn_g1  = (const float*)d_in[9];
    const float* bn_b1  = (const float*)d_in[10];
    const float* gcn_w2 = (const float*)d_in[11];
    const float* bn_g2  = (const float*)d_in[13];
    const float* bn_b2  = (const float*)d_in[14];
    const float* sc_w0  = (const float*)d_in[15];
    const float* sc_b0  = (const float*)d_in[16];
    const float* edge_w = (const float*)d_in[17];
    const float* fd_w0  = (const float*)d_in[18];
    const float* fd_b0  = (const float*)d_in[19];
    const float* fd_g0  = (const float*)d_in[20];
    const float* fd_be0 = (const float*)d_in[21];
    const float* fd_w1  = (const float*)d_in[22];
    const float* fd_b1  = (const float*)d_in[23];
    const float* fd_g1  = (const float*)d_in[24];
    const float* fd_be1 = (const float*)d_in[25];
    const float* fd_w2  = (const float*)d_in[26];
    const float* fd_b2  = (const float*)d_in[27];
    const float* ph_w0  = (const float*)d_in[28];
    const float* ph_b0  = (const float*)d_in[29];
    const float* ph_w1  = (const float*)d_in[30];
    const float* ph_b1  = (const float*)d_in[31];

    float* out     = (float*)d_out;
    float* out_z   = out;
    float* out_adj = out + 8388608;
    float* out_xr  = out + 12582912;
    float* out_zg  = out + 16777216;
    float* out_zgm = out + 16842752;

    float* w     = (float*)d_ws;
    float* part  = w;                        // 131072
    float* stats = w + 131072;               // 512
    bf*    wT    = (bf*)(w + 131584);        // 557056 bf16
    bf*    Aadjb = (bf*)(w + 410112);        // 4194304 bf16
    bf*    U4    = (bf*)(w + 2507264);       // 8388608 bf16
    bf*    U1    = (bf*)(w + 6701568);       // 8388608 bf16
    bf*    U2    = (bf*)(w + 10895872);      // 8388608 bf16
    bf*    U3    = (bf*)(w + 15090176);      // 8388608 bf16
    bf*    ZGb   = (bf*)(w + 19284480);      // 65536 bf16
    bf*    P1b   = (bf*)(w + 19317248);      // 65536 bf16

    WTpack pk;
    pk.w[0] = {gcn_w0, 128, 256, 0};
    pk.w[1] = {sc_w0,  128, 256, 32768};
    pk.w[2] = {gcn_w1, 256, 256, 65536};
    pk.w[3] = {gcn_w2, 256, 256, 131072};
    pk.w[4] = {edge_w, 256, 256, 196608};
    pk.w[5] = {fd_w0,  256, 256, 262144};
    pk.w[6] = {fd_w1,  256, 256, 327680};
    pk.w[7] = {fd_w2,  256, 128, 393216};
    pk.w[8] = {ph_w0,  256, 256, 425984};
    pk.w[9] = {ph_w1,  256, 256, 491520};

    k_adj<<<256, 256, 0, stream>>>(srcL, dstL, Aadjb);
    k_wt<<<dim3(4, 4, 10), 256, 0, stream>>>(pk, wT);

    // --- layer 0 (fused, 4 phase-blocks/graph): AG0 -> U2, res0 -> U1 ---
    k_fused<2><<<dim3(256, 4), 512, 0, stream>>>(nullptr, x, nullptr, nullptr,
                                                 wT + 0, wT + 32768, sc_b0, Aadjb,
                                                 nullptr, U2, U1, part, nullptr);
    k_bnfin<<<256, 256, 0, stream>>>(part, bn_g0, bn_b0, stats);

    // --- layer 1 (2 phase-blocks/graph): Z0 -> U3, AG1 -> U4 ---
    k_fused<0><<<dim3(256, 2), 512, 0, stream>>>(U2, nullptr, U1, stats,
                                                 wT + 65536, nullptr, nullptr, Aadjb,
                                                 U3, U4, nullptr, part, nullptr);
    k_bnfin<<<256, 256, 0, stream>>>(part, bn_g1, bn_b1, stats);

    // --- layer 2: Z1 -> U1, AG2 -> U2 ---
    k_fused<0><<<dim3(256, 2), 512, 0, stream>>>(U4, nullptr, U3, stats,
                                                 wT + 131072, nullptr, nullptr, Aadjb,
                                                 U1, U2, nullptr, part, nullptr);
    k_bnfin<<<256, 256, 0, stream>>>(part, bn_g2, bn_b2, stats);

    // --- BN-apply + L2 + pool: AG2 (U2), res Z1 (U1) -> out_z, Zn (U3), zg ---
    k_finz<<<256, 512, 0, stream>>>(U2, stats, U1, out_z, U3, out_zg, ZGb);

    // --- edge decoder ---
    k_fused<1><<<dim3(256, 1), 512, 0, stream>>>(U3, nullptr, nullptr, nullptr,
                                                 wT + 196608, nullptr, nullptr, nullptr,
                                                 nullptr, nullptr, nullptr, nullptr,
                                                 out_adj);

    // --- feature decoder ---
    MG<2, 1, true, false>(stream, U3, wT + 262144, fd_b0, nullptr,
                          nullptr, U4, part, NN, HD, HD, 256);
    k_bnfin<<<256, 256, 0, stream>>>(part, fd_g0, fd_be0, stats);
    MG<2, 1, true, true>(stream, U4, wT + 327680, fd_b1, stats,
                         nullptr, U2, part, NN, HD, HD, 256);
    k_bnfin<<<256, 256, 0, stream>>>(part, fd_g1, fd_be1, stats);
    MG<1, 0, false, true>(stream, U2, wT + 393216, fd_b2, stats,
                          out_xr, nullptr, nullptr, NN, 128, HD, 128);

    // --- pooling head ---
    MG<2, 1, false, false>(stream, ZGb, wT + 425984, ph_b0, nullptr,
                           nullptr, P1b, nullptr, 256, 256, 256, 256);
    MG<1, 0, false, false>(stream, P1b, wT + 491520, ph_b1, nullptr,
                           out_zgm, nullptr, nullptr, 256, 256, 256, 256);
}

// Round 10
// 185.701 us; speedup vs baseline: 5.7906x; 1.1542x over previous
//
#include <hip/hip_runtime.h>
#include <hip/hip_bf16.h>

using bf = __hip_bfloat16;
typedef __attribute__((ext_vector_type(8))) short s8;
typedef __attribute__((ext_vector_type(4))) float f4;

constexpr int NN  = 32768;
constexpr int HD  = 256;

__device__ __forceinline__ float u2f(unsigned short h) {
    union { unsigned u; float f; } x; x.u = ((unsigned)h) << 16;
    return x.f;
}
__device__ __forceinline__ unsigned short f2u(float f) {
    union { float f; unsigned u; } x; x.f = f;
    unsigned r = x.u + 0x7FFF + ((x.u >> 16) & 1);
    return (unsigned short)(r >> 16);
}
__device__ __forceinline__ bf f2bf(float f) {
    unsigned short h = f2u(f);
    return *reinterpret_cast<bf*>(&h);
}
__device__ __forceinline__ float bf2f(bf b) {
    return u2f(*reinterpret_cast<unsigned short*>(&b));
}

__device__ __forceinline__ int swz(int row, int slot) {      // 64-col rows
    return row * 64 + ((slot ^ (row & 7)) << 3);
}
__device__ __forceinline__ int swz128(int row, int slot) {   // 128-col rows
    return row * 128 + ((slot ^ (row & 7)) << 3);
}

// ---------------- adjacency build ----------------
__global__ __launch_bounds__(256) void k_adj(const int* __restrict__ srcL,
                                             const int* __restrict__ dstL,
                                             bf* __restrict__ A) {
    __shared__ float sT[128 * 64];
    __shared__ float sdin[128];
    int g = blockIdx.x, t = threadIdx.x;
    const int* sg = srcL + (g << 11);
    const int* dg = dstL + (g << 11);
    if (t < 128) sdin[t] = 0.f;
    __syncthreads();
    for (int e = t; e < 2048; e += 256) atomicAdd(&sdin[dg[e]], 1.0f);
    __syncthreads();
    if (t < 128) sdin[t] = rsqrtf(sdin[t] + 1.0f);
    __syncthreads();
    bf* out = A + ((long)g << 14);
    for (int half = 0; half < 2; ++half) {
        for (int i = t; i < 8192; i += 256) sT[i] = 0.f;
        __syncthreads();
        for (int e = t; e < 2048; e += 256) {
            int s = sg[e], d = dg[e];
            if ((s >> 6) == half)
                atomicAdd(&sT[(d << 6) + (s & 63)], sdin[s] * sdin[d]);
        }
        __syncthreads();
        if (t < 128 && (t >> 6) == half)
            sT[(t << 6) + (t & 63)] += sdin[t] * sdin[t];
        __syncthreads();
        for (int i4 = t; i4 < 2048; i4 += 256) {
            int d = i4 >> 4, c4 = (i4 & 15) * 4;
            float4 v = *(float4*)&sT[(d << 6) + c4];
            ushort4 u = make_ushort4(f2u(v.x), f2u(v.y), f2u(v.z), f2u(v.w));
            *(ushort4*)&out[(d << 7) + (half << 6) + c4] = u;
        }
        __syncthreads();
    }
}

// ---------------- weight transpose f32 [K x N] -> bf16 [N x K] ----------------
struct WTd { const float* src; int K, N, off; };
struct WTpack { WTd w[10]; };
__global__ void k_wt(WTpack p, bf* __restrict__ out) {
    WTd d = p.w[blockIdx.z];
    int n0 = blockIdx.x * 64, k0 = blockIdx.y * 64;
    if (n0 >= d.N || k0 >= d.K) return;
    __shared__ float s[64][65];
    int t = threadIdx.x;
    int cc = t & 63, rq = t >> 6;
#pragma unroll
    for (int i = 0; i < 16; ++i) {
        int r = i * 4 + rq;
        s[r][cc] = d.src[(long)(k0 + r) * d.N + n0 + cc];
    }
    __syncthreads();
#pragma unroll
    for (int i = 0; i < 16; ++i) {
        int r = i * 4 + rq;
        out[d.off + (long)(n0 + r) * d.K + k0 + cc] = f2bf(s[cc][r]);
    }
}

// ---------------- MFMA GEMM (fd / ph chains) ----------------
template <int EPI, int OUT, bool PART, bool BNA>
__global__ __launch_bounds__(256) void mg(
    const bf* __restrict__ A, const bf* __restrict__ BT,
    const float* __restrict__ bias, const float* __restrict__ bnstats,
    float* __restrict__ Cf, bf* __restrict__ Cb, float* __restrict__ part,
    int M, int N, int K, int ldc) {
    __shared__ __align__(16) bf sAl[128 * 64];
    __shared__ __align__(16) bf sBl[128 * 64];
    const int m0 = blockIdx.y * 128, n0 = blockIdx.x * 128;
    const bf* Ab = A + (long)m0 * K;
    const bf* Bb = BT + (long)n0 * K;
    const int t = threadIdx.x;
    const int lane = t & 63;
    const int w = t >> 6;
    const int wm = (w >> 1) * 64, wn = (w & 1) * 64;
    const int fr16 = lane & 15, kq = lane >> 4;
    f4 acc[4][4] = {};
    for (int k0 = 0; k0 < K; k0 += 64) {
#pragma unroll
        for (int i = 0; i < 4; ++i) {
            int sdx = i * 256 + t;
            int row = sdx >> 3, sl = sdx & 7;
            s8 av = *(const s8*)&Ab[(long)row * K + k0 + sl * 8];
            if constexpr (BNA) {
                int c = k0 + sl * 8;
                float4 sc0 = *(const float4*)&bnstats[c];
                float4 sc1 = *(const float4*)&bnstats[c + 4];
                float4 sh0 = *(const float4*)&bnstats[256 + c];
                float4 sh1 = *(const float4*)&bnstats[256 + c + 4];
                float scv[8] = {sc0.x, sc0.y, sc0.z, sc0.w, sc1.x, sc1.y, sc1.z, sc1.w};
                float shv[8] = {sh0.x, sh0.y, sh0.z, sh0.w, sh1.x, sh1.y, sh1.z, sh1.w};
                unsigned short* u = (unsigned short*)&av;
#pragma unroll
                for (int j = 0; j < 8; ++j)
                    u[j] = f2u(fmaf(u2f(u[j]), scv[j], shv[j]));
            }
            *(s8*)&sAl[swz(row, sl)] = av;
            *(s8*)&sBl[swz(row, sl)] = *(const s8*)&Bb[(long)row * K + k0 + sl * 8];
        }
        __syncthreads();
#pragma unroll
        for (int ks = 0; ks < 2; ++ks) {
            s8 af[4], bg[4];
#pragma unroll
            for (int f = 0; f < 4; ++f) {
                af[f] = *(const s8*)&sAl[swz(wm + f * 16 + fr16, kq + 4 * ks)];
                bg[f] = *(const s8*)&sBl[swz(wn + f * 16 + fr16, kq + 4 * ks)];
            }
#pragma unroll
            for (int fr = 0; fr < 4; ++fr)
#pragma unroll
                for (int fc = 0; fc < 4; ++fc)
                    acc[fr][fc] = __builtin_amdgcn_mfma_f32_16x16x32_bf16(
                        af[fr], bg[fc], acc[fr][fc], 0, 0, 0);
        }
        __syncthreads();
    }
    float ps[4], ps2[4];
    if (PART) {
#pragma unroll
        for (int fc = 0; fc < 4; ++fc) { ps[fc] = 0.f; ps2[fc] = 0.f; }
    }
#pragma unroll
    for (int fr = 0; fr < 4; ++fr) {
        int rl = wm + fr * 16 + (lane >> 4) * 4;
#pragma unroll
        for (int fc = 0; fc < 4; ++fc) {
            int cl = wn + fc * 16 + (lane & 15);
            int col = n0 + cl;
            float bv = bias[col];
#pragma unroll
            for (int i = 0; i < 4; ++i) {
                float v = acc[fr][fc][i] + bv;
                if (EPI == 2) v = fmaxf(v, 0.f);
                if (PART) { ps[fc] += v; ps2[fc] += v * v; }
                if (OUT == 0) Cf[(long)(m0 + rl + i) * ldc + col] = v;
                if (OUT == 1) Cb[(long)(m0 + rl + i) * ldc + col] = f2bf(v);
            }
        }
    }
    if (PART) {
        __syncthreads();
        float* scr = (float*)sAl;
#pragma unroll
        for (int fc = 0; fc < 4; ++fc) {
            ps[fc] += __shfl_xor(ps[fc], 16);  ps[fc] += __shfl_xor(ps[fc], 32);
            ps2[fc] += __shfl_xor(ps2[fc], 16); ps2[fc] += __shfl_xor(ps2[fc], 32);
        }
        if (lane < 16) {
#pragma unroll
            for (int fc = 0; fc < 4; ++fc) {
                scr[(w * 2 + 0) * 64 + fc * 16 + lane] = ps[fc];
                scr[(w * 2 + 1) * 64 + fc * 16 + lane] = ps2[fc];
            }
        }
        __syncthreads();
        int id = blockIdx.x * gridDim.y + blockIdx.y;   // gridDim = (2, 256)
        int stat = t >> 7, c = t & 127;
        int ci = c & 63, half = c >> 6;
        float v = scr[(half * 2 + stat) * 64 + ci] + scr[((half + 2) * 2 + stat) * 64 + ci];
        part[(long)id * 256 + stat * 128 + c] = v;
    }
}

// ---------------- fused per-graph kernels ----------------
// MODE 0 (grid 256x2): phase hb = blockIdx.y (independent col-halves)
// MODE 2 (grid 256x4): phases 0,1 = GCN halves; 2,3 = shortcut halves
// MODE 1 (grid 256x1): edge decoder, internal h loop (acc2 accumulates)
template <int MODE>
__global__ __launch_bounds__(512) void k_fused(
    const bf* __restrict__ Xin, const float* __restrict__ xf,
    const bf* __restrict__ Res, const float* __restrict__ stats,
    const bf* __restrict__ Wt, const bf* __restrict__ Wt2,
    const float* __restrict__ scb, const bf* __restrict__ Adj,
    bf* __restrict__ Zout, bf* __restrict__ AG, bf* __restrict__ ResOut,
    float* __restrict__ part, float* __restrict__ adjout) {
    __shared__ __align__(16) bf sOut[128 * 128];
    __shared__ __align__(16) bf sStg[128 * 128];
    const int g = blockIdx.x;
    const int hb = blockIdx.y;
    const int t = threadIdx.x;
    const int lane = t & 63, w = t >> 6;
    const int wm = w >> 2, wn = w & 3;
    const int l15 = lane & 15, kq = lane >> 4;
    constexpr int KS1 = (MODE == 2) ? 128 : 256;
    const int h0 = (MODE == 1) ? 0 : hb;
    const int h1 = (MODE == 1) ? 2 : hb + 1;
    const bf* Xg = (MODE != 2) ? Xin + (long)g * 32768 : nullptr;
    const bf* Rg = (MODE == 0) ? Res + (long)g * 32768 : nullptr;
    f4 acc2[4][2] = {};
    for (int h = h0; h < h1; ++h) {
        // ---- stage 1 ----
        f4 acc1[4][2] = {};
        for (int k0 = 0; k0 < KS1; k0 += 64) {
            __syncthreads();
#pragma unroll
            for (int i = 0; i < 2; ++i) {
                int sdx = i * 512 + t;
                int row = sdx >> 3, sl = sdx & 7;
                int c = k0 + sl * 8;
                s8 av;
                if constexpr (MODE == 0) {
                    av = *(const s8*)&Xg[row * 256 + c];
                    s8 rv = *(const s8*)&Rg[row * 256 + c];
                    float4 sc0 = *(const float4*)&stats[c];
                    float4 sc1 = *(const float4*)&stats[c + 4];
                    float4 sh0 = *(const float4*)&stats[256 + c];
                    float4 sh1 = *(const float4*)&stats[256 + c + 4];
                    float scv[8] = {sc0.x, sc0.y, sc0.z, sc0.w, sc1.x, sc1.y, sc1.z, sc1.w};
                    float shv[8] = {sh0.x, sh0.y, sh0.z, sh0.w, sh1.x, sh1.y, sh1.z, sh1.w};
                    unsigned short* u = (unsigned short*)&av;
                    const unsigned short* ru = (const unsigned short*)&rv;
#pragma unroll
                    for (int j = 0; j < 8; ++j) {
                        float v = fmaf(u2f(u[j]), scv[j], shv[j]);
                        v = fmaxf(v, 0.f) + u2f(ru[j]);
                        u[j] = f2u(fmaxf(v, 0.f));
                    }
                    if (h == 0)
                        *(s8*)&Zout[(long)g * 32768 + row * 256 + c] = av;
                } else if constexpr (MODE == 2) {
                    const float* src = xf + ((long)(g * 128 + row)) * 128 + c;
                    float4 f0 = *(const float4*)src;
                    float4 f1 = *(const float4*)(src + 4);
                    unsigned short u[8] = {f2u(f0.x), f2u(f0.y), f2u(f0.z), f2u(f0.w),
                                           f2u(f1.x), f2u(f1.y), f2u(f1.z), f2u(f1.w)};
                    av = *(s8*)u;
                } else {  // MODE 1
                    av = *(const s8*)&Wt[(h * 128 + row) * 256 + c];
                }
                *(s8*)&sStg[swz(row, sl)] = av;
                s8 bv;
                if constexpr (MODE == 0)
                    bv = *(const s8*)&Wt[(h * 128 + row) * 256 + c];
                else if constexpr (MODE == 2) {
                    const bf* Wsrc = (h < 2) ? Wt : Wt2;
                    bv = *(const s8*)&Wsrc[((h & 1) * 128 + row) * 128 + c];
                } else  // MODE 1
                    bv = *(const s8*)&Xg[row * 256 + c];
                *(s8*)&sStg[8192 + swz(row, sl)] = bv;
            }
            __syncthreads();
#pragma unroll
            for (int ks = 0; ks < 2; ++ks) {
                s8 af[4], bg[2];
#pragma unroll
                for (int f = 0; f < 4; ++f)
                    af[f] = *(const s8*)&sStg[swz(wm * 64 + f * 16 + l15, kq + 4 * ks)];
#pragma unroll
                for (int f = 0; f < 2; ++f)
                    bg[f] = *(const s8*)&sStg[8192 + swz(wn * 32 + f * 16 + l15, kq + 4 * ks)];
#pragma unroll
                for (int fr = 0; fr < 4; ++fr)
#pragma unroll
                    for (int fc = 0; fc < 2; ++fc)
                        acc1[fr][fc] = __builtin_amdgcn_mfma_f32_16x16x32_bf16(
                            af[fr], bg[fc], acc1[fr][fc], 0, 0, 0);
            }
        }
        if (MODE == 2 && h >= 2) {
#pragma unroll
            for (int fr = 0; fr < 4; ++fr) {
                int rl = wm * 64 + fr * 16 + kq * 4;
#pragma unroll
                for (int fc = 0; fc < 2; ++fc) {
                    int cl = wn * 32 + fc * 16 + l15;
                    float bv = scb[(h - 2) * 128 + cl];
#pragma unroll
                    for (int i = 0; i < 4; ++i)
                        ResOut[(long)(g * 128 + rl + i) * 256 + (h - 2) * 128 + cl] =
                            f2bf(acc1[fr][fc][i] + bv);
                }
            }
            continue;
        }
        // transposed store of stage-1 result
#pragma unroll
        for (int fr = 0; fr < 4; ++fr) {
            int rl = wm * 64 + fr * 16 + kq * 4;
#pragma unroll
            for (int fc = 0; fc < 2; ++fc) {
                int cl = wn * 32 + fc * 16 + l15;
                ushort4 q = make_ushort4(f2u(acc1[fr][fc][0]), f2u(acc1[fr][fc][1]),
                                         f2u(acc1[fr][fc][2]), f2u(acc1[fr][fc][3]));
                int off = cl * 128 + (((rl >> 3) ^ (cl & 7)) << 3) + (rl & 7);
                *(ushort4*)&sOut[off] = q;
            }
        }
        __syncthreads();
        // ---- stage 2 staging ----
#pragma unroll
        for (int i = 0; i < 4; ++i) {
            int sdx = i * 512 + t;
            int row = sdx >> 4, sl = sdx & 15;
            const bf* src = (MODE == 1)
                ? Xg + row * 256 + h * 128 + sl * 8
                : Adj + ((long)g << 14) + row * 128 + sl * 8;
            *(s8*)&sStg[swz128(row, sl)] = *(const s8*)src;
        }
        __syncthreads();
        if (MODE != 1) {
#pragma unroll
            for (int fr = 0; fr < 4; ++fr)
#pragma unroll
                for (int fc = 0; fc < 2; ++fc) acc2[fr][fc] = f4{0.f, 0.f, 0.f, 0.f};
        }
#pragma unroll
        for (int ks = 0; ks < 4; ++ks) {
            s8 af[4], bg[2];
#pragma unroll
            for (int f = 0; f < 4; ++f)
                af[f] = *(const s8*)&sStg[swz128(wm * 64 + f * 16 + l15, ks * 4 + kq)];
#pragma unroll
            for (int f = 0; f < 2; ++f)
                bg[f] = *(const s8*)&sOut[swz128(wn * 32 + f * 16 + l15, ks * 4 + kq)];
#pragma unroll
            for (int fr = 0; fr < 4; ++fr)
#pragma unroll
                for (int fc = 0; fc < 2; ++fc)
                    acc2[fr][fc] = __builtin_amdgcn_mfma_f32_16x16x32_bf16(
                        af[fr], bg[fc], acc2[fr][fc], 0, 0, 0);
        }
        if (MODE != 1) {
            float ps[2] = {0.f, 0.f}, ps2[2] = {0.f, 0.f};
#pragma unroll
            for (int fr = 0; fr < 4; ++fr) {
                int rl = wm * 64 + fr * 16 + kq * 4;
#pragma unroll
                for (int fc = 0; fc < 2; ++fc) {
                    int cl = wn * 32 + fc * 16 + l15;
#pragma unroll
                    for (int i = 0; i < 4; ++i) {
                        float v = acc2[fr][fc][i];
                        ps[fc] += v; ps2[fc] += v * v;
                        AG[(long)(g * 128 + rl + i) * 256 + h * 128 + cl] = f2bf(v);
                    }
                }
            }
            __syncthreads();
            float* scr = (float*)sStg;
#pragma unroll
            for (int fc = 0; fc < 2; ++fc) {
                ps[fc] += __shfl_xor(ps[fc], 16);  ps[fc] += __shfl_xor(ps[fc], 32);
                ps2[fc] += __shfl_xor(ps2[fc], 16); ps2[fc] += __shfl_xor(ps2[fc], 32);
            }
            if (lane < 16) {
#pragma unroll
                for (int fc = 0; fc < 2; ++fc) {
                    int c = wn * 32 + fc * 16 + lane;
                    scr[(c * 2 + wm) * 2 + 0] = ps[fc];
                    scr[(c * 2 + wm) * 2 + 1] = ps2[fc];
                }
            }
            __syncthreads();
            if (t < 256) {
                int col = t & 127, s = t >> 7;
                part[(long)(h * 256 + g) * 256 + s * 128 + col] =
                    scr[(col * 2 + 0) * 2 + s] + scr[(col * 2 + 1) * 2 + s];
            }
        }
        if (MODE == 1 && h == 1) {
#pragma unroll
            for (int fr = 0; fr < 4; ++fr) {
                int rl = wm * 64 + fr * 16 + kq * 4;
#pragma unroll
                for (int fc = 0; fc < 2; ++fc) {
                    int cl = wn * 32 + fc * 16 + l15;
                    float vv[4];
#pragma unroll
                    for (int i = 0; i < 4; ++i) {
                        float v = 1.f / (1.f + __expf(-acc2[fr][fc][i]));
                        if (cl == rl + i) v = 0.f;
                        vv[i] = v;
                    }
                    float4 o; o.x = vv[0]; o.y = vv[1]; o.z = vv[2]; o.w = vv[3];
                    *(float4*)&adjout[((long)g << 14) + cl * 128 + rl] = o;
                }
            }
        }
    }
}

// ---------------- batchnorm finalize -> (scale, shift) ----------------
__global__ void k_bnfin(const float* __restrict__ part, const float* __restrict__ gam,
                        const float* __restrict__ bet, float* __restrict__ stats) {
    int ch = blockIdx.x;
    int half = ch >> 7, cc = ch & 127;
    int t = threadIdx.x;
    __shared__ float2 sm[256];
    const float* p = part + (long)(half * 256 + t) * 256;
    sm[t] = make_float2(p[cc], p[128 + cc]);
    __syncthreads();
    for (int s = 128; s > 0; s >>= 1) {
        if (t < s) { sm[t].x += sm[t + s].x; sm[t].y += sm[t + s].y; }
        __syncthreads();
    }
    if (t == 0) {
        float m = sm[0].x / (float)NN;
        float var = sm[0].y / (float)NN - m * m;
        float sc = rsqrtf(var + 1e-5f) * gam[ch];
        stats[ch]       = sc;
        stats[256 + ch] = bet[ch] - m * sc;
    }
}

// ---------------- final: BN-apply + residual + relu + L2-norm + col-max ----------------
// grid (256 graphs, 2 halves), 512 thr = 8 waves; wave = one row at a time,
// lane l owns channels 4l..4l+3; butterfly shfl_xor row-reduce (no syncs in loop).
// Col-max via uint atomicMax on zero-initialized out_zg (values >= 0: exact, deterministic).
__global__ __launch_bounds__(512) void k_finz(
    const bf* __restrict__ X, const float* __restrict__ stats,
    const bf* __restrict__ res, float* __restrict__ outz, bf* __restrict__ Znb,
    unsigned* __restrict__ zgu) {
    int g = blockIdx.x, half = blockIdx.y;
    int t = threadIdx.x;
    int lane = t & 63, w = t >> 6;
    int c4 = lane * 4;
    float4 sc = *(const float4*)&stats[c4];
    float4 sh = *(const float4*)&stats[256 + c4];
    float scv[4] = {sc.x, sc.y, sc.z, sc.w};
    float shv[4] = {sh.x, sh.y, sh.z, sh.w};
    float cmax[4] = {0.f, 0.f, 0.f, 0.f};
#pragma unroll
    for (int it = 0; it < 8; ++it) {
        int r = half * 64 + w * 8 + it;
        long i = (long)(g * 128 + r) * 256 + c4;
        ushort4 xv = *(const ushort4*)(X + i);
        ushort4 rv = *(const ushort4*)(res + i);
        unsigned short xs[4] = {xv.x, xv.y, xv.z, xv.w};
        unsigned short rs[4] = {rv.x, rv.y, rv.z, rv.w};
        float v[4];
        float s = 0.f;
#pragma unroll
        for (int j = 0; j < 4; ++j) {
            float vv = fmaf(u2f(xs[j]), scv[j], shv[j]);
            vv = fmaxf(vv, 0.f) + u2f(rs[j]);
            vv = fmaxf(vv, 0.f);
            v[j] = vv;
            s += vv * vv;
        }
#pragma unroll
        for (int o = 1; o < 64; o <<= 1) s += __shfl_xor(s, o);
        float den = fmaxf(sqrtf(s), 1e-12f);
        float4 fo;
        unsigned short us[4];
#pragma unroll
        for (int j = 0; j < 4; ++j) {
            float o = v[j] / den;
            ((float*)&fo)[j] = o;
            us[j] = f2u(o);
            cmax[j] = fmaxf(cmax[j], o);
        }
        *(float4*)(outz + i) = fo;
        *(ushort4*)(Znb + i) = make_ushort4(us[0], us[1], us[2], us[3]);
    }
    __shared__ float pm[8][256];
#pragma unroll
    for (int j = 0; j < 4; ++j) pm[w][c4 + j] = cmax[j];
    __syncthreads();
    if (t < 256) {
        float m = pm[0][t];
#pragma unroll
        for (int ww = 1; ww < 8; ++ww) m = fmaxf(m, pm[ww][t]);
        atomicMax(&zgu[g * 256 + t], __float_as_uint(m));
    }
}

// zg f32 -> bf16 (for pooling-head GEMM input)
__global__ void k_zgcvt(const float* __restrict__ zg, bf* __restrict__ ZGb) {
    int i4 = (blockIdx.x * 256 + threadIdx.x) * 4;
    float4 v = *(const float4*)&zg[i4];
    *(ushort4*)&ZGb[i4] = make_ushort4(f2u(v.x), f2u(v.y), f2u(v.z), f2u(v.w));
}

// ---------------- host ----------------
template <int EPI, int OUT, bool PART, bool BNA>
static void MG(hipStream_t st, const bf* A, const bf* BT, const float* bias,
               const float* bnstats, float* Cf, bf* Cb, float* part,
               int M, int N, int K, int ldc) {
    dim3 g(N / 128, M / 128, 1);
    mg<EPI, OUT, PART, BNA><<<g, 256, 0, st>>>(A, BT, bias, bnstats, Cf, Cb, part,
                                               M, N, K, ldc);
}

extern "C" void kernel_launch(void* const* d_in, const int* in_sizes, int n_in,
                              void* d_out, int out_size, void* d_ws, size_t ws_size,
                              hipStream_t stream) {
    const float* x      = (const float*)d_in[0];
    const int*   srcL   = (const int*)d_in[1];
    const int*   dstL   = (const int*)d_in[2];
    const float* gcn_w0 = (const float*)d_in[3];
    const float* bn_g0  = (const float*)d_in[5];
    const float* bn_b0  = (const float*)d_in[6];
    const float* gcn_w1 = (const float*)d_in[7];
    const float* bn_g1  = (const float*)d_in[9];
    const float* bn_b1  = (const float*)d_in[10];
    const float* gcn_w2 = (const float*)d_in[11];
    const float* bn_g2  = (const float*)d_in[13];
    const float* bn_b2  = (const float*)d_in[14];
    const float* sc_w0  = (const float*)d_in[15];
    const float* sc_b0  = (const float*)d_in[16];
    const float* edge_w = (const float*)d_in[17];
    const float* fd_w0  = (const float*)d_in[18];
    const float* fd_b0  = (const float*)d_in[19];
    const float* fd_g0  = (const float*)d_in[20];
    const float* fd_be0 = (const float*)d_in[21];
    const float* fd_w1  = (const float*)d_in[22];
    const float* fd_b1  = (const float*)d_in[23];
    const float* fd_g1  = (const float*)d_in[24];
    const float* fd_be1 = (const float*)d_in[25];
    const float* fd_w2  = (const float*)d_in[26];
    const float* fd_b2  = (const float*)d_in[27];
    const float* ph_w0  = (const float*)d_in[28];
    const float* ph_b0  = (const float*)d_in[29];
    const float* ph_w1  = (const float*)d_in[30];
    const float* ph_b1  = (const float*)d_in[31];

    float* out     = (float*)d_out;
    float* out_z   = out;
    float* out_adj = out + 8388608;
    float* out_xr  = out + 12582912;
    float* out_zg  = out + 16777216;
    float* out_zgm = out + 16842752;

    float* w     = (float*)d_ws;
    float* part  = w;                        // 131072
    float* stats = w + 131072;               // 512
    bf*    wT    = (bf*)(w + 131584);        // 557056 bf16
    bf*    Aadjb = (bf*)(w + 410112);        // 4194304 bf16
    bf*    U4    = (bf*)(w + 2507264);       // 8388608 bf16
    bf*    U1    = (bf*)(w + 6701568);       // 8388608 bf16
    bf*    U2    = (bf*)(w + 10895872);      // 8388608 bf16
    bf*    U3    = (bf*)(w + 15090176);      // 8388608 bf16
    bf*    ZGb   = (bf*)(w + 19284480);      // 65536 bf16
    bf*    P1b   = (bf*)(w + 19317248);      // 65536 bf16

    WTpack pk;
    pk.w[0] = {gcn_w0, 128, 256, 0};
    pk.w[1] = {sc_w0,  128, 256, 32768};
    pk.w[2] = {gcn_w1, 256, 256, 65536};
    pk.w[3] = {gcn_w2, 256, 256, 131072};
    pk.w[4] = {edge_w, 256, 256, 196608};
    pk.w[5] = {fd_w0,  256, 256, 262144};
    pk.w[6] = {fd_w1,  256, 256, 327680};
    pk.w[7] = {fd_w2,  256, 128, 393216};
    pk.w[8] = {ph_w0,  256, 256, 425984};
    pk.w[9] = {ph_w1,  256, 256, 491520};

    // zero out_zg early (atomicMax target; harness poisons d_out)
    hipMemsetAsync(out_zg, 0, 65536 * 4, stream);

    k_adj<<<256, 256, 0, stream>>>(srcL, dstL, Aadjb);
    k_wt<<<dim3(4, 4, 10), 256, 0, stream>>>(pk, wT);

    // --- layer 0 (fused, 4 phase-blocks/graph): AG0 -> U2, res0 -> U1 ---
    k_fused<2><<<dim3(256, 4), 512, 0, stream>>>(nullptr, x, nullptr, nullptr,
                                                 wT + 0, wT + 32768, sc_b0, Aadjb,
                                                 nullptr, U2, U1, part, nullptr);
    k_bnfin<<<256, 256, 0, stream>>>(part, bn_g0, bn_b0, stats);

    // --- layer 1 (2 phase-blocks/graph): Z0 -> U3, AG1 -> U4 ---
    k_fused<0><<<dim3(256, 2), 512, 0, stream>>>(U2, nullptr, U1, stats,
                                                 wT + 65536, nullptr, nullptr, Aadjb,
                                                 U3, U4, nullptr, part, nullptr);
    k_bnfin<<<256, 256, 0, stream>>>(part, bn_g1, bn_b1, stats);

    // --- layer 2: Z1 -> U1, AG2 -> U2 ---
    k_fused<0><<<dim3(256, 2), 512, 0, stream>>>(U4, nullptr, U3, stats,
                                                 wT + 131072, nullptr, nullptr, Aadjb,
                                                 U1, U2, nullptr, part, nullptr);
    k_bnfin<<<256, 256, 0, stream>>>(part, bn_g2, bn_b2, stats);

    // --- BN-apply + L2 + col-max: AG2 (U2), res Z1 (U1) -> out_z, Zn (U3), zg ---
    k_finz<<<dim3(256, 2), 512, 0, stream>>>(U2, stats, U1, out_z, U3,
                                             (unsigned*)out_zg);
    k_zgcvt<<<64, 256, 0, stream>>>(out_zg, ZGb);

    // --- edge decoder ---
    k_fused<1><<<dim3(256, 1), 512, 0, stream>>>(U3, nullptr, nullptr, nullptr,
                                                 wT + 196608, nullptr, nullptr, nullptr,
                                                 nullptr, nullptr, nullptr, nullptr,
                                                 out_adj);

    // --- feature decoder ---
    MG<2, 1, true, false>(stream, U3, wT + 262144, fd_b0, nullptr,
                          nullptr, U4, part, NN, HD, HD, 256);
    k_bnfin<<<256, 256, 0, stream>>>(part, fd_g0, fd_be0, stats);
    MG<2, 1, true, true>(stream, U4, wT + 327680, fd_b1, stats,
                         nullptr, U2, part, NN, HD, HD, 256);
    k_bnfin<<<256, 256, 0, stream>>>(part, fd_g1, fd_be1, stats);
    MG<1, 0, false, true>(stream, U2, wT + 393216, fd_b2, stats,
                          out_xr, nullptr, nullptr, NN, 128, HD, 128);

    // --- pooling head ---
    MG<2, 1, false, false>(stream, ZGb, wT + 425984, ph_b0, nullptr,
                           nullptr, P1b, nullptr, 256, 256, 256, 256);
    MG<1, 0, false, false>(stream, P1b, wT + 491520, ph_b1, nullptr,
                           out_zgm, nullptr, nullptr, 256, 256, 256, 256);
}

// Round 11
// 182.591 us; speedup vs baseline: 5.8892x; 1.0170x over previous
//
#include <hip/hip_runtime.h>
#include <hip/hip_bf16.h>

using bf = __hip_bfloat16;
typedef __attribute__((ext_vector_type(8))) short s8;
typedef __attribute__((ext_vector_type(4))) float f4;

constexpr int NN  = 32768;
constexpr int HD  = 256;

__device__ __forceinline__ float u2f(unsigned short h) {
    union { unsigned u; float f; } x; x.u = ((unsigned)h) << 16;
    return x.f;
}
__device__ __forceinline__ unsigned short f2u(float f) {
    union { float f; unsigned u; } x; x.f = f;
    unsigned r = x.u + 0x7FFF + ((x.u >> 16) & 1);
    return (unsigned short)(r >> 16);
}
__device__ __forceinline__ bf f2bf(float f) {
    unsigned short h = f2u(f);
    return *reinterpret_cast<bf*>(&h);
}
__device__ __forceinline__ float bf2f(bf b) {
    return u2f(*reinterpret_cast<unsigned short*>(&b));
}

__device__ __forceinline__ int swz(int row, int slot) {      // 64-col rows
    return row * 64 + ((slot ^ (row & 7)) << 3);
}
__device__ __forceinline__ int swz128(int row, int slot) {   // 128-col rows
    return row * 128 + ((slot ^ (row & 7)) << 3);
}

// ---------------- prep: adjacency (blocks 0..255) + weight transpose (256..415)
//                  + x f32->bf16 (416..671), one dispatch ----------------
struct WTd { const float* src; int K, N, off; };
struct WTpack { WTd w[10]; };

__global__ __launch_bounds__(256) void k_prep(const int* __restrict__ srcL,
                                              const int* __restrict__ dstL,
                                              const float* __restrict__ xf,
                                              WTpack p, bf* __restrict__ A,
                                              bf* __restrict__ xb,
                                              bf* __restrict__ wT) {
    __shared__ __align__(16) float shm[8320];   // 33.3KB, aliased by branches
    int b = blockIdx.x, t = threadIdx.x;
    if (b < 256) {
        // ---- adjacency build for graph b ----
        float* sT = shm;            // [128][64]
        float* sdin = shm + 8192;   // [128]
        int g = b;
        const int* sg = srcL + (g << 11);
        const int* dg = dstL + (g << 11);
        if (t < 128) sdin[t] = 0.f;
        __syncthreads();
        for (int e = t; e < 2048; e += 256) atomicAdd(&sdin[dg[e]], 1.0f);
        __syncthreads();
        if (t < 128) sdin[t] = rsqrtf(sdin[t] + 1.0f);
        __syncthreads();
        bf* out = A + ((long)g << 14);
        for (int half = 0; half < 2; ++half) {
            for (int i = t; i < 8192; i += 256) sT[i] = 0.f;
            __syncthreads();
            for (int e = t; e < 2048; e += 256) {
                int s = sg[e], d = dg[e];
                if ((s >> 6) == half)
                    atomicAdd(&sT[(d << 6) + (s & 63)], sdin[s] * sdin[d]);
            }
            __syncthreads();
            if (t < 128 && (t >> 6) == half)
                sT[(t << 6) + (t & 63)] += sdin[t] * sdin[t];
            __syncthreads();
            for (int i4 = t; i4 < 2048; i4 += 256) {
                int d = i4 >> 4, c4 = (i4 & 15) * 4;
                float4 v = *(float4*)&sT[(d << 6) + c4];
                ushort4 u = make_ushort4(f2u(v.x), f2u(v.y), f2u(v.z), f2u(v.w));
                *(ushort4*)&out[(d << 7) + (half << 6) + c4] = u;
            }
            __syncthreads();
        }
    } else if (b < 416) {
        // ---- weight transpose tile ----
        int idx = b - 256;
        WTd d = p.w[idx >> 4];
        int rem = idx & 15;
        int n0 = (rem & 3) * 64, k0 = (rem >> 2) * 64;
        if (n0 >= d.N || k0 >= d.K) return;
        float (*s)[65] = (float(*)[65])shm;
        int cc = t & 63, rq = t >> 6;
#pragma unroll
        for (int i = 0; i < 16; ++i) {
            int r = i * 4 + rq;
            s[r][cc] = d.src[(long)(k0 + r) * d.N + n0 + cc];
        }
        __syncthreads();
#pragma unroll
        for (int i = 0; i < 16; ++i) {
            int r = i * 4 + rq;
            wT[d.off + (long)(n0 + r) * d.K + k0 + cc] = f2bf(s[cc][r]);
        }
    } else {
        // ---- x f32 -> bf16 ----
        long base = (long)(b - 416) * 16384;
#pragma unroll
        for (int it = 0; it < 16; ++it) {
            long i4 = base + (it * 256 + t) * 4;
            float4 v = *(const float4*)&xf[i4];
            *(ushort4*)&xb[i4] = make_ushort4(f2u(v.x), f2u(v.y), f2u(v.z), f2u(v.w));
        }
    }
}

// ---------------- MFMA GEMM (fd / ph chains) ----------------
// AF32: A is f32 row-major, converted during staging.
template <int EPI, int OUT, bool PART, bool BNA, bool AF32>
__global__ __launch_bounds__(256) void mg(
    const void* __restrict__ Av, const bf* __restrict__ BT,
    const float* __restrict__ bias, const float* __restrict__ bnstats,
    float* __restrict__ Cf, bf* __restrict__ Cb, float* __restrict__ part,
    int M, int N, int K, int ldc) {
    __shared__ __align__(16) bf sAl[128 * 64];
    __shared__ __align__(16) bf sBl[128 * 64];
    const int m0 = blockIdx.y * 128, n0 = blockIdx.x * 128;
    const bf* Bb = BT + (long)n0 * K;
    const int t = threadIdx.x;
    const int lane = t & 63;
    const int w = t >> 6;
    const int wm = (w >> 1) * 64, wn = (w & 1) * 64;
    const int fr16 = lane & 15, kq = lane >> 4;
    f4 acc[4][4] = {};
    for (int k0 = 0; k0 < K; k0 += 64) {
#pragma unroll
        for (int i = 0; i < 4; ++i) {
            int sdx = i * 256 + t;
            int row = sdx >> 3, sl = sdx & 7;
            s8 av;
            if constexpr (AF32) {
                const float* src = (const float*)Av + (long)(m0 + row) * K + k0 + sl * 8;
                float4 f0 = *(const float4*)src;
                float4 f1 = *(const float4*)(src + 4);
                unsigned short u[8] = {f2u(f0.x), f2u(f0.y), f2u(f0.z), f2u(f0.w),
                                       f2u(f1.x), f2u(f1.y), f2u(f1.z), f2u(f1.w)};
                av = *(s8*)u;
            } else {
                av = *(const s8*)&((const bf*)Av)[(long)(m0 + row) * K + k0 + sl * 8];
                if constexpr (BNA) {
                    int c = k0 + sl * 8;
                    float4 sc0 = *(const float4*)&bnstats[c];
                    float4 sc1 = *(const float4*)&bnstats[c + 4];
                    float4 sh0 = *(const float4*)&bnstats[256 + c];
                    float4 sh1 = *(const float4*)&bnstats[256 + c + 4];
                    float scv[8] = {sc0.x, sc0.y, sc0.z, sc0.w, sc1.x, sc1.y, sc1.z, sc1.w};
                    float shv[8] = {sh0.x, sh0.y, sh0.z, sh0.w, sh1.x, sh1.y, sh1.z, sh1.w};
                    unsigned short* u = (unsigned short*)&av;
#pragma unroll
                    for (int j = 0; j < 8; ++j)
                        u[j] = f2u(fmaf(u2f(u[j]), scv[j], shv[j]));
                }
            }
            *(s8*)&sAl[swz(row, sl)] = av;
            *(s8*)&sBl[swz(row, sl)] = *(const s8*)&Bb[(long)row * K + k0 + sl * 8];
        }
        __syncthreads();
#pragma unroll
        for (int ks = 0; ks < 2; ++ks) {
            s8 af[4], bg[4];
#pragma unroll
            for (int f = 0; f < 4; ++f) {
                af[f] = *(const s8*)&sAl[swz(wm + f * 16 + fr16, kq + 4 * ks)];
                bg[f] = *(const s8*)&sBl[swz(wn + f * 16 + fr16, kq + 4 * ks)];
            }
#pragma unroll
            for (int fr = 0; fr < 4; ++fr)
#pragma unroll
                for (int fc = 0; fc < 4; ++fc)
                    acc[fr][fc] = __builtin_amdgcn_mfma_f32_16x16x32_bf16(
                        af[fr], bg[fc], acc[fr][fc], 0, 0, 0);
        }
        __syncthreads();
    }
    float ps[4], ps2[4];
    if (PART) {
#pragma unroll
        for (int fc = 0; fc < 4; ++fc) { ps[fc] = 0.f; ps2[fc] = 0.f; }
    }
#pragma unroll
    for (int fr = 0; fr < 4; ++fr) {
        int rl = wm + fr * 16 + (lane >> 4) * 4;
#pragma unroll
        for (int fc = 0; fc < 4; ++fc) {
            int cl = wn + fc * 16 + (lane & 15);
            int col = n0 + cl;
            float bv = bias[col];
#pragma unroll
            for (int i = 0; i < 4; ++i) {
                float v = acc[fr][fc][i] + bv;
                if (EPI == 2) v = fmaxf(v, 0.f);
                if (PART) { ps[fc] += v; ps2[fc] += v * v; }
                if (OUT == 0) Cf[(long)(m0 + rl + i) * ldc + col] = v;
                if (OUT == 1) Cb[(long)(m0 + rl + i) * ldc + col] = f2bf(v);
            }
        }
    }
    if (PART) {
        __syncthreads();
        float* scr = (float*)sAl;
#pragma unroll
        for (int fc = 0; fc < 4; ++fc) {
            ps[fc] += __shfl_xor(ps[fc], 16);  ps[fc] += __shfl_xor(ps[fc], 32);
            ps2[fc] += __shfl_xor(ps2[fc], 16); ps2[fc] += __shfl_xor(ps2[fc], 32);
        }
        if (lane < 16) {
#pragma unroll
            for (int fc = 0; fc < 4; ++fc) {
                scr[(w * 2 + 0) * 64 + fc * 16 + lane] = ps[fc];
                scr[(w * 2 + 1) * 64 + fc * 16 + lane] = ps2[fc];
            }
        }
        __syncthreads();
        int id = blockIdx.x * gridDim.y + blockIdx.y;   // gridDim = (2, 256)
        int stat = t >> 7, c = t & 127;
        int ci = c & 63, half = c >> 6;
        float v = scr[(half * 2 + stat) * 64 + ci] + scr[((half + 2) * 2 + stat) * 64 + ci];
        part[(long)id * 256 + stat * 128 + c] = v;
    }
}

// ---------------- fused per-graph kernels ----------------
// MODE 0 (grid 256x2): phase hb = blockIdx.y (independent col-halves)
// MODE 2 (grid 256x4): phases 0,1 = GCN halves; 2,3 = shortcut halves; x is bf16
// MODE 1 (grid 256x1): edge decoder, internal h loop (acc2 accumulates)
template <int MODE>
__global__ __launch_bounds__(512) void k_fused(
    const bf* __restrict__ Xin,
    const bf* __restrict__ Res, const float* __restrict__ stats,
    const bf* __restrict__ Wt, const bf* __restrict__ Wt2,
    const float* __restrict__ scb, const bf* __restrict__ Adj,
    bf* __restrict__ Zout, bf* __restrict__ AG, bf* __restrict__ ResOut,
    float* __restrict__ part, float* __restrict__ adjout) {
    __shared__ __align__(16) bf sOut[128 * 128];
    __shared__ __align__(16) bf sStg[128 * 128];
    const int g = blockIdx.x;
    const int hb = blockIdx.y;
    const int t = threadIdx.x;
    const int lane = t & 63, w = t >> 6;
    const int wm = w >> 2, wn = w & 3;
    const int l15 = lane & 15, kq = lane >> 4;
    constexpr int KS1 = (MODE == 2) ? 128 : 256;
    const int h0 = (MODE == 1) ? 0 : hb;
    const int h1 = (MODE == 1) ? 2 : hb + 1;
    const bf* Xg = Xin + (long)g * ((MODE == 2) ? 16384 : 32768);
    const bf* Rg = (MODE == 0) ? Res + (long)g * 32768 : nullptr;
    f4 acc2[4][2] = {};
    for (int h = h0; h < h1; ++h) {
        // ---- stage 1 ----
        f4 acc1[4][2] = {};
        for (int k0 = 0; k0 < KS1; k0 += 64) {
            __syncthreads();
#pragma unroll
            for (int i = 0; i < 2; ++i) {
                int sdx = i * 512 + t;
                int row = sdx >> 3, sl = sdx & 7;
                int c = k0 + sl * 8;
                s8 av;
                if constexpr (MODE == 0) {
                    av = *(const s8*)&Xg[row * 256 + c];
                    s8 rv = *(const s8*)&Rg[row * 256 + c];
                    float4 sc0 = *(const float4*)&stats[c];
                    float4 sc1 = *(const float4*)&stats[c + 4];
                    float4 sh0 = *(const float4*)&stats[256 + c];
                    float4 sh1 = *(const float4*)&stats[256 + c + 4];
                    float scv[8] = {sc0.x, sc0.y, sc0.z, sc0.w, sc1.x, sc1.y, sc1.z, sc1.w};
                    float shv[8] = {sh0.x, sh0.y, sh0.z, sh0.w, sh1.x, sh1.y, sh1.z, sh1.w};
                    unsigned short* u = (unsigned short*)&av;
                    const unsigned short* ru = (const unsigned short*)&rv;
#pragma unroll
                    for (int j = 0; j < 8; ++j) {
                        float v = fmaf(u2f(u[j]), scv[j], shv[j]);
                        v = fmaxf(v, 0.f) + u2f(ru[j]);
                        u[j] = f2u(fmaxf(v, 0.f));
                    }
                    if (h == 0)
                        *(s8*)&Zout[(long)g * 32768 + row * 256 + c] = av;
                } else if constexpr (MODE == 2) {
                    av = *(const s8*)&Xg[row * 128 + c];
                } else {  // MODE 1
                    av = *(const s8*)&Wt[(h * 128 + row) * 256 + c];
                }
                *(s8*)&sStg[swz(row, sl)] = av;
                s8 bv;
                if constexpr (MODE == 0)
                    bv = *(const s8*)&Wt[(h * 128 + row) * 256 + c];
                else if constexpr (MODE == 2) {
                    const bf* Wsrc = (h < 2) ? Wt : Wt2;
                    bv = *(const s8*)&Wsrc[((h & 1) * 128 + row) * 128 + c];
                } else  // MODE 1
                    bv = *(const s8*)&Xg[row * 256 + c];
                *(s8*)&sStg[8192 + swz(row, sl)] = bv;
            }
            __syncthreads();
#pragma unroll
            for (int ks = 0; ks < 2; ++ks) {
                s8 af[4], bg[2];
#pragma unroll
                for (int f = 0; f < 4; ++f)
                    af[f] = *(const s8*)&sStg[swz(wm * 64 + f * 16 + l15, kq + 4 * ks)];
#pragma unroll
                for (int f = 0; f < 2; ++f)
                    bg[f] = *(const s8*)&sStg[8192 + swz(wn * 32 + f * 16 + l15, kq + 4 * ks)];
#pragma unroll
                for (int fr = 0; fr < 4; ++fr)
#pragma unroll
                    for (int fc = 0; fc < 2; ++fc)
                        acc1[fr][fc] = __builtin_amdgcn_mfma_f32_16x16x32_bf16(
                            af[fr], bg[fc], acc1[fr][fc], 0, 0, 0);
            }
        }
        if (MODE == 2 && h >= 2) {
#pragma unroll
            for (int fr = 0; fr < 4; ++fr) {
                int rl = wm * 64 + fr * 16 + kq * 4;
#pragma unroll
                for (int fc = 0; fc < 2; ++fc) {
                    int cl = wn * 32 + fc * 16 + l15;
                    float bv = scb[(h - 2) * 128 + cl];
#pragma unroll
                    for (int i = 0; i < 4; ++i)
                        ResOut[(long)(g * 128 + rl + i) * 256 + (h - 2) * 128 + cl] =
                            f2bf(acc1[fr][fc][i] + bv);
                }
            }
            continue;
        }
        // transposed store of stage-1 result
#pragma unroll
        for (int fr = 0; fr < 4; ++fr) {
            int rl = wm * 64 + fr * 16 + kq * 4;
#pragma unroll
            for (int fc = 0; fc < 2; ++fc) {
                int cl = wn * 32 + fc * 16 + l15;
                ushort4 q = make_ushort4(f2u(acc1[fr][fc][0]), f2u(acc1[fr][fc][1]),
                                         f2u(acc1[fr][fc][2]), f2u(acc1[fr][fc][3]));
                int off = cl * 128 + (((rl >> 3) ^ (cl & 7)) << 3) + (rl & 7);
                *(ushort4*)&sOut[off] = q;
            }
        }
        __syncthreads();
        // ---- stage 2 staging ----
#pragma unroll
        for (int i = 0; i < 4; ++i) {
            int sdx = i * 512 + t;
            int row = sdx >> 4, sl = sdx & 15;
            const bf* src = (MODE == 1)
                ? Xg + row * 256 + h * 128 + sl * 8
                : Adj + ((long)g << 14) + row * 128 + sl * 8;
            *(s8*)&sStg[swz128(row, sl)] = *(const s8*)src;
        }
        __syncthreads();
        if (MODE != 1) {
#pragma unroll
            for (int fr = 0; fr < 4; ++fr)
#pragma unroll
                for (int fc = 0; fc < 2; ++fc) acc2[fr][fc] = f4{0.f, 0.f, 0.f, 0.f};
        }
#pragma unroll
        for (int ks = 0; ks < 4; ++ks) {
            s8 af[4], bg[2];
#pragma unroll
            for (int f = 0; f < 4; ++f)
                af[f] = *(const s8*)&sStg[swz128(wm * 64 + f * 16 + l15, ks * 4 + kq)];
#pragma unroll
            for (int f = 0; f < 2; ++f)
                bg[f] = *(const s8*)&sOut[swz128(wn * 32 + f * 16 + l15, ks * 4 + kq)];
#pragma unroll
            for (int fr = 0; fr < 4; ++fr)
#pragma unroll
                for (int fc = 0; fc < 2; ++fc)
                    acc2[fr][fc] = __builtin_amdgcn_mfma_f32_16x16x32_bf16(
                        af[fr], bg[fc], acc2[fr][fc], 0, 0, 0);
        }
        if (MODE != 1) {
            float ps[2] = {0.f, 0.f}, ps2[2] = {0.f, 0.f};
#pragma unroll
            for (int fr = 0; fr < 4; ++fr) {
                int rl = wm * 64 + fr * 16 + kq * 4;
#pragma unroll
                for (int fc = 0; fc < 2; ++fc) {
                    int cl = wn * 32 + fc * 16 + l15;
#pragma unroll
                    for (int i = 0; i < 4; ++i) {
                        float v = acc2[fr][fc][i];
                        ps[fc] += v; ps2[fc] += v * v;
                        AG[(long)(g * 128 + rl + i) * 256 + h * 128 + cl] = f2bf(v);
                    }
                }
            }
            __syncthreads();
            float* scr = (float*)sStg;
#pragma unroll
            for (int fc = 0; fc < 2; ++fc) {
                ps[fc] += __shfl_xor(ps[fc], 16);  ps[fc] += __shfl_xor(ps[fc], 32);
                ps2[fc] += __shfl_xor(ps2[fc], 16); ps2[fc] += __shfl_xor(ps2[fc], 32);
            }
            if (lane < 16) {
#pragma unroll
                for (int fc = 0; fc < 2; ++fc) {
                    int c = wn * 32 + fc * 16 + lane;
                    scr[(c * 2 + wm) * 2 + 0] = ps[fc];
                    scr[(c * 2 + wm) * 2 + 1] = ps2[fc];
                }
            }
            __syncthreads();
            if (t < 256) {
                int col = t & 127, s = t >> 7;
                part[(long)(h * 256 + g) * 256 + s * 128 + col] =
                    scr[(col * 2 + 0) * 2 + s] + scr[(col * 2 + 1) * 2 + s];
            }
        }
        if (MODE == 1 && h == 1) {
#pragma unroll
            for (int fr = 0; fr < 4; ++fr) {
                int rl = wm * 64 + fr * 16 + kq * 4;
#pragma unroll
                for (int fc = 0; fc < 2; ++fc) {
                    int cl = wn * 32 + fc * 16 + l15;
                    float vv[4];
#pragma unroll
                    for (int i = 0; i < 4; ++i) {
                        float v = 1.f / (1.f + __expf(-acc2[fr][fc][i]));
                        if (cl == rl + i) v = 0.f;
                        vv[i] = v;
                    }
                    float4 o; o.x = vv[0]; o.y = vv[1]; o.z = vv[2]; o.w = vv[3];
                    *(float4*)&adjout[((long)g << 14) + cl * 128 + rl] = o;
                }
            }
        }
    }
}

// ---------------- batchnorm finalize -> (scale, shift) ----------------
__global__ void k_bnfin(const float* __restrict__ part, const float* __restrict__ gam,
                        const float* __restrict__ bet, float* __restrict__ stats) {
    int ch = blockIdx.x;
    int half = ch >> 7, cc = ch & 127;
    int t = threadIdx.x;
    __shared__ float2 sm[256];
    const float* p = part + (long)(half * 256 + t) * 256;
    sm[t] = make_float2(p[cc], p[128 + cc]);
    __syncthreads();
    for (int s = 128; s > 0; s >>= 1) {
        if (t < s) { sm[t].x += sm[t + s].x; sm[t].y += sm[t + s].y; }
        __syncthreads();
    }
    if (t == 0) {
        float m = sm[0].x / (float)NN;
        float var = sm[0].y / (float)NN - m * m;
        float sc = rsqrtf(var + 1e-5f) * gam[ch];
        stats[ch]       = sc;
        stats[256 + ch] = bet[ch] - m * sc;
    }
}

// ---------------- final: BN-apply + residual + relu + L2-norm + col-max ----------------
__global__ __launch_bounds__(512) void k_finz(
    const bf* __restrict__ X, const float* __restrict__ stats,
    const bf* __restrict__ res, float* __restrict__ outz, bf* __restrict__ Znb,
    unsigned* __restrict__ zgu) {
    int g = blockIdx.x, half = blockIdx.y;
    int t = threadIdx.x;
    int lane = t & 63, w = t >> 6;
    int c4 = lane * 4;
    float4 sc = *(const float4*)&stats[c4];
    float4 sh = *(const float4*)&stats[256 + c4];
    float scv[4] = {sc.x, sc.y, sc.z, sc.w};
    float shv[4] = {sh.x, sh.y, sh.z, sh.w};
    float cmax[4] = {0.f, 0.f, 0.f, 0.f};
#pragma unroll
    for (int it = 0; it < 8; ++it) {
        int r = half * 64 + w * 8 + it;
        long i = (long)(g * 128 + r) * 256 + c4;
        ushort4 xv = *(const ushort4*)(X + i);
        ushort4 rv = *(const ushort4*)(res + i);
        unsigned short xs[4] = {xv.x, xv.y, xv.z, xv.w};
        unsigned short rs[4] = {rv.x, rv.y, rv.z, rv.w};
        float v[4];
        float s = 0.f;
#pragma unroll
        for (int j = 0; j < 4; ++j) {
            float vv = fmaf(u2f(xs[j]), scv[j], shv[j]);
            vv = fmaxf(vv, 0.f) + u2f(rs[j]);
            vv = fmaxf(vv, 0.f);
            v[j] = vv;
            s += vv * vv;
        }
#pragma unroll
        for (int o = 1; o < 64; o <<= 1) s += __shfl_xor(s, o);
        float den = fmaxf(sqrtf(s), 1e-12f);
        float4 fo;
        unsigned short us[4];
#pragma unroll
        for (int j = 0; j < 4; ++j) {
            float o = v[j] / den;
            ((float*)&fo)[j] = o;
            us[j] = f2u(o);
            cmax[j] = fmaxf(cmax[j], o);
        }
        *(float4*)(outz + i) = fo;
        *(ushort4*)(Znb + i) = make_ushort4(us[0], us[1], us[2], us[3]);
    }
    __shared__ float pm[8][256];
#pragma unroll
    for (int j = 0; j < 4; ++j) pm[w][c4 + j] = cmax[j];
    __syncthreads();
    if (t < 256) {
        float m = pm[0][t];
#pragma unroll
        for (int ww = 1; ww < 8; ++ww) m = fmaxf(m, pm[ww][t]);
        atomicMax(&zgu[g * 256 + t], __float_as_uint(m));
    }
}

// ---------------- host ----------------
template <int EPI, int OUT, bool PART, bool BNA, bool AF32>
static void MG(hipStream_t st, const void* A, const bf* BT, const float* bias,
               const float* bnstats, float* Cf, bf* Cb, float* part,
               int M, int N, int K, int ldc) {
    dim3 g(N / 128, M / 128, 1);
    mg<EPI, OUT, PART, BNA, AF32><<<g, 256, 0, st>>>(A, BT, bias, bnstats, Cf, Cb, part,
                                                     M, N, K, ldc);
}

extern "C" void kernel_launch(void* const* d_in, const int* in_sizes, int n_in,
                              void* d_out, int out_size, void* d_ws, size_t ws_size,
                              hipStream_t stream) {
    const float* x      = (const float*)d_in[0];
    const int*   srcL   = (const int*)d_in[1];
    const int*   dstL   = (const int*)d_in[2];
    const float* gcn_w0 = (const float*)d_in[3];
    const float* bn_g0  = (const float*)d_in[5];
    const float* bn_b0  = (const float*)d_in[6];
    const float* gcn_w1 = (const float*)d_in[7];
    const float* bn_g1  = (const float*)d_in[9];
    const float* bn_b1  = (const float*)d_in[10];
    const float* gcn_w2 = (const float*)d_in[11];
    const float* bn_g2  = (const float*)d_in[13];
    const float* bn_b2  = (const float*)d_in[14];
    const float* sc_w0  = (const float*)d_in[15];
    const float* sc_b0  = (const float*)d_in[16];
    const float* edge_w = (const float*)d_in[17];
    const float* fd_w0  = (const float*)d_in[18];
    const float* fd_b0  = (const float*)d_in[19];
    const float* fd_g0  = (const float*)d_in[20];
    const float* fd_be0 = (const float*)d_in[21];
    const float* fd_w1  = (const float*)d_in[22];
    const float* fd_b1  = (const float*)d_in[23];
    const float* fd_g1  = (const float*)d_in[24];
    const float* fd_be1 = (const float*)d_in[25];
    const float* fd_w2  = (const float*)d_in[26];
    const float* fd_b2  = (const float*)d_in[27];
    const float* ph_w0  = (const float*)d_in[28];
    const float* ph_b0  = (const float*)d_in[29];
    const float* ph_w1  = (const float*)d_in[30];
    const float* ph_b1  = (const float*)d_in[31];

    float* out     = (float*)d_out;
    float* out_z   = out;
    float* out_adj = out + 8388608;
    float* out_xr  = out + 12582912;
    float* out_zg  = out + 16777216;
    float* out_zgm = out + 16842752;

    float* w     = (float*)d_ws;
    float* part  = w;                        // 131072
    float* stats = w + 131072;               // 512
    bf*    wT    = (bf*)(w + 131584);        // 557056 bf16
    bf*    Aadjb = (bf*)(w + 410112);        // 4194304 bf16
    bf*    U4    = (bf*)(w + 2507264);       // 8388608 bf16
    bf*    U1    = (bf*)(w + 6701568);       // 8388608 bf16
    bf*    U2    = (bf*)(w + 10895872);      // 8388608 bf16
    bf*    U3    = (bf*)(w + 15090176);      // 8388608 bf16
    bf*    P1b   = (bf*)(w + 19284480);      // 65536 bf16
    bf*    xb    = (bf*)(w + 19317248);      // 4194304 bf16
    // total ~86.0 MB

    WTpack pk;
    pk.w[0] = {gcn_w0, 128, 256, 0};
    pk.w[1] = {sc_w0,  128, 256, 32768};
    pk.w[2] = {gcn_w1, 256, 256, 65536};
    pk.w[3] = {gcn_w2, 256, 256, 131072};
    pk.w[4] = {edge_w, 256, 256, 196608};
    pk.w[5] = {fd_w0,  256, 256, 262144};
    pk.w[6] = {fd_w1,  256, 256, 327680};
    pk.w[7] = {fd_w2,  256, 128, 393216};
    pk.w[8] = {ph_w0,  256, 256, 425984};
    pk.w[9] = {ph_w1,  256, 256, 491520};

    // zero out_zg early (atomicMax target; harness poisons d_out)
    hipMemsetAsync(out_zg, 0, 65536 * 4, stream);

    // --- prep: adjacency + weight transpose + x->bf16, one dispatch ---
    k_prep<<<672, 256, 0, stream>>>(srcL, dstL, x, pk, Aadjb, xb, wT);

    // --- layer 0 (fused, 4 phase-blocks/graph): AG0 -> U2, res0 -> U1 ---
    k_fused<2><<<dim3(256, 4), 512, 0, stream>>>(xb, nullptr, nullptr,
                                                 wT + 0, wT + 32768, sc_b0, Aadjb,
                                                 nullptr, U2, U1, part, nullptr);
    k_bnfin<<<256, 256, 0, stream>>>(part, bn_g0, bn_b0, stats);

    // --- layer 1 (2 phase-blocks/graph): Z0 -> U3, AG1 -> U4 ---
    k_fused<0><<<dim3(256, 2), 512, 0, stream>>>(U2, U1, stats,
                                                 wT + 65536, nullptr, nullptr, Aadjb,
                                                 U3, U4, nullptr, part, nullptr);
    k_bnfin<<<256, 256, 0, stream>>>(part, bn_g1, bn_b1, stats);

    // --- layer 2: Z1 -> U1, AG2 -> U2 ---
    k_fused<0><<<dim3(256, 2), 512, 0, stream>>>(U4, U3, stats,
                                                 wT + 131072, nullptr, nullptr, Aadjb,
                                                 U1, U2, nullptr, part, nullptr);
    k_bnfin<<<256, 256, 0, stream>>>(part, bn_g2, bn_b2, stats);

    // --- BN-apply + L2 + col-max: AG2 (U2), res Z1 (U1) -> out_z, Zn (U3), zg ---
    k_finz<<<dim3(256, 2), 512, 0, stream>>>(U2, stats, U1, out_z, U3,
                                             (unsigned*)out_zg);

    // --- edge decoder ---
    k_fused<1><<<dim3(256, 1), 512, 0, stream>>>(U3, nullptr, nullptr,
                                                 wT + 196608, nullptr, nullptr, nullptr,
                                                 nullptr, nullptr, nullptr, nullptr,
                                                 out_adj);

    // --- feature decoder ---
    MG<2, 1, true, false, false>(stream, U3, wT + 262144, fd_b0, nullptr,
                                 nullptr, U4, part, NN, HD, HD, 256);
    k_bnfin<<<256, 256, 0, stream>>>(part, fd_g0, fd_be0, stats);
    MG<2, 1, true, true, false>(stream, U4, wT + 327680, fd_b1, stats,
                                nullptr, U2, part, NN, HD, HD, 256);
    k_bnfin<<<256, 256, 0, stream>>>(part, fd_g1, fd_be1, stats);
    MG<1, 0, false, true, false>(stream, U2, wT + 393216, fd_b2, stats,
                                 out_xr, nullptr, nullptr, NN, 128, HD, 128);

    // --- pooling head (ph0 reads out_zg f32 directly) ---
    MG<2, 1, false, false, true>(stream, out_zg, wT + 425984, ph_b0, nullptr,
                                 nullptr, P1b, nullptr, 256, 256, 256, 256);
    MG<1, 0, false, false, false>(stream, P1b, wT + 491520, ph_b1, nullptr,
                                  out_zgm, nullptr, nullptr, 256, 256, 256, 256);
}